// Round 8
// baseline (803.842 us; speedup 1.0000x reference)
//
#include <hip/hip_runtime.h>
#include <stdint.h>

typedef unsigned short u16;
typedef uint32_t u32;
typedef __attribute__((ext_vector_type(4))) float f32x4;
typedef __attribute__((ext_vector_type(8))) short bf16x8;

#define DEVINL __device__ __forceinline__

DEVINL u16 f2bf(float f) {
    union { float f; u32 u; } a; a.f = f;
    u32 u = a.u;
    return (u16)((u + 0x7fffu + ((u >> 16) & 1u)) >> 16);   // RNE
}
DEVINL u32 pk2(float a, float b) { return (u32)f2bf(a) | ((u32)f2bf(b) << 16); }

// 128B-row swizzled tile (conflict-free vector row reads) — verified R2..R7
DEVINL u32 swz128(u32 row, u32 colb) { return row * 128u + (colb ^ ((row & 7u) << 4)); }

// async global->LDS, 16B per lane
DEVINL void gload_lds16(const u16* g, char* l) {
    __builtin_amdgcn_global_load_lds(
        (const __attribute__((address_space(1))) void*)g,
        (__attribute__((address_space(3))) void*)l, 16, 0, 0);
}

// 4x4 transpose among 4 lanes (lane&3) over the 4 regs of v (R4-verified)
DEVINL f32x4 trans4(f32x4 v, int q) {
    float s0 = __shfl_xor(v[0], 1), s1 = __shfl_xor(v[1], 1),
          s2 = __shfl_xor(v[2], 1), s3 = __shfl_xor(v[3], 1);
    f32x4 t;
    bool q1 = (q & 1) != 0;
    t[0] = q1 ? s1 : v[0];
    t[1] = q1 ? v[1] : s0;
    t[2] = q1 ? s3 : v[2];
    t[3] = q1 ? v[3] : s2;
    float u0 = __shfl_xor(t[0], 2), u1 = __shfl_xor(t[1], 2),
          u2 = __shfl_xor(t[2], 2), u3 = __shfl_xor(t[3], 2);
    f32x4 r;
    bool q2 = (q & 2) != 0;
    r[0] = q2 ? u2 : t[0];
    r[1] = q2 ? u3 : t[1];
    r[2] = q2 ? t[2] : u0;
    r[3] = q2 ? t[3] : u1;
    return r;
}

// ---- cross-kernel progress sync (agent scope, release/acquire) ----
DEVINL void bump(u32* c) {
    __hip_atomic_fetch_add(c, 1u, __ATOMIC_RELEASE, __HIP_MEMORY_SCOPE_AGENT);
}
DEVINL void spin_ge(u32* c, u32 tgt) {
    while (__hip_atomic_load(c, __ATOMIC_ACQUIRE, __HIP_MEMORY_SCOPE_AGENT) < tgt)
        __builtin_amdgcn_s_sleep(2);
}

// ---------------------------------------------------------------------------
// Kernel 0: fp32 -> bf16 convert pass
// ---------------------------------------------------------------------------
__global__ __launch_bounds__(256) void convert_kernel(
    const float* __restrict__ x, const float* __restrict__ Wq,
    const float* __restrict__ Wk, const float* __restrict__ Wv,
    const float* __restrict__ Wo, const float* __restrict__ Wlr,
    const float* __restrict__ Wbeta,
    u16* __restrict__ xb, u16* __restrict__ wb, u16* __restrict__ wob,
    u16* __restrict__ wlb)
{
    const int t0 = blockIdx.x * 256 + threadIdx.x;
    const int stride = gridDim.x * 256;
    auto cv = [&](const float* src, u16* dst, int n4) {
        for (int i = t0; i < n4; i += stride) {
            float4 v = ((const float4*)src)[i];
            uint2 p;
            p.x = pk2(v.x, v.y);
            p.y = pk2(v.z, v.w);
            ((uint2*)dst)[i] = p;
        }
    };
    cv(x, xb, 4194304);
    cv(Wq, wb, 262144);
    cv(Wk, wb + 1048576, 262144);
    cv(Wv, wb + 2097152, 262144);
    cv(Wo, wob, 262144);
    cv(Wlr, wlb, 8192);
    cv(Wbeta, wlb + 32768, 8192);
}

// ---------------------------------------------------------------------------
// Kernel A+B fused: blocks [0,3072): q/k/v projections (progress -> prog2);
//                   blocks [3072,3200): lr/wd heads + chunk means (-> prog3)
// ---------------------------------------------------------------------------
__global__ __launch_bounds__(256) void proj_fused_kernel(
    const u16* __restrict__ xb, const u16* __restrict__ wb,
    const u16* __restrict__ wlb,
    u16* __restrict__ qb, u16* __restrict__ kb, u16* __restrict__ vb,
    float* __restrict__ lrc_all, u32* __restrict__ prog2, u32* __restrict__ prog3)
{
    __shared__ __align__(16) char As[128 * 128];
    __shared__ __align__(16) char Bs[128 * 128];
    __shared__ float acc2[2][64];
    const int bid = blockIdx.x;
    const int tid = threadIdx.x;
    const int lane = tid & 63;
    const int wv = tid >> 6;
    const int li = lane & 15, g = lane >> 4;
    const int lr8 = lane >> 3, lc8 = lane & 7;

    if (bid < 3072) {
        // ================= proj path =================
        const int bn = bid % 24;
        const int bm = bid / 24;
        const int wsel = bn >> 3;
        u16* __restrict__ dst = (wsel == 0) ? qb : ((wsel == 1) ? kb : vb);
        const int cb = (bn & 7) * 128;
        const int wrow = bn * 128;
        const int rb = bm * 128;
        const int wr = (wv >> 1) * 64, wc = (wv & 1) * 64;

        f32x4 acc[4][4];
#pragma unroll
        for (int i = 0; i < 4; ++i)
#pragma unroll
            for (int j = 0; j < 4; ++j) acc[i][j] = (f32x4)0.0f;

        for (int k0 = 0; k0 < 1024; k0 += 64) {
            __syncthreads();
#pragma unroll
            for (int ld = 0; ld < 4; ++ld) {
                int r0 = wv * 32 + ld * 8;
                gload_lds16(xb + (size_t)(rb + r0 + lr8) * 1024 + k0 + lc8 * 8, As + r0 * 128);
                gload_lds16(wb + (size_t)(wrow + r0 + lr8) * 1024 + k0 + lc8 * 8, Bs + r0 * 128);
            }
            __syncthreads();
#pragma unroll
            for (int ks = 0; ks < 2; ++ks) {
                bf16x8 af[4], bfr[4];
#pragma unroll
                for (int m = 0; m < 4; ++m)
                    af[m] = *(const bf16x8*)(As + (wr + m * 16 + li) * 128 + ks * 64 + g * 16);
#pragma unroll
                for (int n = 0; n < 4; ++n)
                    bfr[n] = *(const bf16x8*)(Bs + (wc + n * 16 + li) * 128 + ks * 64 + g * 16);
#pragma unroll
                for (int m = 0; m < 4; ++m)
#pragma unroll
                    for (int n = 0; n < 4; ++n)
                        acc[m][n] = __builtin_amdgcn_mfma_f32_16x16x32_bf16(af[m], bfr[n], acc[m][n], 0, 0, 0);
            }
        }
        const bool do_silu = (wsel < 2);
#pragma unroll
        for (int m = 0; m < 4; ++m) {
            int t = rb + wr + m * 16 + g * 4;
#pragma unroll
            for (int r = 0; r < 4; ++r) {
#pragma unroll
                for (int n = 0; n < 4; ++n) {
                    float v = acc[m][n][r];
                    if (do_silu) v = v / (1.0f + __expf(-v));
                    int col = cb + wc + n * 16 + li;
                    dst[(size_t)(t + r) * 1024 + col] = f2bf(v);
                }
            }
        }
        __syncthreads();            // all waves' global stores drained at barrier
        if (tid == 0) bump(&prog2[bm]);
    } else {
        // ================= lrwd path =================
        const int bm2 = bid - 3072;          // 0..127
        const int rb = bm2 * 128;
        if (tid < 128) acc2[tid >> 6][tid & 63] = 0.f;

        f32x4 acc[2][4];
#pragma unroll
        for (int i = 0; i < 2; ++i)
#pragma unroll
            for (int j = 0; j < 4; ++j) acc[i][j] = (f32x4)0.0f;

        for (int k0 = 0; k0 < 1024; k0 += 64) {
            __syncthreads();
#pragma unroll
            for (int ld = 0; ld < 4; ++ld) {
                int r0 = wv * 32 + ld * 8;
                gload_lds16(xb + (size_t)(rb + r0 + lr8) * 1024 + k0 + lc8 * 8, As + r0 * 128);
            }
#pragma unroll
            for (int ld = 0; ld < 2; ++ld) {
                int r0 = wv * 16 + ld * 8;
                gload_lds16(wlb + (size_t)(r0 + lr8) * 1024 + k0 + lc8 * 8, Bs + r0 * 128);
            }
            __syncthreads();
#pragma unroll
            for (int ks = 0; ks < 2; ++ks) {
                bf16x8 af[2], bfr[4];
#pragma unroll
                for (int m = 0; m < 2; ++m)
                    af[m] = *(const bf16x8*)(As + (wv * 32 + m * 16 + li) * 128 + ks * 64 + g * 16);
#pragma unroll
                for (int n = 0; n < 4; ++n)
                    bfr[n] = *(const bf16x8*)(Bs + (n * 16 + li) * 128 + ks * 64 + g * 16);
#pragma unroll
                for (int m = 0; m < 2; ++m)
#pragma unroll
                    for (int n = 0; n < 4; ++n)
                        acc[m][n] = __builtin_amdgcn_mfma_f32_16x16x32_bf16(af[m], bfr[n], acc[m][n], 0, 0, 0);
            }
        }
        // per-chunk column sums: this thread's 8 tokens all lie in chunk wv>>1
        const int chunk = wv >> 1;
#pragma unroll
        for (int n = 0; n < 4; ++n) {
            int col = n * 16 + li;
            float scale = (col < 32) ? 1e-3f : 0.9f;
            float s = 0.f;
#pragma unroll
            for (int m = 0; m < 2; ++m)
#pragma unroll
                for (int r = 0; r < 4; ++r)
                    s += scale / (1.0f + __expf(-acc[m][n][r]));
            atomicAdd(&acc2[chunk][col], s);
        }
        __syncthreads();
        if (tid < 128) {
            int ch = tid >> 6, col = tid & 63;
            int b = bm2 >> 5;
            int cidx = (bm2 & 31) * 2 + ch;
            lrc_all[((size_t)(b * 64 + cidx)) * 64 + col] = acc2[ch][col] * (1.0f / 64.0f);
        }
        __syncthreads();
        if (tid == 0) bump(&prog3[bm2 >> 5]);
    }
}

// ---------------------------------------------------------------------------
// Kernel C: chunk scan — R5 dual-pipeline structure (355 us, verified), plus:
//   * acquire-spin on prog3 (lrc ready) and prog2 (q/k/v rows ready)
//   * release-bump of prog[b*64+c] after each chunk-end barrier
//   * packed o-store via trans4 (verified in R7)
// ---------------------------------------------------------------------------
__global__ __launch_bounds__(512) void scan_kernel(
    const u16* __restrict__ qb, const u16* __restrict__ kb, const u16* __restrict__ vb,
    const float* __restrict__ lrc_all, const float* __restrict__ Wi0,
    const float* __restrict__ Wo0, u16* __restrict__ ob,
    u32* __restrict__ prog, u32* __restrict__ prog2, u32* __restrict__ prog3)
{
    const int bh = blockIdx.x;
    const int b = bh >> 4, h = bh & 15;
    const int tid = threadIdx.x;
    const int lane = tid & 63;
    const int w8 = tid >> 6;            // 0..7
    const bool isA = (w8 < 4);
    const int wq = w8;                  // A-wave index (0..3) when isA
    const int wk = w8 - 4;              // B-wave index (0..3) when !isA
    const int li = lane & 15, g = lane >> 4;
    const int q4 = li & 3, b4 = li & 12;

    __shared__ __align__(16) char SQ2[2][8192];    // q   [n][d]
    __shared__ __align__(16) char Kc2[2][8192];    // k   [n][d]
    __shared__ __align__(16) char Vc2[2][8192];    // v   [n][d]
    __shared__ __align__(16) char KcT2[2][8192];   // k^T [d][n]
    __shared__ __align__(16) char VcT2[2][8192];   // v^T [d][n]
    __shared__ __align__(16) char SWoT2[2][8192];  // Wo^T[d][D] (dbuf: M3 reads cur)
    __shared__ __align__(16) char SWiN[8192];      // Wi  [D][d]
    __shared__ __align__(16) char SWoN[8192];      // Wo  [D][d]
    __shared__ __align__(16) char SPQ[8192];       // pq  [n][D]
    __shared__ __align__(16) char SPTN[8192];      // p^T [D][n]
    __shared__ __align__(16) char SGZN[8192];      // gz^T[D][n]
    __shared__ float spart[256];
    __shared__ float lrc[256];

    // ---- B-side state: fp32 regs (MFMA C-layout) + LDS mirrors ----
    f32x4 WiR[4], WoR[4];
    if (!isA) {
#pragma unroll
        for (int tn = 0; tn < 4; ++tn) {
            int d = tn * 16 + li;
#pragma unroll
            for (int r = 0; r < 4; ++r) {
                int D = wk * 16 + g * 4 + r;
                WiR[tn][r] = Wi0[((size_t)D * 16 + h) * 64 + d];
                WoR[tn][r] = Wo0[((size_t)D * 16 + h) * 64 + d];
            }
            *(uint2*)(SWoT2[0] + swz128(d, wk * 32 + g * 8)) =
                make_uint2(pk2(WoR[tn][0], WoR[tn][1]), pk2(WoR[tn][2], WoR[tn][3]));
            f32x4 ti = trans4(WiR[tn], q4);
            *(uint2*)(SWiN + swz128(wk * 16 + g * 4 + q4, tn * 32 + b4 * 2)) =
                make_uint2(pk2(ti[0], ti[1]), pk2(ti[2], ti[3]));
            f32x4 to = trans4(WoR[tn], q4);
            *(uint2*)(SWoN + swz128(wk * 16 + g * 4 + q4, tn * 32 + b4 * 2)) =
                make_uint2(pk2(to[0], to[1]), pk2(to[2], to[3]));
        }
    }
    if (tid < 256) {
        spin_ge(&prog3[b], 32);           // lrc_all rows for this b ready
        int cc = tid >> 2, j = tid & 3;
        lrc[cc * 4 + j] = lrc_all[((size_t)(b * 64 + cc)) * 64 + j * 16 + h];
    }

    // ---- A-side staging (verified commit math, 256 A-threads) ----
    const int nb4 = ((tid & 255) >> 4) * 4;
    const int db4 = (tid & 15) * 4;
    uint4 pq_[2];
    uint2 pk_[4], pv_[4];
    auto prefetch = [&](int c) {
        const size_t base = ((size_t)(b * 4096 + c * 64)) * 1024 + h * 64;
#pragma unroll
        for (int p = 0; p < 2; ++p) {
            int id = p * 256 + (tid & 255);
            int n = id >> 3;
            int d0 = (id & 7) * 8;
            pq_[p] = *(const uint4*)(qb + base + (size_t)n * 1024 + d0);
        }
#pragma unroll
        for (int j = 0; j < 4; ++j) {
            pk_[j] = *(const uint2*)(kb + base + (size_t)(nb4 + j) * 1024 + db4);
            pv_[j] = *(const uint2*)(vb + base + (size_t)(nb4 + j) * 1024 + db4);
        }
    };
    auto commit = [&](int buf) {
#pragma unroll
        for (int p = 0; p < 2; ++p) {
            int id = p * 256 + (tid & 255);
            int n = id >> 3;
            int d0 = (id & 7) * 8;
            *(uint4*)(SQ2[buf] + swz128(n, d0 * 2)) = pq_[p];
        }
#pragma unroll
        for (int j = 0; j < 4; ++j) {
            *(uint2*)(Kc2[buf] + swz128(nb4 + j, db4 * 2)) = pk_[j];
            *(uint2*)(Vc2[buf] + swz128(nb4 + j, db4 * 2)) = pv_[j];
        }
#pragma unroll
        for (int i = 0; i < 4; ++i) {
            u32 k0 = (((i & 2) ? pk_[0].y : pk_[0].x) >> ((i & 1) * 16)) & 0xffffu;
            u32 k1 = (((i & 2) ? pk_[1].y : pk_[1].x) >> ((i & 1) * 16)) & 0xffffu;
            u32 k2 = (((i & 2) ? pk_[2].y : pk_[2].x) >> ((i & 1) * 16)) & 0xffffu;
            u32 k3 = (((i & 2) ? pk_[3].y : pk_[3].x) >> ((i & 1) * 16)) & 0xffffu;
            *(uint2*)(KcT2[buf] + swz128(db4 + i, nb4 * 2)) =
                make_uint2(k0 | (k1 << 16), k2 | (k3 << 16));
            u32 v0 = (((i & 2) ? pv_[0].y : pv_[0].x) >> ((i & 1) * 16)) & 0xffffu;
            u32 v1 = (((i & 2) ? pv_[1].y : pv_[1].x) >> ((i & 1) * 16)) & 0xffffu;
            u32 v2 = (((i & 2) ? pv_[2].y : pv_[2].x) >> ((i & 1) * 16)) & 0xffffu;
            u32 v3 = (((i & 2) ? pv_[3].y : pv_[3].x) >> ((i & 1) * 16)) & 0xffffu;
            *(uint2*)(VcT2[buf] + swz128(db4 + i, nb4 * 2)) =
                make_uint2(v0 | (v1 << 16), v2 | (v3 << 16));
        }
    };

    if (isA) {
        spin_ge(&prog2[b * 32], 24);      // q/k/v rows for chunks 0-1 ready
        prefetch(0);
        commit(0);
    }
    __syncthreads();

    for (int c = 0; c < 64; ++c) {
        const int cur = c & 1, nxt = cur ^ 1;
        f32x4 pk[4], aT[4], go[4];          // B-side live values

        if (isA) {
            // ================= A pipeline: M1 + softmax + SPQ =================
            if (c + 1 < 64) {
                spin_ge(&prog2[b * 32 + ((c + 1) >> 1)], 24);
                prefetch(c + 1);
            }
            bf16x8 wiA0 = *(const bf16x8*)(SWiN + swz128(wq * 16 + li, g * 16));
            bf16x8 wiA1 = *(const bf16x8*)(SWiN + swz128(wq * 16 + li, 64 + g * 16));
            f32x4 sq[4];
#pragma unroll
            for (int tn = 0; tn < 4; ++tn) {
                bf16x8 b0 = *(const bf16x8*)(SQ2[cur] + swz128(tn * 16 + li, g * 16));
                bf16x8 b1 = *(const bf16x8*)(SQ2[cur] + swz128(tn * 16 + li, 64 + g * 16));
                f32x4 z = (f32x4)0.0f;
                z = __builtin_amdgcn_mfma_f32_16x16x32_bf16(wiA0, b0, z, 0, 0, 0);
                z = __builtin_amdgcn_mfma_f32_16x16x32_bf16(wiA1, b1, z, 0, 0, 0);
                sq[tn] = z;
            }
#pragma unroll
            for (int r = 0; r < 4; ++r) {
                float m = fmaxf(fmaxf(sq[0][r], sq[1][r]), fmaxf(sq[2][r], sq[3][r]));
                m = fmaxf(m, __shfl_xor(m, 1)); m = fmaxf(m, __shfl_xor(m, 2));
                m = fmaxf(m, __shfl_xor(m, 4)); m = fmaxf(m, __shfl_xor(m, 8));
                float e0 = __expf(sq[0][r] - m), e1 = __expf(sq[1][r] - m);
                float e2 = __expf(sq[2][r] - m), e3 = __expf(sq[3][r] - m);
                float s = e0 + e1 + e2 + e3;
                s += __shfl_xor(s, 1); s += __shfl_xor(s, 2);
                s += __shfl_xor(s, 4); s += __shfl_xor(s, 8);
                float inv = 1.0f / s;
                sq[0][r] = e0 * inv; sq[1][r] = e1 * inv; sq[2][r] = e2 * inv; sq[3][r] = e3 * inv;
            }
#pragma unroll
            for (int tn = 0; tn < 4; ++tn) {
                int n = tn * 16 + li;
                *(uint2*)(SPQ + swz128(n, (wq * 16 + g * 4) * 2)) =
                    make_uint2(pk2(sq[tn][0], sq[tn][1]), pk2(sq[tn][2], sq[tn][3]));
            }
        } else {
            // ============== B pipeline: M2 + softmax + M4' + spart + SPTN + M5 ==============
            bf16x8 wiA0 = *(const bf16x8*)(SWiN + swz128(wk * 16 + li, g * 16));
            bf16x8 wiA1 = *(const bf16x8*)(SWiN + swz128(wk * 16 + li, 64 + g * 16));
            __builtin_amdgcn_s_setprio(1);
#pragma unroll
            for (int tn = 0; tn < 4; ++tn) {
                bf16x8 b0 = *(const bf16x8*)(Kc2[cur] + swz128(tn * 16 + li, g * 16));
                bf16x8 b1 = *(const bf16x8*)(Kc2[cur] + swz128(tn * 16 + li, 64 + g * 16));
                f32x4 z = (f32x4)0.0f;
                z = __builtin_amdgcn_mfma_f32_16x16x32_bf16(wiA0, b0, z, 0, 0, 0);
                z = __builtin_amdgcn_mfma_f32_16x16x32_bf16(wiA1, b1, z, 0, 0, 0);
                pk[tn] = z;
            }
            __builtin_amdgcn_s_setprio(0);
#pragma unroll
            for (int r = 0; r < 4; ++r) {
                float m = fmaxf(fmaxf(pk[0][r], pk[1][r]), fmaxf(pk[2][r], pk[3][r]));
                m = fmaxf(m, __shfl_xor(m, 1)); m = fmaxf(m, __shfl_xor(m, 2));
                m = fmaxf(m, __shfl_xor(m, 4)); m = fmaxf(m, __shfl_xor(m, 8));
                float e0 = __expf(pk[0][r] - m), e1 = __expf(pk[1][r] - m);
                float e2 = __expf(pk[2][r] - m), e3 = __expf(pk[3][r] - m);
                float s = e0 + e1 + e2 + e3;
                s += __shfl_xor(s, 1); s += __shfl_xor(s, 2);
                s += __shfl_xor(s, 4); s += __shfl_xor(s, 8);
                float inv = 1.0f / s;
                pk[0][r] = e0 * inv; pk[1][r] = e1 * inv; pk[2][r] = e2 * inv; pk[3][r] = e3 * inv;
            }
            bf16x8 woA0 = *(const bf16x8*)(SWoN + swz128(wk * 16 + li, g * 16));
            bf16x8 woA1 = *(const bf16x8*)(SWoN + swz128(wk * 16 + li, 64 + g * 16));
            __builtin_amdgcn_s_setprio(1);
#pragma unroll
            for (int tn = 0; tn < 4; ++tn) {
                bf16x8 b0 = *(const bf16x8*)(Vc2[cur] + swz128(tn * 16 + li, g * 16));
                bf16x8 b1 = *(const bf16x8*)(Vc2[cur] + swz128(tn * 16 + li, 64 + g * 16));
                f32x4 z = (f32x4)0.0f;
                z = __builtin_amdgcn_mfma_f32_16x16x32_bf16(woA0, b0, z, 0, 0, 0);
                z = __builtin_amdgcn_mfma_f32_16x16x32_bf16(woA1, b1, z, 0, 0, 0);
                aT[tn] = z;
            }
            __builtin_amdgcn_s_setprio(0);
#pragma unroll
            for (int tn = 0; tn < 4; ++tn) {
                f32x4 t4 = pk[tn] * aT[tn];
                float s_ = t4[0] + t4[1] + t4[2] + t4[3];
                s_ += __shfl_xor(s_, 16);
                s_ += __shfl_xor(s_, 32);
                if (g == 0) spart[wk * 64 + tn * 16 + li] = s_;
            }
            // SPTN (wave-local rows) then M5 immediately (go)
#pragma unroll
            for (int tn = 0; tn < 4; ++tn) {
                f32x4 tp = trans4(pk[tn], q4);
                *(uint2*)(SPTN + swz128(wk * 16 + g * 4 + q4, tn * 32 + b4 * 2)) =
                    make_uint2(pk2(tp[0], tp[1]), pk2(tp[2], tp[3]));
            }
            {
                bf16x8 a0 = *(const bf16x8*)(SPTN + swz128(wk * 16 + li, g * 16));
                bf16x8 a1 = *(const bf16x8*)(SPTN + swz128(wk * 16 + li, 64 + g * 16));
                __builtin_amdgcn_s_setprio(1);
#pragma unroll
                for (int tn = 0; tn < 4; ++tn) {
                    bf16x8 b0 = *(const bf16x8*)(VcT2[cur] + swz128(tn * 16 + li, g * 16));
                    bf16x8 b1 = *(const bf16x8*)(VcT2[cur] + swz128(tn * 16 + li, 64 + g * 16));
                    f32x4 z = (f32x4)0.0f;
                    z = __builtin_amdgcn_mfma_f32_16x16x32_bf16(a0, b0, z, 0, 0, 0);
                    z = __builtin_amdgcn_mfma_f32_16x16x32_bf16(a1, b1, z, 0, 0, 0);
                    go[tn] = z;
                }
                __builtin_amdgcn_s_setprio(0);
            }
        }
        __syncthreads();   // B1: spart + SPQ visible

        if (isA) {
            // ================= A: M3 + packed o store + commit(c+1) =================
            bf16x8 a0 = *(const bf16x8*)(SPQ + swz128(wq * 16 + li, g * 16));
            bf16x8 a1 = *(const bf16x8*)(SPQ + swz128(wq * 16 + li, 64 + g * 16));
            f32x4 o4[4];
#pragma unroll
            for (int tn = 0; tn < 4; ++tn) {
                bf16x8 b0 = *(const bf16x8*)(SWoT2[cur] + swz128(tn * 16 + li, g * 16));
                bf16x8 b1 = *(const bf16x8*)(SWoT2[cur] + swz128(tn * 16 + li, 64 + g * 16));
                f32x4 z = (f32x4)0.0f;
                z = __builtin_amdgcn_mfma_f32_16x16x32_bf16(a0, b0, z, 0, 0, 0);
                z = __builtin_amdgcn_mfma_f32_16x16x32_bf16(a1, b1, z, 0, 0, 0);
                o4[tn] = z;
            }
            const size_t obase = ((size_t)(b * 4096 + c * 64)) * 1024 + h * 64;
            const int n_ = wq * 16 + g * 4 + q4;
#pragma unroll
            for (int tn = 0; tn < 4; ++tn) {
                f32x4 to = trans4(o4[tn], q4);
                *(uint2*)(ob + obase + (size_t)n_ * 1024 + tn * 16 + b4) =
                    make_uint2(pk2(to[0], to[1]), pk2(to[2], to[3]));
            }
            if (c + 1 < 64) commit(nxt);
        } else {
            // ================= B: gz + SGZN + M6 + state update =================
            f32x4 gz[4];
#pragma unroll
            for (int tn = 0; tn < 4; ++tn) {
                int n = tn * 16 + li;
                float sn = spart[n] + spart[64 + n] + spart[128 + n] + spart[192 + n];
#pragma unroll
                for (int r = 0; r < 4; ++r) gz[tn][r] = pk[tn][r] * (sn - aT[tn][r]);
                f32x4 tg = trans4(gz[tn], q4);
                *(uint2*)(SGZN + swz128(wk * 16 + g * 4 + q4, tn * 32 + b4 * 2)) =
                    make_uint2(pk2(tg[0], tg[1]), pk2(tg[2], tg[3]));
            }
            f32x4 gi[4];
            {
                bf16x8 a0 = *(const bf16x8*)(SGZN + swz128(wk * 16 + li, g * 16));
                bf16x8 a1 = *(const bf16x8*)(SGZN + swz128(wk * 16 + li, 64 + g * 16));
                __builtin_amdgcn_s_setprio(1);
#pragma unroll
                for (int tn = 0; tn < 4; ++tn) {
                    bf16x8 b0 = *(const bf16x8*)(KcT2[cur] + swz128(tn * 16 + li, g * 16));
                    bf16x8 b1 = *(const bf16x8*)(KcT2[cur] + swz128(tn * 16 + li, 64 + g * 16));
                    f32x4 z = (f32x4)0.0f;
                    z = __builtin_amdgcn_mfma_f32_16x16x32_bf16(a0, b0, z, 0, 0, 0);
                    z = __builtin_amdgcn_mfma_f32_16x16x32_bf16(a1, b1, z, 0, 0, 0);
                    gi[tn] = z;
                }
                __builtin_amdgcn_s_setprio(0);
            }
            if (c + 1 < 64) {
                float lin = lrc[c * 4 + 0], lout = lrc[c * 4 + 1];
                float win = lrc[c * 4 + 2], wout = lrc[c * 4 + 3];
#pragma unroll
                for (int tn = 0; tn < 4; ++tn) {
                    WiR[tn] = win * WiR[tn] - lin * gi[tn];
                    WoR[tn] = wout * WoR[tn] + lout * go[tn];   // grad_out = -go
                    int d = tn * 16 + li;
                    *(uint2*)(SWoT2[nxt] + swz128(d, wk * 32 + g * 8)) =
                        make_uint2(pk2(WoR[tn][0], WoR[tn][1]), pk2(WoR[tn][2], WoR[tn][3]));
                    f32x4 ti = trans4(WiR[tn], q4);
                    *(uint2*)(SWiN + swz128(wk * 16 + g * 4 + q4, tn * 32 + b4 * 2)) =
                        make_uint2(pk2(ti[0], ti[1]), pk2(ti[2], ti[3]));
                    f32x4 to = trans4(WoR[tn], q4);
                    *(uint2*)(SWoN + swz128(wk * 16 + g * 4 + q4, tn * 32 + b4 * 2)) =
                        make_uint2(pk2(to[0], to[1]), pk2(to[2], to[3]));
                }
            }
        }
        __syncthreads();   // Bend: tiles(c+1) + state(c+1) visible; stores drained
        if (tid == 0) bump(&prog[b * 64 + c]);
    }
}

// ---------------------------------------------------------------------------
// Kernel D: out[t][m] = sum_j o[t][j] * Wo[m][j]
// Spins (acquire) until scan has produced its two chunks from all 16 heads.
// ---------------------------------------------------------------------------
__global__ __launch_bounds__(256) void out_proj_kernel(
    const u16* __restrict__ ob, const u16* __restrict__ wob, float* __restrict__ out,
    u32* __restrict__ prog)
{
    __shared__ __align__(16) char As[128 * 128];
    __shared__ __align__(16) char Bs[128 * 128];
    const int bn = blockIdx.x;
    const int bm = blockIdx.y;
    const int cb = bn * 128;
    const int rb = bm * 128;
    const int tid = threadIdx.x;
    const int lane = tid & 63;
    const int wv = tid >> 6;
    const int wr = (wv >> 1) * 64, wc = (wv & 1) * 64;
    const int li = lane & 15, g = lane >> 4;
    const int lr8 = lane >> 3, lc8 = lane & 7;

    {
        const int b = bm >> 5;
        const int c0 = (bm & 31) * 2;
        spin_ge(&prog[b * 64 + c0], 16);
        spin_ge(&prog[b * 64 + c0 + 1], 16);
    }

    f32x4 acc[4][4];
#pragma unroll
    for (int i = 0; i < 4; ++i)
#pragma unroll
        for (int j = 0; j < 4; ++j) acc[i][j] = (f32x4)0.0f;

    for (int k0 = 0; k0 < 1024; k0 += 64) {
        __syncthreads();
#pragma unroll
        for (int ld = 0; ld < 4; ++ld) {
            int r0 = wv * 32 + ld * 8;
            gload_lds16(ob + (size_t)(rb + r0 + lr8) * 1024 + k0 + lc8 * 8, As + r0 * 128);
            gload_lds16(wob + (size_t)(cb + r0 + lr8) * 1024 + k0 + lc8 * 8, Bs + r0 * 128);
        }
        __syncthreads();
#pragma unroll
        for (int ks = 0; ks < 2; ++ks) {
            bf16x8 af[4], bfr[4];
#pragma unroll
            for (int m = 0; m < 4; ++m)
                af[m] = *(const bf16x8*)(As + (wr + m * 16 + li) * 128 + ks * 64 + g * 16);
#pragma unroll
            for (int n = 0; n < 4; ++n)
                bfr[n] = *(const bf16x8*)(Bs + (wc + n * 16 + li) * 128 + ks * 64 + g * 16);
#pragma unroll
            for (int m = 0; m < 4; ++m)
#pragma unroll
                for (int n = 0; n < 4; ++n)
                    acc[m][n] = __builtin_amdgcn_mfma_f32_16x16x32_bf16(af[m], bfr[n], acc[m][n], 0, 0, 0);
        }
    }
#pragma unroll
    for (int m = 0; m < 4; ++m) {
        int t = rb + wr + m * 16 + g * 4;
#pragma unroll
        for (int r = 0; r < 4; ++r) {
#pragma unroll
            for (int n = 0; n < 4; ++n) {
                int col = cb + wc + n * 16 + li;
                out[(size_t)(t + r) * 1024 + col] = acc[m][n][r];
            }
        }
    }
}

// ---------------------------------------------------------------------------
extern "C" void kernel_launch(void* const* d_in, const int* in_sizes, int n_in,
                              void* d_out, int out_size, void* d_ws, size_t ws_size,
                              hipStream_t stream)
{
    const float* x     = (const float*)d_in[0];
    const float* Wq    = (const float*)d_in[1];
    const float* Wk    = (const float*)d_in[2];
    const float* Wv    = (const float*)d_in[3];
    const float* Wlr   = (const float*)d_in[4];
    const float* Wbeta = (const float*)d_in[5];
    const float* Wo    = (const float*)d_in[6];
    const float* Wi0   = (const float*)d_in[7];
    const float* Wo0   = (const float*)d_in[8];
    float* out = (float*)d_out;

    // d_out scratch (dead before out_proj writes): xb, wb, wlb, lrc_all
    char* od = (char*)d_out;
    u16* xb       = (u16*)(od);                    // 33,554,432 B
    u16* wb       = (u16*)(od + 33554432u);        //  6,291,456 B
    u16* wlb      = (u16*)(od + 39845888u);        //    131,072 B
    float* lrc_all = (float*)(od + 41943040u);     //     65,536 B  (< 64 MB)

    char* ws = (char*)d_ws;
    u16* qb   = (u16*)(ws);
    u16* kb   = (u16*)(ws + 33554432u);
    u16* vb   = (u16*)(ws + 67108864u);
    u16* obuf = (u16*)(ws + 100663296u);
    u32* prog  = (u32*)(ws + 134217728u);          // 256 cells: scan -> out_proj
    u32* prog2 = prog + 256;                       // 128 cells: proj -> scan
    u32* prog3 = prog + 384;                       //   4 cells: lrwd -> scan
    u16* wob  = (u16*)(ws + 134283264u);
    if (ws_size < 136380416u) return;

    hipMemsetAsync(prog, 0, 2048, stream);
    convert_kernel<<<2048, 256, 0, stream>>>(x, Wq, Wk, Wv, Wo, Wlr, Wbeta,
                                             xb, wb, wob, wlb);
    proj_fused_kernel<<<3200, 256, 0, stream>>>(xb, wb, wlb, qb, kb, vb,
                                                lrc_all, prog2, prog3);
    scan_kernel<<<64, 512, 0, stream>>>(qb, kb, vb, lrc_all, Wi0, Wo0, obuf,
                                        prog, prog2, prog3);
    out_proj_kernel<<<dim3(8, 128), 256, 0, stream>>>(obuf, wob, out, prog);
}

// Round 9
// 602.782 us; speedup vs baseline: 1.3336x; 1.3336x over previous
//
#include <hip/hip_runtime.h>
#include <stdint.h>

typedef unsigned short u16;
typedef uint32_t u32;
typedef __attribute__((ext_vector_type(4))) float f32x4;
typedef __attribute__((ext_vector_type(8))) short bf16x8;

#define DEVINL __device__ __forceinline__

DEVINL u16 f2bf(float f) {
    union { float f; u32 u; } a; a.f = f;
    u32 u = a.u;
    return (u16)((u + 0x7fffu + ((u >> 16) & 1u)) >> 16);   // RNE
}
DEVINL u32 pk2(float a, float b) { return (u32)f2bf(a) | ((u32)f2bf(b) << 16); }

// 128B-row swizzled tile (conflict-free vector row reads) — verified R2..R8
DEVINL u32 swz128(u32 row, u32 colb) { return row * 128u + (colb ^ ((row & 7u) << 4)); }

// async global->LDS, 16B per lane
DEVINL void gload_lds16(const u16* g, char* l) {
    __builtin_amdgcn_global_load_lds(
        (const __attribute__((address_space(1))) void*)g,
        (__attribute__((address_space(3))) void*)l, 16, 0, 0);
}

// 4x4 transpose among 4 lanes (lane&3) over the 4 regs of v (R4-verified)
DEVINL f32x4 trans4(f32x4 v, int q) {
    float s0 = __shfl_xor(v[0], 1), s1 = __shfl_xor(v[1], 1),
          s2 = __shfl_xor(v[2], 1), s3 = __shfl_xor(v[3], 1);
    f32x4 t;
    bool q1 = (q & 1) != 0;
    t[0] = q1 ? s1 : v[0];
    t[1] = q1 ? v[1] : s0;
    t[2] = q1 ? s3 : v[2];
    t[3] = q1 ? v[3] : s2;
    float u0 = __shfl_xor(t[0], 2), u1 = __shfl_xor(t[1], 2),
          u2 = __shfl_xor(t[2], 2), u3 = __shfl_xor(t[3], 2);
    f32x4 r;
    bool q2 = (q & 2) != 0;
    r[0] = q2 ? u2 : t[0];
    r[1] = q2 ? u3 : t[1];
    r[2] = q2 ? t[2] : u0;
    r[3] = q2 ? t[3] : u1;
    return r;
}

// ---------------------------------------------------------------------------
// Kernel 0: fp32 -> bf16 convert pass
// ---------------------------------------------------------------------------
__global__ __launch_bounds__(256) void convert_kernel(
    const float* __restrict__ x, const float* __restrict__ Wq,
    const float* __restrict__ Wk, const float* __restrict__ Wv,
    const float* __restrict__ Wo, const float* __restrict__ Wlr,
    const float* __restrict__ Wbeta,
    u16* __restrict__ xb, u16* __restrict__ wb, u16* __restrict__ wob,
    u16* __restrict__ wlb)
{
    const int t0 = blockIdx.x * 256 + threadIdx.x;
    const int stride = gridDim.x * 256;
    auto cv = [&](const float* src, u16* dst, int n4) {
        for (int i = t0; i < n4; i += stride) {
            float4 v = ((const float4*)src)[i];
            uint2 p;
            p.x = pk2(v.x, v.y);
            p.y = pk2(v.z, v.w);
            ((uint2*)dst)[i] = p;
        }
    };
    cv(x, xb, 4194304);
    cv(Wq, wb, 262144);
    cv(Wk, wb + 1048576, 262144);
    cv(Wv, wb + 2097152, 262144);
    cv(Wo, wob, 262144);
    cv(Wlr, wlb, 8192);
    cv(Wbeta, wlb + 32768, 8192);
}

// ---------------------------------------------------------------------------
// Kernel A: q/k/v projections (bf16 in, bf16 out, fused silu for q,k)
// ---------------------------------------------------------------------------
__global__ __launch_bounds__(256) void proj_qkv_kernel(
    const u16* __restrict__ xb, const u16* __restrict__ wb,
    u16* __restrict__ qb, u16* __restrict__ kb, u16* __restrict__ vb)
{
    __shared__ __align__(16) char As[128 * 128];
    __shared__ __align__(16) char Bs[128 * 128];
    const int bn = blockIdx.x;
    const int bm = blockIdx.y;
    const int wsel = bn >> 3;
    u16* __restrict__ dst = (wsel == 0) ? qb : ((wsel == 1) ? kb : vb);
    const int cb = (bn & 7) * 128;
    const int wrow = bn * 128;
    const int rb = bm * 128;
    const int tid = threadIdx.x;
    const int lane = tid & 63;
    const int wv = tid >> 6;
    const int wr = (wv >> 1) * 64, wc = (wv & 1) * 64;
    const int li = lane & 15, g = lane >> 4;
    const int lr8 = lane >> 3, lc8 = lane & 7;

    f32x4 acc[4][4];
#pragma unroll
    for (int i = 0; i < 4; ++i)
#pragma unroll
        for (int j = 0; j < 4; ++j) acc[i][j] = (f32x4)0.0f;

    for (int k0 = 0; k0 < 1024; k0 += 64) {
        __syncthreads();
#pragma unroll
        for (int ld = 0; ld < 4; ++ld) {
            int r0 = wv * 32 + ld * 8;
            gload_lds16(xb + (size_t)(rb + r0 + lr8) * 1024 + k0 + lc8 * 8, As + r0 * 128);
            gload_lds16(wb + (size_t)(wrow + r0 + lr8) * 1024 + k0 + lc8 * 8, Bs + r0 * 128);
        }
        __syncthreads();
#pragma unroll
        for (int ks = 0; ks < 2; ++ks) {
            bf16x8 af[4], bfr[4];
#pragma unroll
            for (int m = 0; m < 4; ++m)
                af[m] = *(const bf16x8*)(As + (wr + m * 16 + li) * 128 + ks * 64 + g * 16);
#pragma unroll
            for (int n = 0; n < 4; ++n)
                bfr[n] = *(const bf16x8*)(Bs + (wc + n * 16 + li) * 128 + ks * 64 + g * 16);
#pragma unroll
            for (int m = 0; m < 4; ++m)
#pragma unroll
                for (int n = 0; n < 4; ++n)
                    acc[m][n] = __builtin_amdgcn_mfma_f32_16x16x32_bf16(af[m], bfr[n], acc[m][n], 0, 0, 0);
        }
    }
    const bool do_silu = (wsel < 2);
#pragma unroll
    for (int m = 0; m < 4; ++m) {
        int t = rb + wr + m * 16 + g * 4;
#pragma unroll
        for (int r = 0; r < 4; ++r) {
#pragma unroll
            for (int n = 0; n < 4; ++n) {
                float v = acc[m][n][r];
                if (do_silu) v = v / (1.0f + __expf(-v));
                int col = cb + wc + n * 16 + li;
                dst[(size_t)(t + r) * 1024 + col] = f2bf(v);
            }
        }
    }
}

// ---------------------------------------------------------------------------
// Kernel B: lr/wd heads as MFMA GEMM + on-chip per-chunk mean
// ---------------------------------------------------------------------------
__global__ __launch_bounds__(256) void lrwd_kernel(
    const u16* __restrict__ xb, const u16* __restrict__ wlb,
    float* __restrict__ lrc_all)
{
    __shared__ __align__(16) char As[128 * 128];
    __shared__ __align__(16) char Bs[64 * 128];
    __shared__ float red[128][65];
    const int bm = blockIdx.x;
    const int rb = bm * 128;
    const int tid = threadIdx.x;
    const int lane = tid & 63;
    const int wv = tid >> 6;
    const int li = lane & 15, g = lane >> 4;
    const int lr8 = lane >> 3, lc8 = lane & 7;

    f32x4 acc[2][4];
#pragma unroll
    for (int i = 0; i < 2; ++i)
#pragma unroll
        for (int j = 0; j < 4; ++j) acc[i][j] = (f32x4)0.0f;

    for (int k0 = 0; k0 < 1024; k0 += 64) {
        __syncthreads();
#pragma unroll
        for (int ld = 0; ld < 4; ++ld) {
            int r0 = wv * 32 + ld * 8;
            gload_lds16(xb + (size_t)(rb + r0 + lr8) * 1024 + k0 + lc8 * 8, As + r0 * 128);
        }
#pragma unroll
        for (int ld = 0; ld < 2; ++ld) {
            int r0 = wv * 16 + ld * 8;
            gload_lds16(wlb + (size_t)(r0 + lr8) * 1024 + k0 + lc8 * 8, Bs + r0 * 128);
        }
        __syncthreads();
#pragma unroll
        for (int ks = 0; ks < 2; ++ks) {
            bf16x8 af[2], bfr[4];
#pragma unroll
            for (int m = 0; m < 2; ++m)
                af[m] = *(const bf16x8*)(As + (wv * 32 + m * 16 + li) * 128 + ks * 64 + g * 16);
#pragma unroll
            for (int n = 0; n < 4; ++n)
                bfr[n] = *(const bf16x8*)(Bs + (n * 16 + li) * 128 + ks * 64 + g * 16);
#pragma unroll
            for (int m = 0; m < 2; ++m)
#pragma unroll
                for (int n = 0; n < 4; ++n)
                    acc[m][n] = __builtin_amdgcn_mfma_f32_16x16x32_bf16(af[m], bfr[n], acc[m][n], 0, 0, 0);
        }
    }
#pragma unroll
    for (int m = 0; m < 2; ++m) {
#pragma unroll
        for (int n = 0; n < 4; ++n) {
            int col = n * 16 + li;
            float scale = (col < 32) ? 1e-3f : 0.9f;
#pragma unroll
            for (int r = 0; r < 4; ++r) {
                int t = wv * 32 + m * 16 + g * 4 + r;
                float s = acc[m][n][r];
                red[t][col] = scale / (1.0f + __expf(-s));
            }
        }
    }
    __syncthreads();
    if (tid < 128) {
        int chunk = tid >> 6, col = tid & 63;
        float s = 0.f;
#pragma unroll
        for (int i = 0; i < 64; ++i) s += red[chunk * 64 + i][col];
        int b = bm >> 5;
        int cidx = (bm & 31) * 2 + chunk;
        lrc_all[((size_t)(b * 64 + cidx)) * 64 + col] = s * (1.0f / 64.0f);
    }
}

// ---------------------------------------------------------------------------
// Kernel C: chunk scan — R5 dual-pipeline (355us verified) with:
//   * mid-chunk full barrier replaced by GROUP-LOCAL spin syncs (cntA / cntB)
//     — audit: mid-chunk A needs only A-waves' SPQ; B needs only B-waves'
//     spart; all A<->B edges covered by the chunk-end full barrier.
//   * packed b64 o-store via trans4 (R7-verified)
//   * setprio around A-side MFMA clusters (T5)
// ---------------------------------------------------------------------------
__global__ __launch_bounds__(512) void scan_kernel(
    const u16* __restrict__ qb, const u16* __restrict__ kb, const u16* __restrict__ vb,
    const float* __restrict__ lrc_all, const float* __restrict__ Wi0,
    const float* __restrict__ Wo0, u16* __restrict__ ob)
{
    const int bh = blockIdx.x;
    const int b = bh >> 4, h = bh & 15;
    const int tid = threadIdx.x;
    const int lane = tid & 63;
    const int w8 = tid >> 6;            // 0..7
    const bool isA = (w8 < 4);
    const int wq = w8;                  // A-wave index (0..3) when isA
    const int wk = w8 - 4;              // B-wave index (0..3) when !isA
    const int li = lane & 15, g = lane >> 4;
    const int q4 = li & 3, b4 = li & 12;

    __shared__ __align__(16) char SQ2[2][8192];    // q   [n][d]
    __shared__ __align__(16) char Kc2[2][8192];    // k   [n][d]
    __shared__ __align__(16) char Vc2[2][8192];    // v   [n][d]
    __shared__ __align__(16) char KcT2[2][8192];   // k^T [d][n]
    __shared__ __align__(16) char VcT2[2][8192];   // v^T [d][n]
    __shared__ __align__(16) char SWoT2[2][8192];  // Wo^T[d][D]
    __shared__ __align__(16) char SWiN[8192];      // Wi  [D][d]
    __shared__ __align__(16) char SWoN[8192];      // Wo  [D][d]
    __shared__ __align__(16) char SPQ[8192];       // pq  [n][D]
    __shared__ __align__(16) char SPTN[8192];      // p^T [D][n]
    __shared__ __align__(16) char SGZN[8192];      // gz^T[D][n]
    __shared__ float spart[256];
    __shared__ float lrc[256];
    __shared__ u32 cntA, cntB;

    if (tid == 0) { cntA = 0u; cntB = 0u; }

    // ---- B-side state: fp32 regs (MFMA C-layout) + LDS mirrors ----
    f32x4 WiR[4], WoR[4];
    if (!isA) {
#pragma unroll
        for (int tn = 0; tn < 4; ++tn) {
            int d = tn * 16 + li;
#pragma unroll
            for (int r = 0; r < 4; ++r) {
                int D = wk * 16 + g * 4 + r;
                WiR[tn][r] = Wi0[((size_t)D * 16 + h) * 64 + d];
                WoR[tn][r] = Wo0[((size_t)D * 16 + h) * 64 + d];
            }
            *(uint2*)(SWoT2[0] + swz128(d, wk * 32 + g * 8)) =
                make_uint2(pk2(WoR[tn][0], WoR[tn][1]), pk2(WoR[tn][2], WoR[tn][3]));
            f32x4 ti = trans4(WiR[tn], q4);
            *(uint2*)(SWiN + swz128(wk * 16 + g * 4 + q4, tn * 32 + b4 * 2)) =
                make_uint2(pk2(ti[0], ti[1]), pk2(ti[2], ti[3]));
            f32x4 to = trans4(WoR[tn], q4);
            *(uint2*)(SWoN + swz128(wk * 16 + g * 4 + q4, tn * 32 + b4 * 2)) =
                make_uint2(pk2(to[0], to[1]), pk2(to[2], to[3]));
        }
    }
    if (tid < 256) {
        int cc = tid >> 2, j = tid & 3;
        lrc[cc * 4 + j] = lrc_all[((size_t)(b * 64 + cc)) * 64 + j * 16 + h];
    }

    // ---- A-side staging (verified commit math, 256 A-threads) ----
    const int nb4 = ((tid & 255) >> 4) * 4;
    const int db4 = (tid & 15) * 4;
    uint4 pq_[2];
    uint2 pk_[4], pv_[4];
    auto prefetch = [&](int c) {
        const size_t base = ((size_t)(b * 4096 + c * 64)) * 1024 + h * 64;
#pragma unroll
        for (int p = 0; p < 2; ++p) {
            int id = p * 256 + (tid & 255);
            int n = id >> 3;
            int d0 = (id & 7) * 8;
            pq_[p] = *(const uint4*)(qb + base + (size_t)n * 1024 + d0);
        }
#pragma unroll
        for (int j = 0; j < 4; ++j) {
            pk_[j] = *(const uint2*)(kb + base + (size_t)(nb4 + j) * 1024 + db4);
            pv_[j] = *(const uint2*)(vb + base + (size_t)(nb4 + j) * 1024 + db4);
        }
    };
    auto commit = [&](int buf) {
#pragma unroll
        for (int p = 0; p < 2; ++p) {
            int id = p * 256 + (tid & 255);
            int n = id >> 3;
            int d0 = (id & 7) * 8;
            *(uint4*)(SQ2[buf] + swz128(n, d0 * 2)) = pq_[p];
        }
#pragma unroll
        for (int j = 0; j < 4; ++j) {
            *(uint2*)(Kc2[buf] + swz128(nb4 + j, db4 * 2)) = pk_[j];
            *(uint2*)(Vc2[buf] + swz128(nb4 + j, db4 * 2)) = pv_[j];
        }
#pragma unroll
        for (int i = 0; i < 4; ++i) {
            u32 k0 = (((i & 2) ? pk_[0].y : pk_[0].x) >> ((i & 1) * 16)) & 0xffffu;
            u32 k1 = (((i & 2) ? pk_[1].y : pk_[1].x) >> ((i & 1) * 16)) & 0xffffu;
            u32 k2 = (((i & 2) ? pk_[2].y : pk_[2].x) >> ((i & 1) * 16)) & 0xffffu;
            u32 k3 = (((i & 2) ? pk_[3].y : pk_[3].x) >> ((i & 1) * 16)) & 0xffffu;
            *(uint2*)(KcT2[buf] + swz128(db4 + i, nb4 * 2)) =
                make_uint2(k0 | (k1 << 16), k2 | (k3 << 16));
            u32 v0 = (((i & 2) ? pv_[0].y : pv_[0].x) >> ((i & 1) * 16)) & 0xffffu;
            u32 v1 = (((i & 2) ? pv_[1].y : pv_[1].x) >> ((i & 1) * 16)) & 0xffffu;
            u32 v2 = (((i & 2) ? pv_[2].y : pv_[2].x) >> ((i & 1) * 16)) & 0xffffu;
            u32 v3 = (((i & 2) ? pv_[3].y : pv_[3].x) >> ((i & 1) * 16)) & 0xffffu;
            *(uint2*)(VcT2[buf] + swz128(db4 + i, nb4 * 2)) =
                make_uint2(v0 | (v1 << 16), v2 | (v3 << 16));
        }
    };

    if (isA) { prefetch(0); commit(0); }
    __syncthreads();

    for (int c = 0; c < 64; ++c) {
        const int cur = c & 1, nxt = cur ^ 1;
        f32x4 pk[4], aT[4], go[4];          // B-side live values

        if (isA) {
            // ================= A pipeline: M1 + softmax + SPQ =================
            if (c + 1 < 64) prefetch(c + 1);
            bf16x8 wiA0 = *(const bf16x8*)(SWiN + swz128(wq * 16 + li, g * 16));
            bf16x8 wiA1 = *(const bf16x8*)(SWiN + swz128(wq * 16 + li, 64 + g * 16));
            f32x4 sq[4];
            __builtin_amdgcn_s_setprio(1);
#pragma unroll
            for (int tn = 0; tn < 4; ++tn) {
                bf16x8 b0 = *(const bf16x8*)(SQ2[cur] + swz128(tn * 16 + li, g * 16));
                bf16x8 b1 = *(const bf16x8*)(SQ2[cur] + swz128(tn * 16 + li, 64 + g * 16));
                f32x4 z = (f32x4)0.0f;
                z = __builtin_amdgcn_mfma_f32_16x16x32_bf16(wiA0, b0, z, 0, 0, 0);
                z = __builtin_amdgcn_mfma_f32_16x16x32_bf16(wiA1, b1, z, 0, 0, 0);
                sq[tn] = z;
            }
            __builtin_amdgcn_s_setprio(0);
#pragma unroll
            for (int r = 0; r < 4; ++r) {
                float m = fmaxf(fmaxf(sq[0][r], sq[1][r]), fmaxf(sq[2][r], sq[3][r]));
                m = fmaxf(m, __shfl_xor(m, 1)); m = fmaxf(m, __shfl_xor(m, 2));
                m = fmaxf(m, __shfl_xor(m, 4)); m = fmaxf(m, __shfl_xor(m, 8));
                float e0 = __expf(sq[0][r] - m), e1 = __expf(sq[1][r] - m);
                float e2 = __expf(sq[2][r] - m), e3 = __expf(sq[3][r] - m);
                float s = e0 + e1 + e2 + e3;
                s += __shfl_xor(s, 1); s += __shfl_xor(s, 2);
                s += __shfl_xor(s, 4); s += __shfl_xor(s, 8);
                float inv = 1.0f / s;
                sq[0][r] = e0 * inv; sq[1][r] = e1 * inv; sq[2][r] = e2 * inv; sq[3][r] = e3 * inv;
            }
#pragma unroll
            for (int tn = 0; tn < 4; ++tn) {
                int n = tn * 16 + li;
                *(uint2*)(SPQ + swz128(n, (wq * 16 + g * 4) * 2)) =
                    make_uint2(pk2(sq[tn][0], sq[tn][1]), pk2(sq[tn][2], sq[tn][3]));
            }
            // ---- A-group spin sync (SPQ complete among waves 0-3) ----
            __threadfence_block();
            if (lane == 0) atomicAdd(&cntA, 1u);
            {
                volatile u32* vc = &cntA;
                u32 tgt = 4u * (u32)(c + 1);
                while (*vc < tgt) { __builtin_amdgcn_s_sleep(1); }
            }
            __threadfence_block();
        } else {
            // ============== B pipeline: M2 + softmax + M4' + spart + SPTN + M5 ==============
            bf16x8 wiA0 = *(const bf16x8*)(SWiN + swz128(wk * 16 + li, g * 16));
            bf16x8 wiA1 = *(const bf16x8*)(SWiN + swz128(wk * 16 + li, 64 + g * 16));
            __builtin_amdgcn_s_setprio(1);
#pragma unroll
            for (int tn = 0; tn < 4; ++tn) {
                bf16x8 b0 = *(const bf16x8*)(Kc2[cur] + swz128(tn * 16 + li, g * 16));
                bf16x8 b1 = *(const bf16x8*)(Kc2[cur] + swz128(tn * 16 + li, 64 + g * 16));
                f32x4 z = (f32x4)0.0f;
                z = __builtin_amdgcn_mfma_f32_16x16x32_bf16(wiA0, b0, z, 0, 0, 0);
                z = __builtin_amdgcn_mfma_f32_16x16x32_bf16(wiA1, b1, z, 0, 0, 0);
                pk[tn] = z;
            }
            __builtin_amdgcn_s_setprio(0);
#pragma unroll
            for (int r = 0; r < 4; ++r) {
                float m = fmaxf(fmaxf(pk[0][r], pk[1][r]), fmaxf(pk[2][r], pk[3][r]));
                m = fmaxf(m, __shfl_xor(m, 1)); m = fmaxf(m, __shfl_xor(m, 2));
                m = fmaxf(m, __shfl_xor(m, 4)); m = fmaxf(m, __shfl_xor(m, 8));
                float e0 = __expf(pk[0][r] - m), e1 = __expf(pk[1][r] - m);
                float e2 = __expf(pk[2][r] - m), e3 = __expf(pk[3][r] - m);
                float s = e0 + e1 + e2 + e3;
                s += __shfl_xor(s, 1); s += __shfl_xor(s, 2);
                s += __shfl_xor(s, 4); s += __shfl_xor(s, 8);
                float inv = 1.0f / s;
                pk[0][r] = e0 * inv; pk[1][r] = e1 * inv; pk[2][r] = e2 * inv; pk[3][r] = e3 * inv;
            }
            bf16x8 woA0 = *(const bf16x8*)(SWoN + swz128(wk * 16 + li, g * 16));
            bf16x8 woA1 = *(const bf16x8*)(SWoN + swz128(wk * 16 + li, 64 + g * 16));
            __builtin_amdgcn_s_setprio(1);
#pragma unroll
            for (int tn = 0; tn < 4; ++tn) {
                bf16x8 b0 = *(const bf16x8*)(Vc2[cur] + swz128(tn * 16 + li, g * 16));
                bf16x8 b1 = *(const bf16x8*)(Vc2[cur] + swz128(tn * 16 + li, 64 + g * 16));
                f32x4 z = (f32x4)0.0f;
                z = __builtin_amdgcn_mfma_f32_16x16x32_bf16(woA0, b0, z, 0, 0, 0);
                z = __builtin_amdgcn_mfma_f32_16x16x32_bf16(woA1, b1, z, 0, 0, 0);
                aT[tn] = z;
            }
            __builtin_amdgcn_s_setprio(0);
#pragma unroll
            for (int tn = 0; tn < 4; ++tn) {
                f32x4 t4 = pk[tn] * aT[tn];
                float s_ = t4[0] + t4[1] + t4[2] + t4[3];
                s_ += __shfl_xor(s_, 16);
                s_ += __shfl_xor(s_, 32);
                if (g == 0) spart[wk * 64 + tn * 16 + li] = s_;
            }
            // SPTN (wave-local rows) then M5 immediately (go) — independent of spart
#pragma unroll
            for (int tn = 0; tn < 4; ++tn) {
                f32x4 tp = trans4(pk[tn], q4);
                *(uint2*)(SPTN + swz128(wk * 16 + g * 4 + q4, tn * 32 + b4 * 2)) =
                    make_uint2(pk2(tp[0], tp[1]), pk2(tp[2], tp[3]));
            }
            {
                bf16x8 a0 = *(const bf16x8*)(SPTN + swz128(wk * 16 + li, g * 16));
                bf16x8 a1 = *(const bf16x8*)(SPTN + swz128(wk * 16 + li, 64 + g * 16));
                __builtin_amdgcn_s_setprio(1);
#pragma unroll
                for (int tn = 0; tn < 4; ++tn) {
                    bf16x8 b0 = *(const bf16x8*)(VcT2[cur] + swz128(tn * 16 + li, g * 16));
                    bf16x8 b1 = *(const bf16x8*)(VcT2[cur] + swz128(tn * 16 + li, 64 + g * 16));
                    f32x4 z = (f32x4)0.0f;
                    z = __builtin_amdgcn_mfma_f32_16x16x32_bf16(a0, b0, z, 0, 0, 0);
                    z = __builtin_amdgcn_mfma_f32_16x16x32_bf16(a1, b1, z, 0, 0, 0);
                    go[tn] = z;
                }
                __builtin_amdgcn_s_setprio(0);
            }
            // ---- B-group spin sync (spart complete among waves 4-7) ----
            __threadfence_block();
            if (lane == 0) atomicAdd(&cntB, 1u);
            {
                volatile u32* vc = &cntB;
                u32 tgt = 4u * (u32)(c + 1);
                while (*vc < tgt) { __builtin_amdgcn_s_sleep(1); }
            }
            __threadfence_block();
        }

        if (isA) {
            // ================= A: M3 + packed o store + commit(c+1) =================
            bf16x8 a0 = *(const bf16x8*)(SPQ + swz128(wq * 16 + li, g * 16));
            bf16x8 a1 = *(const bf16x8*)(SPQ + swz128(wq * 16 + li, 64 + g * 16));
            f32x4 o4[4];
            __builtin_amdgcn_s_setprio(1);
#pragma unroll
            for (int tn = 0; tn < 4; ++tn) {
                bf16x8 b0 = *(const bf16x8*)(SWoT2[cur] + swz128(tn * 16 + li, g * 16));
                bf16x8 b1 = *(const bf16x8*)(SWoT2[cur] + swz128(tn * 16 + li, 64 + g * 16));
                f32x4 z = (f32x4)0.0f;
                z = __builtin_amdgcn_mfma_f32_16x16x32_bf16(a0, b0, z, 0, 0, 0);
                z = __builtin_amdgcn_mfma_f32_16x16x32_bf16(a1, b1, z, 0, 0, 0);
                o4[tn] = z;
            }
            __builtin_amdgcn_s_setprio(0);
            const size_t obase = ((size_t)(b * 4096 + c * 64)) * 1024 + h * 64;
            const int n_ = wq * 16 + g * 4 + q4;
#pragma unroll
            for (int tn = 0; tn < 4; ++tn) {
                f32x4 to = trans4(o4[tn], q4);
                *(uint2*)(ob + obase + (size_t)n_ * 1024 + tn * 16 + b4) =
                    make_uint2(pk2(to[0], to[1]), pk2(to[2], to[3]));
            }
            if (c + 1 < 64) commit(nxt);
        } else {
            // ================= B: gz + SGZN + M6 + state update =================
            f32x4 gz[4];
#pragma unroll
            for (int tn = 0; tn < 4; ++tn) {
                int n = tn * 16 + li;
                float sn = spart[n] + spart[64 + n] + spart[128 + n] + spart[192 + n];
#pragma unroll
                for (int r = 0; r < 4; ++r) gz[tn][r] = pk[tn][r] * (sn - aT[tn][r]);
                f32x4 tg = trans4(gz[tn], q4);
                *(uint2*)(SGZN + swz128(wk * 16 + g * 4 + q4, tn * 32 + b4 * 2)) =
                    make_uint2(pk2(tg[0], tg[1]), pk2(tg[2], tg[3]));
            }
            f32x4 gi[4];
            {
                bf16x8 a0 = *(const bf16x8*)(SGZN + swz128(wk * 16 + li, g * 16));
                bf16x8 a1 = *(const bf16x8*)(SGZN + swz128(wk * 16 + li, 64 + g * 16));
                __builtin_amdgcn_s_setprio(1);
#pragma unroll
                for (int tn = 0; tn < 4; ++tn) {
                    bf16x8 b0 = *(const bf16x8*)(KcT2[cur] + swz128(tn * 16 + li, g * 16));
                    bf16x8 b1 = *(const bf16x8*)(KcT2[cur] + swz128(tn * 16 + li, 64 + g * 16));
                    f32x4 z = (f32x4)0.0f;
                    z = __builtin_amdgcn_mfma_f32_16x16x32_bf16(a0, b0, z, 0, 0, 0);
                    z = __builtin_amdgcn_mfma_f32_16x16x32_bf16(a1, b1, z, 0, 0, 0);
                    gi[tn] = z;
                }
                __builtin_amdgcn_s_setprio(0);
            }
            if (c + 1 < 64) {
                float lin = lrc[c * 4 + 0], lout = lrc[c * 4 + 1];
                float win = lrc[c * 4 + 2], wout = lrc[c * 4 + 3];
#pragma unroll
                for (int tn = 0; tn < 4; ++tn) {
                    WiR[tn] = win * WiR[tn] - lin * gi[tn];
                    WoR[tn] = wout * WoR[tn] + lout * go[tn];   // grad_out = -go
                    int d = tn * 16 + li;
                    *(uint2*)(SWoT2[nxt] + swz128(d, wk * 32 + g * 8)) =
                        make_uint2(pk2(WoR[tn][0], WoR[tn][1]), pk2(WoR[tn][2], WoR[tn][3]));
                    f32x4 ti = trans4(WiR[tn], q4);
                    *(uint2*)(SWiN + swz128(wk * 16 + g * 4 + q4, tn * 32 + b4 * 2)) =
                        make_uint2(pk2(ti[0], ti[1]), pk2(ti[2], ti[3]));
                    f32x4 to = trans4(WoR[tn], q4);
                    *(uint2*)(SWoN + swz128(wk * 16 + g * 4 + q4, tn * 32 + b4 * 2)) =
                        make_uint2(pk2(to[0], to[1]), pk2(to[2], to[3]));
                }
            }
        }
        __syncthreads();   // chunk end: tiles(c+1) + state(c+1) visible to all
    }
}

// ---------------------------------------------------------------------------
// Kernel D: out[t][m] = sum_j o[t][j] * Wo[m][j]
// ---------------------------------------------------------------------------
__global__ __launch_bounds__(256) void out_proj_kernel(
    const u16* __restrict__ ob, const u16* __restrict__ wob, float* __restrict__ out)
{
    __shared__ __align__(16) char As[128 * 128];
    __shared__ __align__(16) char Bs[128 * 128];
    const int bn = blockIdx.x;
    const int bm = blockIdx.y;
    const int cb = bn * 128;
    const int rb = bm * 128;
    const int tid = threadIdx.x;
    const int lane = tid & 63;
    const int wv = tid >> 6;
    const int wr = (wv >> 1) * 64, wc = (wv & 1) * 64;
    const int li = lane & 15, g = lane >> 4;
    const int lr8 = lane >> 3, lc8 = lane & 7;

    f32x4 acc[4][4];
#pragma unroll
    for (int i = 0; i < 4; ++i)
#pragma unroll
        for (int j = 0; j < 4; ++j) acc[i][j] = (f32x4)0.0f;

    for (int k0 = 0; k0 < 1024; k0 += 64) {
        __syncthreads();
#pragma unroll
        for (int ld = 0; ld < 4; ++ld) {
            int r0 = wv * 32 + ld * 8;
            gload_lds16(ob + (size_t)(rb + r0 + lr8) * 1024 + k0 + lc8 * 8, As + r0 * 128);
            gload_lds16(wob + (size_t)(cb + r0 + lr8) * 1024 + k0 + lc8 * 8, Bs + r0 * 128);
        }
        __syncthreads();
#pragma unroll
        for (int ks = 0; ks < 2; ++ks) {
            bf16x8 af[4], bfr[4];
#pragma unroll
            for (int m = 0; m < 4; ++m)
                af[m] = *(const bf16x8*)(As + (wr + m * 16 + li) * 128 + ks * 64 + g * 16);
#pragma unroll
            for (int n = 0; n < 4; ++n)
                bfr[n] = *(const bf16x8*)(Bs + (wc + n * 16 + li) * 128 + ks * 64 + g * 16);
#pragma unroll
            for (int m = 0; m < 4; ++m)
#pragma unroll
                for (int n = 0; n < 4; ++n)
                    acc[m][n] = __builtin_amdgcn_mfma_f32_16x16x32_bf16(af[m], bfr[n], acc[m][n], 0, 0, 0);
        }
    }
#pragma unroll
    for (int m = 0; m < 4; ++m) {
        int t = rb + wr + m * 16 + g * 4;
#pragma unroll
        for (int r = 0; r < 4; ++r) {
#pragma unroll
            for (int n = 0; n < 4; ++n) {
                int col = cb + wc + n * 16 + li;
                out[(size_t)(t + r) * 1024 + col] = acc[m][n][r];
            }
        }
    }
}

// ---------------------------------------------------------------------------
extern "C" void kernel_launch(void* const* d_in, const int* in_sizes, int n_in,
                              void* d_out, int out_size, void* d_ws, size_t ws_size,
                              hipStream_t stream)
{
    const float* x     = (const float*)d_in[0];
    const float* Wq    = (const float*)d_in[1];
    const float* Wk    = (const float*)d_in[2];
    const float* Wv    = (const float*)d_in[3];
    const float* Wlr   = (const float*)d_in[4];
    const float* Wbeta = (const float*)d_in[5];
    const float* Wo    = (const float*)d_in[6];
    const float* Wi0   = (const float*)d_in[7];
    const float* Wo0   = (const float*)d_in[8];
    float* out = (float*)d_out;

    char* od = (char*)d_out;
    u16* xb  = (u16*)(od);                 // dead before out_proj overwrites
    u16* wb  = (u16*)(od + 33554432u);
    u16* wlb = (u16*)(od + 39845888u);

    char* ws = (char*)d_ws;
    u16* qb        = (u16*)(ws);
    u16* kb        = (u16*)(ws + 33554432u);
    u16* vb        = (u16*)(ws + 67108864u);
    u16* obuf      = (u16*)(ws + 100663296u);
    float* lrc_all = (float*)(ws + 134217728u);
    u16* wob       = (u16*)(ws + 134283264u);
    if (ws_size < 136380416u) return;

    convert_kernel<<<2048, 256, 0, stream>>>(x, Wq, Wk, Wv, Wo, Wlr, Wbeta,
                                             xb, wb, wob, wlb);
    proj_qkv_kernel<<<dim3(24, 128), 256, 0, stream>>>(xb, wb, qb, kb, vb);
    lrwd_kernel<<<128, 256, 0, stream>>>(xb, wlb, lrc_all);
    scan_kernel<<<64, 512, 0, stream>>>(qb, kb, vb, lrc_all, Wi0, Wo0, obuf);
    out_proj_kernel<<<dim3(8, 128), 256, 0, stream>>>(obuf, wob, out);
}

// Round 10
// 575.777 us; speedup vs baseline: 1.3961x; 1.0469x over previous
//
#include <hip/hip_runtime.h>
#include <stdint.h>

typedef unsigned short u16;
typedef uint32_t u32;
typedef __attribute__((ext_vector_type(4))) float f32x4;
typedef __attribute__((ext_vector_type(8))) short bf16x8;

#define DEVINL __device__ __forceinline__

DEVINL u16 f2bf(float f) {
    union { float f; u32 u; } a; a.f = f;
    u32 u = a.u;
    return (u16)((u + 0x7fffu + ((u >> 16) & 1u)) >> 16);   // RNE
}
DEVINL u32 pk2(float a, float b) { return (u32)f2bf(a) | ((u32)f2bf(b) << 16); }

// 128B-row swizzled tile (conflict-free vector row reads) — verified R2..R9
DEVINL u32 swz128(u32 row, u32 colb) { return row * 128u + (colb ^ ((row & 7u) << 4)); }

// async global->LDS, 16B per lane
DEVINL void gload_lds16(const u16* g, char* l) {
    __builtin_amdgcn_global_load_lds(
        (const __attribute__((address_space(1))) void*)g,
        (__attribute__((address_space(3))) void*)l, 16, 0, 0);
}

// 4x4 transpose among 4 lanes (lane&3) over the 4 regs of v (R4-verified)
DEVINL f32x4 trans4(f32x4 v, int q) {
    float s0 = __shfl_xor(v[0], 1), s1 = __shfl_xor(v[1], 1),
          s2 = __shfl_xor(v[2], 1), s3 = __shfl_xor(v[3], 1);
    f32x4 t;
    bool q1 = (q & 1) != 0;
    t[0] = q1 ? s1 : v[0];
    t[1] = q1 ? v[1] : s0;
    t[2] = q1 ? s3 : v[2];
    t[3] = q1 ? v[3] : s2;
    float u0 = __shfl_xor(t[0], 2), u1 = __shfl_xor(t[1], 2),
          u2 = __shfl_xor(t[2], 2), u3 = __shfl_xor(t[3], 2);
    f32x4 r;
    bool q2 = (q & 2) != 0;
    r[0] = q2 ? u2 : t[0];
    r[1] = q2 ? u3 : t[1];
    r[2] = q2 ? t[2] : u0;
    r[3] = q2 ? t[3] : u1;
    return r;
}

// ---------------------------------------------------------------------------
// Kernel 0: fp32 -> bf16 convert pass
// ---------------------------------------------------------------------------
__global__ __launch_bounds__(256) void convert_kernel(
    const float* __restrict__ x, const float* __restrict__ Wq,
    const float* __restrict__ Wk, const float* __restrict__ Wv,
    const float* __restrict__ Wo, const float* __restrict__ Wlr,
    const float* __restrict__ Wbeta,
    u16* __restrict__ xb, u16* __restrict__ wb, u16* __restrict__ wob,
    u16* __restrict__ wlb)
{
    const int t0 = blockIdx.x * 256 + threadIdx.x;
    const int stride = gridDim.x * 256;
    auto cv = [&](const float* src, u16* dst, int n4) {
        for (int i = t0; i < n4; i += stride) {
            float4 v = ((const float4*)src)[i];
            uint2 p;
            p.x = pk2(v.x, v.y);
            p.y = pk2(v.z, v.w);
            ((uint2*)dst)[i] = p;
        }
    };
    cv(x, xb, 4194304);
    cv(Wq, wb, 262144);
    cv(Wk, wb + 1048576, 262144);
    cv(Wv, wb + 2097152, 262144);
    cv(Wo, wob, 262144);
    cv(Wlr, wlb, 8192);
    cv(Wbeta, wlb + 32768, 8192);
}

// ---------------------------------------------------------------------------
// Kernel A: q/k/v projections (bf16 in, bf16 out, fused silu for q,k)
// NEW (R10): swizzled LDS via pre-swizzled gload source (rule #21) + swz128
// fragment reads — kills the 16-way ds_read_b128 bank conflict of the
// linear 128B-row tile (G4/m136).
// ---------------------------------------------------------------------------
__global__ __launch_bounds__(256) void proj_qkv_kernel(
    const u16* __restrict__ xb, const u16* __restrict__ wb,
    u16* __restrict__ qb, u16* __restrict__ kb, u16* __restrict__ vb)
{
    __shared__ __align__(16) char As[128 * 128];
    __shared__ __align__(16) char Bs[128 * 128];
    const int bn = blockIdx.x;
    const int bm = blockIdx.y;
    const int wsel = bn >> 3;
    u16* __restrict__ dst = (wsel == 0) ? qb : ((wsel == 1) ? kb : vb);
    const int cb = (bn & 7) * 128;
    const int wrow = bn * 128;
    const int rb = bm * 128;
    const int tid = threadIdx.x;
    const int lane = tid & 63;
    const int wv = tid >> 6;
    const int wr = (wv >> 1) * 64, wc = (wv & 1) * 64;
    const int li = lane & 15, g = lane >> 4;
    const int lr8 = lane >> 3, lc8 = lane & 7;

    f32x4 acc[4][4];
#pragma unroll
    for (int i = 0; i < 4; ++i)
#pragma unroll
        for (int j = 0; j < 4; ++j) acc[i][j] = (f32x4)0.0f;

    for (int k0 = 0; k0 < 1024; k0 += 64) {
        __syncthreads();
#pragma unroll
        for (int ld = 0; ld < 4; ++ld) {
            int r0 = wv * 32 + ld * 8;
            int rowT = r0 + lr8;                          // row in tile
            int csw = (lc8 * 8) ^ ((rowT & 7) << 3);      // pre-swizzled col (elems)
            gload_lds16(xb + (size_t)(rb + rowT) * 1024 + k0 + csw, As + r0 * 128);
            gload_lds16(wb + (size_t)(wrow + rowT) * 1024 + k0 + csw, Bs + r0 * 128);
        }
        __syncthreads();
#pragma unroll
        for (int ks = 0; ks < 2; ++ks) {
            bf16x8 af[4], bfr[4];
#pragma unroll
            for (int m = 0; m < 4; ++m)
                af[m] = *(const bf16x8*)(As + swz128(wr + m * 16 + li, ks * 64 + g * 16));
#pragma unroll
            for (int n = 0; n < 4; ++n)
                bfr[n] = *(const bf16x8*)(Bs + swz128(wc + n * 16 + li, ks * 64 + g * 16));
#pragma unroll
            for (int m = 0; m < 4; ++m)
#pragma unroll
                for (int n = 0; n < 4; ++n)
                    acc[m][n] = __builtin_amdgcn_mfma_f32_16x16x32_bf16(af[m], bfr[n], acc[m][n], 0, 0, 0);
        }
    }
    const bool do_silu = (wsel < 2);
#pragma unroll
    for (int m = 0; m < 4; ++m) {
        int t = rb + wr + m * 16 + g * 4;
#pragma unroll
        for (int r = 0; r < 4; ++r) {
#pragma unroll
            for (int n = 0; n < 4; ++n) {
                float v = acc[m][n][r];
                if (do_silu) v = v / (1.0f + __expf(-v));
                int col = cb + wc + n * 16 + li;
                dst[(size_t)(t + r) * 1024 + col] = f2bf(v);
            }
        }
    }
}

// ---------------------------------------------------------------------------
// Kernel B: lr/wd heads as MFMA GEMM + on-chip per-chunk mean (swizzled R10)
// ---------------------------------------------------------------------------
__global__ __launch_bounds__(256) void lrwd_kernel(
    const u16* __restrict__ xb, const u16* __restrict__ wlb,
    float* __restrict__ lrc_all)
{
    __shared__ __align__(16) char As[128 * 128];
    __shared__ __align__(16) char Bs[64 * 128];
    __shared__ float red[128][65];
    const int bm = blockIdx.x;
    const int rb = bm * 128;
    const int tid = threadIdx.x;
    const int lane = tid & 63;
    const int wv = tid >> 6;
    const int li = lane & 15, g = lane >> 4;
    const int lr8 = lane >> 3, lc8 = lane & 7;

    f32x4 acc[2][4];
#pragma unroll
    for (int i = 0; i < 2; ++i)
#pragma unroll
        for (int j = 0; j < 4; ++j) acc[i][j] = (f32x4)0.0f;

    for (int k0 = 0; k0 < 1024; k0 += 64) {
        __syncthreads();
#pragma unroll
        for (int ld = 0; ld < 4; ++ld) {
            int r0 = wv * 32 + ld * 8;
            int rowT = r0 + lr8;
            int csw = (lc8 * 8) ^ ((rowT & 7) << 3);
            gload_lds16(xb + (size_t)(rb + rowT) * 1024 + k0 + csw, As + r0 * 128);
        }
#pragma unroll
        for (int ld = 0; ld < 2; ++ld) {
            int r0 = wv * 16 + ld * 8;
            int rowT = r0 + lr8;
            int csw = (lc8 * 8) ^ ((rowT & 7) << 3);
            gload_lds16(wlb + (size_t)rowT * 1024 + k0 + csw, Bs + r0 * 128);
        }
        __syncthreads();
#pragma unroll
        for (int ks = 0; ks < 2; ++ks) {
            bf16x8 af[2], bfr[4];
#pragma unroll
            for (int m = 0; m < 2; ++m)
                af[m] = *(const bf16x8*)(As + swz128(wv * 32 + m * 16 + li, ks * 64 + g * 16));
#pragma unroll
            for (int n = 0; n < 4; ++n)
                bfr[n] = *(const bf16x8*)(Bs + swz128(n * 16 + li, ks * 64 + g * 16));
#pragma unroll
            for (int m = 0; m < 2; ++m)
#pragma unroll
                for (int n = 0; n < 4; ++n)
                    acc[m][n] = __builtin_amdgcn_mfma_f32_16x16x32_bf16(af[m], bfr[n], acc[m][n], 0, 0, 0);
        }
    }
#pragma unroll
    for (int m = 0; m < 2; ++m) {
#pragma unroll
        for (int n = 0; n < 4; ++n) {
            int col = n * 16 + li;
            float scale = (col < 32) ? 1e-3f : 0.9f;
#pragma unroll
            for (int r = 0; r < 4; ++r) {
                int t = wv * 32 + m * 16 + g * 4 + r;
                float s = acc[m][n][r];
                red[t][col] = scale / (1.0f + __expf(-s));
            }
        }
    }
    __syncthreads();
    if (tid < 128) {
        int chunk = tid >> 6, col = tid & 63;
        float s = 0.f;
#pragma unroll
        for (int i = 0; i < 64; ++i) s += red[chunk * 64 + i][col];
        int b = bm >> 5;
        int cidx = (bm & 31) * 2 + chunk;
        lrc_all[((size_t)(b * 64 + cidx)) * 64 + col] = s * (1.0f / 64.0f);
    }
}

// ---------------------------------------------------------------------------
// Kernel C: chunk scan — R9 verbatim (352 us verified best)
// ---------------------------------------------------------------------------
__global__ __launch_bounds__(512) void scan_kernel(
    const u16* __restrict__ qb, const u16* __restrict__ kb, const u16* __restrict__ vb,
    const float* __restrict__ lrc_all, const float* __restrict__ Wi0,
    const float* __restrict__ Wo0, u16* __restrict__ ob)
{
    const int bh = blockIdx.x;
    const int b = bh >> 4, h = bh & 15;
    const int tid = threadIdx.x;
    const int lane = tid & 63;
    const int w8 = tid >> 6;            // 0..7
    const bool isA = (w8 < 4);
    const int wq = w8;                  // A-wave index (0..3) when isA
    const int wk = w8 - 4;              // B-wave index (0..3) when !isA
    const int li = lane & 15, g = lane >> 4;
    const int q4 = li & 3, b4 = li & 12;

    __shared__ __align__(16) char SQ2[2][8192];    // q   [n][d]
    __shared__ __align__(16) char Kc2[2][8192];    // k   [n][d]
    __shared__ __align__(16) char Vc2[2][8192];    // v   [n][d]
    __shared__ __align__(16) char KcT2[2][8192];   // k^T [d][n]
    __shared__ __align__(16) char VcT2[2][8192];   // v^T [d][n]
    __shared__ __align__(16) char SWoT2[2][8192];  // Wo^T[d][D]
    __shared__ __align__(16) char SWiN[8192];      // Wi  [D][d]
    __shared__ __align__(16) char SWoN[8192];      // Wo  [D][d]
    __shared__ __align__(16) char SPQ[8192];       // pq  [n][D]
    __shared__ __align__(16) char SPTN[8192];      // p^T [D][n]
    __shared__ __align__(16) char SGZN[8192];      // gz^T[D][n]
    __shared__ float spart[256];
    __shared__ float lrc[256];
    __shared__ u32 cntA, cntB;

    if (tid == 0) { cntA = 0u; cntB = 0u; }

    f32x4 WiR[4], WoR[4];
    if (!isA) {
#pragma unroll
        for (int tn = 0; tn < 4; ++tn) {
            int d = tn * 16 + li;
#pragma unroll
            for (int r = 0; r < 4; ++r) {
                int D = wk * 16 + g * 4 + r;
                WiR[tn][r] = Wi0[((size_t)D * 16 + h) * 64 + d];
                WoR[tn][r] = Wo0[((size_t)D * 16 + h) * 64 + d];
            }
            *(uint2*)(SWoT2[0] + swz128(d, wk * 32 + g * 8)) =
                make_uint2(pk2(WoR[tn][0], WoR[tn][1]), pk2(WoR[tn][2], WoR[tn][3]));
            f32x4 ti = trans4(WiR[tn], q4);
            *(uint2*)(SWiN + swz128(wk * 16 + g * 4 + q4, tn * 32 + b4 * 2)) =
                make_uint2(pk2(ti[0], ti[1]), pk2(ti[2], ti[3]));
            f32x4 to = trans4(WoR[tn], q4);
            *(uint2*)(SWoN + swz128(wk * 16 + g * 4 + q4, tn * 32 + b4 * 2)) =
                make_uint2(pk2(to[0], to[1]), pk2(to[2], to[3]));
        }
    }
    if (tid < 256) {
        int cc = tid >> 2, j = tid & 3;
        lrc[cc * 4 + j] = lrc_all[((size_t)(b * 64 + cc)) * 64 + j * 16 + h];
    }

    const int nb4 = ((tid & 255) >> 4) * 4;
    const int db4 = (tid & 15) * 4;
    uint4 pq_[2];
    uint2 pk_[4], pv_[4];
    auto prefetch = [&](int c) {
        const size_t base = ((size_t)(b * 4096 + c * 64)) * 1024 + h * 64;
#pragma unroll
        for (int p = 0; p < 2; ++p) {
            int id = p * 256 + (tid & 255);
            int n = id >> 3;
            int d0 = (id & 7) * 8;
            pq_[p] = *(const uint4*)(qb + base + (size_t)n * 1024 + d0);
        }
#pragma unroll
        for (int j = 0; j < 4; ++j) {
            pk_[j] = *(const uint2*)(kb + base + (size_t)(nb4 + j) * 1024 + db4);
            pv_[j] = *(const uint2*)(vb + base + (size_t)(nb4 + j) * 1024 + db4);
        }
    };
    auto commit = [&](int buf) {
#pragma unroll
        for (int p = 0; p < 2; ++p) {
            int id = p * 256 + (tid & 255);
            int n = id >> 3;
            int d0 = (id & 7) * 8;
            *(uint4*)(SQ2[buf] + swz128(n, d0 * 2)) = pq_[p];
        }
#pragma unroll
        for (int j = 0; j < 4; ++j) {
            *(uint2*)(Kc2[buf] + swz128(nb4 + j, db4 * 2)) = pk_[j];
            *(uint2*)(Vc2[buf] + swz128(nb4 + j, db4 * 2)) = pv_[j];
        }
#pragma unroll
        for (int i = 0; i < 4; ++i) {
            u32 k0 = (((i & 2) ? pk_[0].y : pk_[0].x) >> ((i & 1) * 16)) & 0xffffu;
            u32 k1 = (((i & 2) ? pk_[1].y : pk_[1].x) >> ((i & 1) * 16)) & 0xffffu;
            u32 k2 = (((i & 2) ? pk_[2].y : pk_[2].x) >> ((i & 1) * 16)) & 0xffffu;
            u32 k3 = (((i & 2) ? pk_[3].y : pk_[3].x) >> ((i & 1) * 16)) & 0xffffu;
            *(uint2*)(KcT2[buf] + swz128(db4 + i, nb4 * 2)) =
                make_uint2(k0 | (k1 << 16), k2 | (k3 << 16));
            u32 v0 = (((i & 2) ? pv_[0].y : pv_[0].x) >> ((i & 1) * 16)) & 0xffffu;
            u32 v1 = (((i & 2) ? pv_[1].y : pv_[1].x) >> ((i & 1) * 16)) & 0xffffu;
            u32 v2 = (((i & 2) ? pv_[2].y : pv_[2].x) >> ((i & 1) * 16)) & 0xffffu;
            u32 v3 = (((i & 2) ? pv_[3].y : pv_[3].x) >> ((i & 1) * 16)) & 0xffffu;
            *(uint2*)(VcT2[buf] + swz128(db4 + i, nb4 * 2)) =
                make_uint2(v0 | (v1 << 16), v2 | (v3 << 16));
        }
    };

    if (isA) { prefetch(0); commit(0); }
    __syncthreads();

    for (int c = 0; c < 64; ++c) {
        const int cur = c & 1, nxt = cur ^ 1;
        f32x4 pk[4], aT[4], go[4];

        if (isA) {
            if (c + 1 < 64) prefetch(c + 1);
            bf16x8 wiA0 = *(const bf16x8*)(SWiN + swz128(wq * 16 + li, g * 16));
            bf16x8 wiA1 = *(const bf16x8*)(SWiN + swz128(wq * 16 + li, 64 + g * 16));
            f32x4 sq[4];
            __builtin_amdgcn_s_setprio(1);
#pragma unroll
            for (int tn = 0; tn < 4; ++tn) {
                bf16x8 b0 = *(const bf16x8*)(SQ2[cur] + swz128(tn * 16 + li, g * 16));
                bf16x8 b1 = *(const bf16x8*)(SQ2[cur] + swz128(tn * 16 + li, 64 + g * 16));
                f32x4 z = (f32x4)0.0f;
                z = __builtin_amdgcn_mfma_f32_16x16x32_bf16(wiA0, b0, z, 0, 0, 0);
                z = __builtin_amdgcn_mfma_f32_16x16x32_bf16(wiA1, b1, z, 0, 0, 0);
                sq[tn] = z;
            }
            __builtin_amdgcn_s_setprio(0);
#pragma unroll
            for (int r = 0; r < 4; ++r) {
                float m = fmaxf(fmaxf(sq[0][r], sq[1][r]), fmaxf(sq[2][r], sq[3][r]));
                m = fmaxf(m, __shfl_xor(m, 1)); m = fmaxf(m, __shfl_xor(m, 2));
                m = fmaxf(m, __shfl_xor(m, 4)); m = fmaxf(m, __shfl_xor(m, 8));
                float e0 = __expf(sq[0][r] - m), e1 = __expf(sq[1][r] - m);
                float e2 = __expf(sq[2][r] - m), e3 = __expf(sq[3][r] - m);
                float s = e0 + e1 + e2 + e3;
                s += __shfl_xor(s, 1); s += __shfl_xor(s, 2);
                s += __shfl_xor(s, 4); s += __shfl_xor(s, 8);
                float inv = 1.0f / s;
                sq[0][r] = e0 * inv; sq[1][r] = e1 * inv; sq[2][r] = e2 * inv; sq[3][r] = e3 * inv;
            }
#pragma unroll
            for (int tn = 0; tn < 4; ++tn) {
                int n = tn * 16 + li;
                *(uint2*)(SPQ + swz128(n, (wq * 16 + g * 4) * 2)) =
                    make_uint2(pk2(sq[tn][0], sq[tn][1]), pk2(sq[tn][2], sq[tn][3]));
            }
            __threadfence_block();
            if (lane == 0) atomicAdd(&cntA, 1u);
            {
                volatile u32* vc = &cntA;
                u32 tgt = 4u * (u32)(c + 1);
                while (*vc < tgt) { __builtin_amdgcn_s_sleep(1); }
            }
            __threadfence_block();
        } else {
            bf16x8 wiA0 = *(const bf16x8*)(SWiN + swz128(wk * 16 + li, g * 16));
            bf16x8 wiA1 = *(const bf16x8*)(SWiN + swz128(wk * 16 + li, 64 + g * 16));
            __builtin_amdgcn_s_setprio(1);
#pragma unroll
            for (int tn = 0; tn < 4; ++tn) {
                bf16x8 b0 = *(const bf16x8*)(Kc2[cur] + swz128(tn * 16 + li, g * 16));
                bf16x8 b1 = *(const bf16x8*)(Kc2[cur] + swz128(tn * 16 + li, 64 + g * 16));
                f32x4 z = (f32x4)0.0f;
                z = __builtin_amdgcn_mfma_f32_16x16x32_bf16(wiA0, b0, z, 0, 0, 0);
                z = __builtin_amdgcn_mfma_f32_16x16x32_bf16(wiA1, b1, z, 0, 0, 0);
                pk[tn] = z;
            }
            __builtin_amdgcn_s_setprio(0);
#pragma unroll
            for (int r = 0; r < 4; ++r) {
                float m = fmaxf(fmaxf(pk[0][r], pk[1][r]), fmaxf(pk[2][r], pk[3][r]));
                m = fmaxf(m, __shfl_xor(m, 1)); m = fmaxf(m, __shfl_xor(m, 2));
                m = fmaxf(m, __shfl_xor(m, 4)); m = fmaxf(m, __shfl_xor(m, 8));
                float e0 = __expf(pk[0][r] - m), e1 = __expf(pk[1][r] - m);
                float e2 = __expf(pk[2][r] - m), e3 = __expf(pk[3][r] - m);
                float s = e0 + e1 + e2 + e3;
                s += __shfl_xor(s, 1); s += __shfl_xor(s, 2);
                s += __shfl_xor(s, 4); s += __shfl_xor(s, 8);
                float inv = 1.0f / s;
                pk[0][r] = e0 * inv; pk[1][r] = e1 * inv; pk[2][r] = e2 * inv; pk[3][r] = e3 * inv;
            }
            bf16x8 woA0 = *(const bf16x8*)(SWoN + swz128(wk * 16 + li, g * 16));
            bf16x8 woA1 = *(const bf16x8*)(SWoN + swz128(wk * 16 + li, 64 + g * 16));
            __builtin_amdgcn_s_setprio(1);
#pragma unroll
            for (int tn = 0; tn < 4; ++tn) {
                bf16x8 b0 = *(const bf16x8*)(Vc2[cur] + swz128(tn * 16 + li, g * 16));
                bf16x8 b1 = *(const bf16x8*)(Vc2[cur] + swz128(tn * 16 + li, 64 + g * 16));
                f32x4 z = (f32x4)0.0f;
                z = __builtin_amdgcn_mfma_f32_16x16x32_bf16(woA0, b0, z, 0, 0, 0);
                z = __builtin_amdgcn_mfma_f32_16x16x32_bf16(woA1, b1, z, 0, 0, 0);
                aT[tn] = z;
            }
            __builtin_amdgcn_s_setprio(0);
#pragma unroll
            for (int tn = 0; tn < 4; ++tn) {
                f32x4 t4 = pk[tn] * aT[tn];
                float s_ = t4[0] + t4[1] + t4[2] + t4[3];
                s_ += __shfl_xor(s_, 16);
                s_ += __shfl_xor(s_, 32);
                if (g == 0) spart[wk * 64 + tn * 16 + li] = s_;
            }
#pragma unroll
            for (int tn = 0; tn < 4; ++tn) {
                f32x4 tp = trans4(pk[tn], q4);
                *(uint2*)(SPTN + swz128(wk * 16 + g * 4 + q4, tn * 32 + b4 * 2)) =
                    make_uint2(pk2(tp[0], tp[1]), pk2(tp[2], tp[3]));
            }
            {
                bf16x8 a0 = *(const bf16x8*)(SPTN + swz128(wk * 16 + li, g * 16));
                bf16x8 a1 = *(const bf16x8*)(SPTN + swz128(wk * 16 + li, 64 + g * 16));
                __builtin_amdgcn_s_setprio(1);
#pragma unroll
                for (int tn = 0; tn < 4; ++tn) {
                    bf16x8 b0 = *(const bf16x8*)(VcT2[cur] + swz128(tn * 16 + li, g * 16));
                    bf16x8 b1 = *(const bf16x8*)(VcT2[cur] + swz128(tn * 16 + li, 64 + g * 16));
                    f32x4 z = (f32x4)0.0f;
                    z = __builtin_amdgcn_mfma_f32_16x16x32_bf16(a0, b0, z, 0, 0, 0);
                    z = __builtin_amdgcn_mfma_f32_16x16x32_bf16(a1, b1, z, 0, 0, 0);
                    go[tn] = z;
                }
                __builtin_amdgcn_s_setprio(0);
            }
            __threadfence_block();
            if (lane == 0) atomicAdd(&cntB, 1u);
            {
                volatile u32* vc = &cntB;
                u32 tgt = 4u * (u32)(c + 1);
                while (*vc < tgt) { __builtin_amdgcn_s_sleep(1); }
            }
            __threadfence_block();
        }

        if (isA) {
            bf16x8 a0 = *(const bf16x8*)(SPQ + swz128(wq * 16 + li, g * 16));
            bf16x8 a1 = *(const bf16x8*)(SPQ + swz128(wq * 16 + li, 64 + g * 16));
            f32x4 o4[4];
            __builtin_amdgcn_s_setprio(1);
#pragma unroll
            for (int tn = 0; tn < 4; ++tn) {
                bf16x8 b0 = *(const bf16x8*)(SWoT2[cur] + swz128(tn * 16 + li, g * 16));
                bf16x8 b1 = *(const bf16x8*)(SWoT2[cur] + swz128(tn * 16 + li, 64 + g * 16));
                f32x4 z = (f32x4)0.0f;
                z = __builtin_amdgcn_mfma_f32_16x16x32_bf16(a0, b0, z, 0, 0, 0);
                z = __builtin_amdgcn_mfma_f32_16x16x32_bf16(a1, b1, z, 0, 0, 0);
                o4[tn] = z;
            }
            __builtin_amdgcn_s_setprio(0);
            const size_t obase = ((size_t)(b * 4096 + c * 64)) * 1024 + h * 64;
            const int n_ = wq * 16 + g * 4 + q4;
#pragma unroll
            for (int tn = 0; tn < 4; ++tn) {
                f32x4 to = trans4(o4[tn], q4);
                *(uint2*)(ob + obase + (size_t)n_ * 1024 + tn * 16 + b4) =
                    make_uint2(pk2(to[0], to[1]), pk2(to[2], to[3]));
            }
            if (c + 1 < 64) commit(nxt);
        } else {
            f32x4 gz[4];
#pragma unroll
            for (int tn = 0; tn < 4; ++tn) {
                int n = tn * 16 + li;
                float sn = spart[n] + spart[64 + n] + spart[128 + n] + spart[192 + n];
#pragma unroll
                for (int r = 0; r < 4; ++r) gz[tn][r] = pk[tn][r] * (sn - aT[tn][r]);
                f32x4 tg = trans4(gz[tn], q4);
                *(uint2*)(SGZN + swz128(wk * 16 + g * 4 + q4, tn * 32 + b4 * 2)) =
                    make_uint2(pk2(tg[0], tg[1]), pk2(tg[2], tg[3]));
            }
            f32x4 gi[4];
            {
                bf16x8 a0 = *(const bf16x8*)(SGZN + swz128(wk * 16 + li, g * 16));
                bf16x8 a1 = *(const bf16x8*)(SGZN + swz128(wk * 16 + li, 64 + g * 16));
                __builtin_amdgcn_s_setprio(1);
#pragma unroll
                for (int tn = 0; tn < 4; ++tn) {
                    bf16x8 b0 = *(const bf16x8*)(KcT2[cur] + swz128(tn * 16 + li, g * 16));
                    bf16x8 b1 = *(const bf16x8*)(KcT2[cur] + swz128(tn * 16 + li, 64 + g * 16));
                    f32x4 z = (f32x4)0.0f;
                    z = __builtin_amdgcn_mfma_f32_16x16x32_bf16(a0, b0, z, 0, 0, 0);
                    z = __builtin_amdgcn_mfma_f32_16x16x32_bf16(a1, b1, z, 0, 0, 0);
                    gi[tn] = z;
                }
                __builtin_amdgcn_s_setprio(0);
            }
            if (c + 1 < 64) {
                float lin = lrc[c * 4 + 0], lout = lrc[c * 4 + 1];
                float win = lrc[c * 4 + 2], wout = lrc[c * 4 + 3];
#pragma unroll
                for (int tn = 0; tn < 4; ++tn) {
                    WiR[tn] = win * WiR[tn] - lin * gi[tn];
                    WoR[tn] = wout * WoR[tn] + lout * go[tn];   // grad_out = -go
                    int d = tn * 16 + li;
                    *(uint2*)(SWoT2[nxt] + swz128(d, wk * 32 + g * 8)) =
                        make_uint2(pk2(WoR[tn][0], WoR[tn][1]), pk2(WoR[tn][2], WoR[tn][3]));
                    f32x4 ti = trans4(WiR[tn], q4);
                    *(uint2*)(SWiN + swz128(wk * 16 + g * 4 + q4, tn * 32 + b4 * 2)) =
                        make_uint2(pk2(ti[0], ti[1]), pk2(ti[2], ti[3]));
                    f32x4 to = trans4(WoR[tn], q4);
                    *(uint2*)(SWoN + swz128(wk * 16 + g * 4 + q4, tn * 32 + b4 * 2)) =
                        make_uint2(pk2(to[0], to[1]), pk2(to[2], to[3]));
                }
            }
        }
        __syncthreads();   // chunk end: tiles(c+1) + state(c+1) visible to all
    }
}

// ---------------------------------------------------------------------------
// Kernel D: out[t][m] = sum_j o[t][j] * Wo[m][j]  (swizzled R10)
// ---------------------------------------------------------------------------
__global__ __launch_bounds__(256) void out_proj_kernel(
    const u16* __restrict__ ob, const u16* __restrict__ wob, float* __restrict__ out)
{
    __shared__ __align__(16) char As[128 * 128];
    __shared__ __align__(16) char Bs[128 * 128];
    const int bn = blockIdx.x;
    const int bm = blockIdx.y;
    const int cb = bn * 128;
    const int rb = bm * 128;
    const int tid = threadIdx.x;
    const int lane = tid & 63;
    const int wv = tid >> 6;
    const int wr = (wv >> 1) * 64, wc = (wv & 1) * 64;
    const int li = lane & 15, g = lane >> 4;
    const int lr8 = lane >> 3, lc8 = lane & 7;

    f32x4 acc[4][4];
#pragma unroll
    for (int i = 0; i < 4; ++i)
#pragma unroll
        for (int j = 0; j < 4; ++j) acc[i][j] = (f32x4)0.0f;

    for (int k0 = 0; k0 < 1024; k0 += 64) {
        __syncthreads();
#pragma unroll
        for (int ld = 0; ld < 4; ++ld) {
            int r0 = wv * 32 + ld * 8;
            int rowT = r0 + lr8;
            int csw = (lc8 * 8) ^ ((rowT & 7) << 3);
            gload_lds16(ob + (size_t)(rb + rowT) * 1024 + k0 + csw, As + r0 * 128);
            gload_lds16(wob + (size_t)(cb + rowT) * 1024 + k0 + csw, Bs + r0 * 128);
        }
        __syncthreads();
#pragma unroll
        for (int ks = 0; ks < 2; ++ks) {
            bf16x8 af[4], bfr[4];
#pragma unroll
            for (int m = 0; m < 4; ++m)
                af[m] = *(const bf16x8*)(As + swz128(wr + m * 16 + li, ks * 64 + g * 16));
#pragma unroll
            for (int n = 0; n < 4; ++n)
                bfr[n] = *(const bf16x8*)(Bs + swz128(wc + n * 16 + li, ks * 64 + g * 16));
#pragma unroll
            for (int m = 0; m < 4; ++m)
#pragma unroll
                for (int n = 0; n < 4; ++n)
                    acc[m][n] = __builtin_amdgcn_mfma_f32_16x16x32_bf16(af[m], bfr[n], acc[m][n], 0, 0, 0);
        }
    }
#pragma unroll
    for (int m = 0; m < 4; ++m) {
        int t = rb + wr + m * 16 + g * 4;
#pragma unroll
        for (int r = 0; r < 4; ++r) {
#pragma unroll
            for (int n = 0; n < 4; ++n) {
                int col = cb + wc + n * 16 + li;
                out[(size_t)(t + r) * 1024 + col] = acc[m][n][r];
            }
        }
    }
}

// ---------------------------------------------------------------------------
extern "C" void kernel_launch(void* const* d_in, const int* in_sizes, int n_in,
                              void* d_out, int out_size, void* d_ws, size_t ws_size,
                              hipStream_t stream)
{
    const float* x     = (const float*)d_in[0];
    const float* Wq    = (const float*)d_in[1];
    const float* Wk    = (const float*)d_in[2];
    const float* Wv    = (const float*)d_in[3];
    const float* Wlr   = (const float*)d_in[4];
    const float* Wbeta = (const float*)d_in[5];
    const float* Wo    = (const float*)d_in[6];
    const float* Wi0   = (const float*)d_in[7];
    const float* Wo0   = (const float*)d_in[8];
    float* out = (float*)d_out;

    char* od = (char*)d_out;
    u16* xb  = (u16*)(od);                 // dead before out_proj overwrites
    u16* wb  = (u16*)(od + 33554432u);
    u16* wlb = (u16*)(od + 39845888u);

    char* ws = (char*)d_ws;
    u16* qb        = (u16*)(ws);
    u16* kb        = (u16*)(ws + 33554432u);
    u16* vb        = (u16*)(ws + 67108864u);
    u16* obuf      = (u16*)(ws + 100663296u);
    float* lrc_all = (float*)(ws + 134217728u);
    u16* wob       = (u16*)(ws + 134283264u);
    if (ws_size < 136380416u) return;

    convert_kernel<<<2048, 256, 0, stream>>>(x, Wq, Wk, Wv, Wo, Wlr, Wbeta,
                                             xb, wb, wob, wlb);
    proj_qkv_kernel<<<dim3(24, 128), 256, 0, stream>>>(xb, wb, qb, kb, vb);
    lrwd_kernel<<<128, 256, 0, stream>>>(xb, wlb, lrc_all);
    scan_kernel<<<64, 512, 0, stream>>>(qb, kb, vb, lrc_all, Wi0, Wo0, obuf);
    out_proj_kernel<<<dim3(8, 128), 256, 0, stream>>>(obuf, wob, out);
}

// Round 11
// 508.513 us; speedup vs baseline: 1.5808x; 1.1323x over previous
//
#include <hip/hip_runtime.h>
#include <stdint.h>

typedef unsigned short u16;
typedef uint32_t u32;
typedef __attribute__((ext_vector_type(4))) float f32x4;
typedef __attribute__((ext_vector_type(8))) short bf16x8;

#define DEVINL __device__ __forceinline__

DEVINL u16 f2bf(float f) {
    union { float f; u32 u; } a; a.f = f;
    u32 u = a.u;
    return (u16)((u + 0x7fffu + ((u >> 16) & 1u)) >> 16);   // RNE
}
DEVINL u32 pk2(float a, float b) { return (u32)f2bf(a) | ((u32)f2bf(b) << 16); }

// 128B-row swizzled tile (conflict-free vector row reads) — verified R2..R10
DEVINL u32 swz128(u32 row, u32 colb) { return row * 128u + (colb ^ ((row & 7u) << 4)); }

// async global->LDS, 16B per lane
DEVINL void gload_lds16(const u16* g, char* l) {
    __builtin_amdgcn_global_load_lds(
        (const __attribute__((address_space(1))) void*)g,
        (__attribute__((address_space(3))) void*)l, 16, 0, 0);
}

// ---- DPP cross-lane (VALU pipe, replaces ds_bpermute-based __shfl_xor) ----
// quad_perm 0xB1 = [1,0,3,2] (exact xor1 in quads); 0x4E = [2,3,0,1] (xor2).
// row_ror 0x121/0x122/0x124/0x128 = rotate within 16-lane row by 1/2/4/8.
template<int C> DEVINL float fdpp(float x) {
    union { float f; int i; } a, b; a.f = x;
    b.i = __builtin_amdgcn_update_dpp(0, a.i, C, 0xf, 0xf, false);
    return b.f;
}
DEVINL float rmax16(float v) {
    v = fmaxf(v, fdpp<0x128>(v)); v = fmaxf(v, fdpp<0x124>(v));
    v = fmaxf(v, fdpp<0x122>(v)); v = fmaxf(v, fdpp<0x121>(v)); return v;
}
DEVINL float rsum16(float v) {
    v += fdpp<0x128>(v); v += fdpp<0x124>(v);
    v += fdpp<0x122>(v); v += fdpp<0x121>(v); return v;
}

// 4x4 transpose among 4 lanes (lane&3) over the 4 regs of v — same index
// algebra as the R4-verified shfl version, cross-lane moves now DPP quad_perm.
DEVINL f32x4 trans4(f32x4 v, int q) {
    float s0 = fdpp<0xB1>(v[0]), s1 = fdpp<0xB1>(v[1]),
          s2 = fdpp<0xB1>(v[2]), s3 = fdpp<0xB1>(v[3]);
    f32x4 t;
    bool q1 = (q & 1) != 0;
    t[0] = q1 ? s1 : v[0];
    t[1] = q1 ? v[1] : s0;
    t[2] = q1 ? s3 : v[2];
    t[3] = q1 ? v[3] : s2;
    float u0 = fdpp<0x4E>(t[0]), u1 = fdpp<0x4E>(t[1]),
          u2 = fdpp<0x4E>(t[2]), u3 = fdpp<0x4E>(t[3]);
    f32x4 r;
    bool q2 = (q & 2) != 0;
    r[0] = q2 ? u2 : t[0];
    r[1] = q2 ? u3 : t[1];
    r[2] = q2 ? t[2] : u0;
    r[3] = q2 ? t[3] : u1;
    return r;
}

// ---------------------------------------------------------------------------
// Kernel 0: fp32 -> bf16 convert pass
// ---------------------------------------------------------------------------
__global__ __launch_bounds__(256) void convert_kernel(
    const float* __restrict__ x, const float* __restrict__ Wq,
    const float* __restrict__ Wk, const float* __restrict__ Wv,
    const float* __restrict__ Wo, const float* __restrict__ Wlr,
    const float* __restrict__ Wbeta,
    u16* __restrict__ xb, u16* __restrict__ wb, u16* __restrict__ wob,
    u16* __restrict__ wlb)
{
    const int t0 = blockIdx.x * 256 + threadIdx.x;
    const int stride = gridDim.x * 256;
    auto cv = [&](const float* src, u16* dst, int n4) {
        for (int i = t0; i < n4; i += stride) {
            float4 v = ((const float4*)src)[i];
            uint2 p;
            p.x = pk2(v.x, v.y);
            p.y = pk2(v.z, v.w);
            ((uint2*)dst)[i] = p;
        }
    };
    cv(x, xb, 4194304);
    cv(Wq, wb, 262144);
    cv(Wk, wb + 1048576, 262144);
    cv(Wv, wb + 2097152, 262144);
    cv(Wo, wob, 262144);
    cv(Wlr, wlb, 8192);
    cv(Wbeta, wlb + 32768, 8192);
}

// ---------------------------------------------------------------------------
// Kernel A: q/k/v projections (swizzled LDS, R10-verified)
// ---------------------------------------------------------------------------
__global__ __launch_bounds__(256) void proj_qkv_kernel(
    const u16* __restrict__ xb, const u16* __restrict__ wb,
    u16* __restrict__ qb, u16* __restrict__ kb, u16* __restrict__ vb)
{
    __shared__ __align__(16) char As[128 * 128];
    __shared__ __align__(16) char Bs[128 * 128];
    const int bn = blockIdx.x;
    const int bm = blockIdx.y;
    const int wsel = bn >> 3;
    u16* __restrict__ dst = (wsel == 0) ? qb : ((wsel == 1) ? kb : vb);
    const int cb = (bn & 7) * 128;
    const int wrow = bn * 128;
    const int rb = bm * 128;
    const int tid = threadIdx.x;
    const int lane = tid & 63;
    const int wv = tid >> 6;
    const int wr = (wv >> 1) * 64, wc = (wv & 1) * 64;
    const int li = lane & 15, g = lane >> 4;
    const int lr8 = lane >> 3, lc8 = lane & 7;

    f32x4 acc[4][4];
#pragma unroll
    for (int i = 0; i < 4; ++i)
#pragma unroll
        for (int j = 0; j < 4; ++j) acc[i][j] = (f32x4)0.0f;

    for (int k0 = 0; k0 < 1024; k0 += 64) {
        __syncthreads();
#pragma unroll
        for (int ld = 0; ld < 4; ++ld) {
            int r0 = wv * 32 + ld * 8;
            int rowT = r0 + lr8;
            int csw = (lc8 * 8) ^ ((rowT & 7) << 3);
            gload_lds16(xb + (size_t)(rb + rowT) * 1024 + k0 + csw, As + r0 * 128);
            gload_lds16(wb + (size_t)(wrow + rowT) * 1024 + k0 + csw, Bs + r0 * 128);
        }
        __syncthreads();
#pragma unroll
        for (int ks = 0; ks < 2; ++ks) {
            bf16x8 af[4], bfr[4];
#pragma unroll
            for (int m = 0; m < 4; ++m)
                af[m] = *(const bf16x8*)(As + swz128(wr + m * 16 + li, ks * 64 + g * 16));
#pragma unroll
            for (int n = 0; n < 4; ++n)
                bfr[n] = *(const bf16x8*)(Bs + swz128(wc + n * 16 + li, ks * 64 + g * 16));
#pragma unroll
            for (int m = 0; m < 4; ++m)
#pragma unroll
                for (int n = 0; n < 4; ++n)
                    acc[m][n] = __builtin_amdgcn_mfma_f32_16x16x32_bf16(af[m], bfr[n], acc[m][n], 0, 0, 0);
        }
    }
    const bool do_silu = (wsel < 2);
#pragma unroll
    for (int m = 0; m < 4; ++m) {
        int t = rb + wr + m * 16 + g * 4;
#pragma unroll
        for (int r = 0; r < 4; ++r) {
#pragma unroll
            for (int n = 0; n < 4; ++n) {
                float v = acc[m][n][r];
                if (do_silu) v = v / (1.0f + __expf(-v));
                int col = cb + wc + n * 16 + li;
                dst[(size_t)(t + r) * 1024 + col] = f2bf(v);
            }
        }
    }
}

// ---------------------------------------------------------------------------
// Kernel B: lr/wd heads (swizzled R10)
// ---------------------------------------------------------------------------
__global__ __launch_bounds__(256) void lrwd_kernel(
    const u16* __restrict__ xb, const u16* __restrict__ wlb,
    float* __restrict__ lrc_all)
{
    __shared__ __align__(16) char As[128 * 128];
    __shared__ __align__(16) char Bs[64 * 128];
    __shared__ float red[128][65];
    const int bm = blockIdx.x;
    const int rb = bm * 128;
    const int tid = threadIdx.x;
    const int lane = tid & 63;
    const int wv = tid >> 6;
    const int li = lane & 15, g = lane >> 4;
    const int lr8 = lane >> 3, lc8 = lane & 7;

    f32x4 acc[2][4];
#pragma unroll
    for (int i = 0; i < 2; ++i)
#pragma unroll
        for (int j = 0; j < 4; ++j) acc[i][j] = (f32x4)0.0f;

    for (int k0 = 0; k0 < 1024; k0 += 64) {
        __syncthreads();
#pragma unroll
        for (int ld = 0; ld < 4; ++ld) {
            int r0 = wv * 32 + ld * 8;
            int rowT = r0 + lr8;
            int csw = (lc8 * 8) ^ ((rowT & 7) << 3);
            gload_lds16(xb + (size_t)(rb + rowT) * 1024 + k0 + csw, As + r0 * 128);
        }
#pragma unroll
        for (int ld = 0; ld < 2; ++ld) {
            int r0 = wv * 16 + ld * 8;
            int rowT = r0 + lr8;
            int csw = (lc8 * 8) ^ ((rowT & 7) << 3);
            gload_lds16(wlb + (size_t)rowT * 1024 + k0 + csw, Bs + r0 * 128);
        }
        __syncthreads();
#pragma unroll
        for (int ks = 0; ks < 2; ++ks) {
            bf16x8 af[2], bfr[4];
#pragma unroll
            for (int m = 0; m < 2; ++m)
                af[m] = *(const bf16x8*)(As + swz128(wv * 32 + m * 16 + li, ks * 64 + g * 16));
#pragma unroll
            for (int n = 0; n < 4; ++n)
                bfr[n] = *(const bf16x8*)(Bs + swz128(n * 16 + li, ks * 64 + g * 16));
#pragma unroll
            for (int m = 0; m < 2; ++m)
#pragma unroll
                for (int n = 0; n < 4; ++n)
                    acc[m][n] = __builtin_amdgcn_mfma_f32_16x16x32_bf16(af[m], bfr[n], acc[m][n], 0, 0, 0);
        }
    }
#pragma unroll
    for (int m = 0; m < 2; ++m) {
#pragma unroll
        for (int n = 0; n < 4; ++n) {
            int col = n * 16 + li;
            float scale = (col < 32) ? 1e-3f : 0.9f;
#pragma unroll
            for (int r = 0; r < 4; ++r) {
                int t = wv * 32 + m * 16 + g * 4 + r;
                float s = acc[m][n][r];
                red[t][col] = scale / (1.0f + __expf(-s));
            }
        }
    }
    __syncthreads();
    if (tid < 128) {
        int chunk = tid >> 6, col = tid & 63;
        float s = 0.f;
#pragma unroll
        for (int i = 0; i < 64; ++i) s += red[chunk * 64 + i][col];
        int b = bm >> 5;
        int cidx = (bm & 31) * 2 + chunk;
        lrc_all[((size_t)(b * 64 + cidx)) * 64 + col] = s * (1.0f / 64.0f);
    }
}

// ---------------------------------------------------------------------------
// Kernel C: chunk scan — R9/R10 structure; all 16-lane reduces and 4-lane
// transposes moved from __shfl_xor (ds_bpermute / LDS pipe) to DPP (VALU).
// ---------------------------------------------------------------------------
__global__ __launch_bounds__(512) void scan_kernel(
    const u16* __restrict__ qb, const u16* __restrict__ kb, const u16* __restrict__ vb,
    const float* __restrict__ lrc_all, const float* __restrict__ Wi0,
    const float* __restrict__ Wo0, u16* __restrict__ ob)
{
    const int bh = blockIdx.x;
    const int b = bh >> 4, h = bh & 15;
    const int tid = threadIdx.x;
    const int lane = tid & 63;
    const int w8 = tid >> 6;            // 0..7
    const bool isA = (w8 < 4);
    const int wq = w8;
    const int wk = w8 - 4;
    const int li = lane & 15, g = lane >> 4;
    const int q4 = li & 3, b4 = li & 12;

    __shared__ __align__(16) char SQ2[2][8192];
    __shared__ __align__(16) char Kc2[2][8192];
    __shared__ __align__(16) char Vc2[2][8192];
    __shared__ __align__(16) char KcT2[2][8192];
    __shared__ __align__(16) char VcT2[2][8192];
    __shared__ __align__(16) char SWoT2[2][8192];
    __shared__ __align__(16) char SWiN[8192];
    __shared__ __align__(16) char SWoN[8192];
    __shared__ __align__(16) char SPQ[8192];
    __shared__ __align__(16) char SPTN[8192];
    __shared__ __align__(16) char SGZN[8192];
    __shared__ float spart[256];
    __shared__ float lrc[256];
    __shared__ u32 cntA, cntB;

    if (tid == 0) { cntA = 0u; cntB = 0u; }

    f32x4 WiR[4], WoR[4];
    if (!isA) {
#pragma unroll
        for (int tn = 0; tn < 4; ++tn) {
            int d = tn * 16 + li;
#pragma unroll
            for (int r = 0; r < 4; ++r) {
                int D = wk * 16 + g * 4 + r;
                WiR[tn][r] = Wi0[((size_t)D * 16 + h) * 64 + d];
                WoR[tn][r] = Wo0[((size_t)D * 16 + h) * 64 + d];
            }
            *(uint2*)(SWoT2[0] + swz128(d, wk * 32 + g * 8)) =
                make_uint2(pk2(WoR[tn][0], WoR[tn][1]), pk2(WoR[tn][2], WoR[tn][3]));
            f32x4 ti = trans4(WiR[tn], q4);
            *(uint2*)(SWiN + swz128(wk * 16 + g * 4 + q4, tn * 32 + b4 * 2)) =
                make_uint2(pk2(ti[0], ti[1]), pk2(ti[2], ti[3]));
            f32x4 to = trans4(WoR[tn], q4);
            *(uint2*)(SWoN + swz128(wk * 16 + g * 4 + q4, tn * 32 + b4 * 2)) =
                make_uint2(pk2(to[0], to[1]), pk2(to[2], to[3]));
        }
    }
    if (tid < 256) {
        int cc = tid >> 2, j = tid & 3;
        lrc[cc * 4 + j] = lrc_all[((size_t)(b * 64 + cc)) * 64 + j * 16 + h];
    }

    const int nb4 = ((tid & 255) >> 4) * 4;
    const int db4 = (tid & 15) * 4;
    uint4 pq_[2];
    uint2 pk_[4], pv_[4];
    auto prefetch = [&](int c) {
        const size_t base = ((size_t)(b * 4096 + c * 64)) * 1024 + h * 64;
#pragma unroll
        for (int p = 0; p < 2; ++p) {
            int id = p * 256 + (tid & 255);
            int n = id >> 3;
            int d0 = (id & 7) * 8;
            pq_[p] = *(const uint4*)(qb + base + (size_t)n * 1024 + d0);
        }
#pragma unroll
        for (int j = 0; j < 4; ++j) {
            pk_[j] = *(const uint2*)(kb + base + (size_t)(nb4 + j) * 1024 + db4);
            pv_[j] = *(const uint2*)(vb + base + (size_t)(nb4 + j) * 1024 + db4);
        }
    };
    auto commit = [&](int buf) {
#pragma unroll
        for (int p = 0; p < 2; ++p) {
            int id = p * 256 + (tid & 255);
            int n = id >> 3;
            int d0 = (id & 7) * 8;
            *(uint4*)(SQ2[buf] + swz128(n, d0 * 2)) = pq_[p];
        }
#pragma unroll
        for (int j = 0; j < 4; ++j) {
            *(uint2*)(Kc2[buf] + swz128(nb4 + j, db4 * 2)) = pk_[j];
            *(uint2*)(Vc2[buf] + swz128(nb4 + j, db4 * 2)) = pv_[j];
        }
#pragma unroll
        for (int i = 0; i < 4; ++i) {
            u32 k0 = (((i & 2) ? pk_[0].y : pk_[0].x) >> ((i & 1) * 16)) & 0xffffu;
            u32 k1 = (((i & 2) ? pk_[1].y : pk_[1].x) >> ((i & 1) * 16)) & 0xffffu;
            u32 k2 = (((i & 2) ? pk_[2].y : pk_[2].x) >> ((i & 1) * 16)) & 0xffffu;
            u32 k3 = (((i & 2) ? pk_[3].y : pk_[3].x) >> ((i & 1) * 16)) & 0xffffu;
            *(uint2*)(KcT2[buf] + swz128(db4 + i, nb4 * 2)) =
                make_uint2(k0 | (k1 << 16), k2 | (k3 << 16));
            u32 v0 = (((i & 2) ? pv_[0].y : pv_[0].x) >> ((i & 1) * 16)) & 0xffffu;
            u32 v1 = (((i & 2) ? pv_[1].y : pv_[1].x) >> ((i & 1) * 16)) & 0xffffu;
            u32 v2 = (((i & 2) ? pv_[2].y : pv_[2].x) >> ((i & 1) * 16)) & 0xffffu;
            u32 v3 = (((i & 2) ? pv_[3].y : pv_[3].x) >> ((i & 1) * 16)) & 0xffffu;
            *(uint2*)(VcT2[buf] + swz128(db4 + i, nb4 * 2)) =
                make_uint2(v0 | (v1 << 16), v2 | (v3 << 16));
        }
    };

    if (isA) { prefetch(0); commit(0); }
    __syncthreads();

    for (int c = 0; c < 64; ++c) {
        const int cur = c & 1, nxt = cur ^ 1;
        f32x4 pk[4], aT[4], go[4];

        if (isA) {
            if (c + 1 < 64) prefetch(c + 1);
            bf16x8 wiA0 = *(const bf16x8*)(SWiN + swz128(wq * 16 + li, g * 16));
            bf16x8 wiA1 = *(const bf16x8*)(SWiN + swz128(wq * 16 + li, 64 + g * 16));
            f32x4 sq[4];
            __builtin_amdgcn_s_setprio(1);
#pragma unroll
            for (int tn = 0; tn < 4; ++tn) {
                bf16x8 b0 = *(const bf16x8*)(SQ2[cur] + swz128(tn * 16 + li, g * 16));
                bf16x8 b1 = *(const bf16x8*)(SQ2[cur] + swz128(tn * 16 + li, 64 + g * 16));
                f32x4 z = (f32x4)0.0f;
                z = __builtin_amdgcn_mfma_f32_16x16x32_bf16(wiA0, b0, z, 0, 0, 0);
                z = __builtin_amdgcn_mfma_f32_16x16x32_bf16(wiA1, b1, z, 0, 0, 0);
                sq[tn] = z;
            }
            __builtin_amdgcn_s_setprio(0);
#pragma unroll
            for (int r = 0; r < 4; ++r) {
                float m = fmaxf(fmaxf(sq[0][r], sq[1][r]), fmaxf(sq[2][r], sq[3][r]));
                m = rmax16(m);
                float e0 = __expf(sq[0][r] - m), e1 = __expf(sq[1][r] - m);
                float e2 = __expf(sq[2][r] - m), e3 = __expf(sq[3][r] - m);
                float s = rsum16(e0 + e1 + e2 + e3);
                float inv = 1.0f / s;
                sq[0][r] = e0 * inv; sq[1][r] = e1 * inv; sq[2][r] = e2 * inv; sq[3][r] = e3 * inv;
            }
#pragma unroll
            for (int tn = 0; tn < 4; ++tn) {
                int n = tn * 16 + li;
                *(uint2*)(SPQ + swz128(n, (wq * 16 + g * 4) * 2)) =
                    make_uint2(pk2(sq[tn][0], sq[tn][1]), pk2(sq[tn][2], sq[tn][3]));
            }
            __threadfence_block();
            if (lane == 0) atomicAdd(&cntA, 1u);
            {
                volatile u32* vc = &cntA;
                u32 tgt = 4u * (u32)(c + 1);
                while (*vc < tgt) { __builtin_amdgcn_s_sleep(1); }
            }
            __threadfence_block();
        } else {
            bf16x8 wiA0 = *(const bf16x8*)(SWiN + swz128(wk * 16 + li, g * 16));
            bf16x8 wiA1 = *(const bf16x8*)(SWiN + swz128(wk * 16 + li, 64 + g * 16));
            __builtin_amdgcn_s_setprio(1);
#pragma unroll
            for (int tn = 0; tn < 4; ++tn) {
                bf16x8 b0 = *(const bf16x8*)(Kc2[cur] + swz128(tn * 16 + li, g * 16));
                bf16x8 b1 = *(const bf16x8*)(Kc2[cur] + swz128(tn * 16 + li, 64 + g * 16));
                f32x4 z = (f32x4)0.0f;
                z = __builtin_amdgcn_mfma_f32_16x16x32_bf16(wiA0, b0, z, 0, 0, 0);
                z = __builtin_amdgcn_mfma_f32_16x16x32_bf16(wiA1, b1, z, 0, 0, 0);
                pk[tn] = z;
            }
            __builtin_amdgcn_s_setprio(0);
#pragma unroll
            for (int r = 0; r < 4; ++r) {
                float m = fmaxf(fmaxf(pk[0][r], pk[1][r]), fmaxf(pk[2][r], pk[3][r]));
                m = rmax16(m);
                float e0 = __expf(pk[0][r] - m), e1 = __expf(pk[1][r] - m);
                float e2 = __expf(pk[2][r] - m), e3 = __expf(pk[3][r] - m);
                float s = rsum16(e0 + e1 + e2 + e3);
                float inv = 1.0f / s;
                pk[0][r] = e0 * inv; pk[1][r] = e1 * inv; pk[2][r] = e2 * inv; pk[3][r] = e3 * inv;
            }
            bf16x8 woA0 = *(const bf16x8*)(SWoN + swz128(wk * 16 + li, g * 16));
            bf16x8 woA1 = *(const bf16x8*)(SWoN + swz128(wk * 16 + li, 64 + g * 16));
            __builtin_amdgcn_s_setprio(1);
#pragma unroll
            for (int tn = 0; tn < 4; ++tn) {
                bf16x8 b0 = *(const bf16x8*)(Vc2[cur] + swz128(tn * 16 + li, g * 16));
                bf16x8 b1 = *(const bf16x8*)(Vc2[cur] + swz128(tn * 16 + li, 64 + g * 16));
                f32x4 z = (f32x4)0.0f;
                z = __builtin_amdgcn_mfma_f32_16x16x32_bf16(woA0, b0, z, 0, 0, 0);
                z = __builtin_amdgcn_mfma_f32_16x16x32_bf16(woA1, b1, z, 0, 0, 0);
                aT[tn] = z;
            }
            __builtin_amdgcn_s_setprio(0);
#pragma unroll
            for (int tn = 0; tn < 4; ++tn) {
                f32x4 t4 = pk[tn] * aT[tn];
                float s_ = t4[0] + t4[1] + t4[2] + t4[3];
                s_ += __shfl_xor(s_, 16);
                s_ += __shfl_xor(s_, 32);
                if (g == 0) spart[wk * 64 + tn * 16 + li] = s_;
            }
#pragma unroll
            for (int tn = 0; tn < 4; ++tn) {
                f32x4 tp = trans4(pk[tn], q4);
                *(uint2*)(SPTN + swz128(wk * 16 + g * 4 + q4, tn * 32 + b4 * 2)) =
                    make_uint2(pk2(tp[0], tp[1]), pk2(tp[2], tp[3]));
            }
            {
                bf16x8 a0 = *(const bf16x8*)(SPTN + swz128(wk * 16 + li, g * 16));
                bf16x8 a1 = *(const bf16x8*)(SPTN + swz128(wk * 16 + li, 64 + g * 16));
                __builtin_amdgcn_s_setprio(1);
#pragma unroll
                for (int tn = 0; tn < 4; ++tn) {
                    bf16x8 b0 = *(const bf16x8*)(VcT2[cur] + swz128(tn * 16 + li, g * 16));
                    bf16x8 b1 = *(const bf16x8*)(VcT2[cur] + swz128(tn * 16 + li, 64 + g * 16));
                    f32x4 z = (f32x4)0.0f;
                    z = __builtin_amdgcn_mfma_f32_16x16x32_bf16(a0, b0, z, 0, 0, 0);
                    z = __builtin_amdgcn_mfma_f32_16x16x32_bf16(a1, b1, z, 0, 0, 0);
                    go[tn] = z;
                }
                __builtin_amdgcn_s_setprio(0);
            }
            __threadfence_block();
            if (lane == 0) atomicAdd(&cntB, 1u);
            {
                volatile u32* vc = &cntB;
                u32 tgt = 4u * (u32)(c + 1);
                while (*vc < tgt) { __builtin_amdgcn_s_sleep(1); }
            }
            __threadfence_block();
        }

        if (isA) {
            bf16x8 a0 = *(const bf16x8*)(SPQ + swz128(wq * 16 + li, g * 16));
            bf16x8 a1 = *(const bf16x8*)(SPQ + swz128(wq * 16 + li, 64 + g * 16));
            f32x4 o4[4];
            __builtin_amdgcn_s_setprio(1);
#pragma unroll
            for (int tn = 0; tn < 4; ++tn) {
                bf16x8 b0 = *(const bf16x8*)(SWoT2[cur] + swz128(tn * 16 + li, g * 16));
                bf16x8 b1 = *(const bf16x8*)(SWoT2[cur] + swz128(tn * 16 + li, 64 + g * 16));
                f32x4 z = (f32x4)0.0f;
                z = __builtin_amdgcn_mfma_f32_16x16x32_bf16(a0, b0, z, 0, 0, 0);
                z = __builtin_amdgcn_mfma_f32_16x16x32_bf16(a1, b1, z, 0, 0, 0);
                o4[tn] = z;
            }
            __builtin_amdgcn_s_setprio(0);
            const size_t obase = ((size_t)(b * 4096 + c * 64)) * 1024 + h * 64;
            const int n_ = wq * 16 + g * 4 + q4;
#pragma unroll
            for (int tn = 0; tn < 4; ++tn) {
                f32x4 to = trans4(o4[tn], q4);
                *(uint2*)(ob + obase + (size_t)n_ * 1024 + tn * 16 + b4) =
                    make_uint2(pk2(to[0], to[1]), pk2(to[2], to[3]));
            }
            if (c + 1 < 64) commit(nxt);
        } else {
            f32x4 gz[4];
#pragma unroll
            for (int tn = 0; tn < 4; ++tn) {
                int n = tn * 16 + li;
                float sn = spart[n] + spart[64 + n] + spart[128 + n] + spart[192 + n];
#pragma unroll
                for (int r = 0; r < 4; ++r) gz[tn][r] = pk[tn][r] * (sn - aT[tn][r]);
                f32x4 tg = trans4(gz[tn], q4);
                *(uint2*)(SGZN + swz128(wk * 16 + g * 4 + q4, tn * 32 + b4 * 2)) =
                    make_uint2(pk2(tg[0], tg[1]), pk2(tg[2], tg[3]));
            }
            f32x4 gi[4];
            {
                bf16x8 a0 = *(const bf16x8*)(SGZN + swz128(wk * 16 + li, g * 16));
                bf16x8 a1 = *(const bf16x8*)(SGZN + swz128(wk * 16 + li, 64 + g * 16));
                __builtin_amdgcn_s_setprio(1);
#pragma unroll
                for (int tn = 0; tn < 4; ++tn) {
                    bf16x8 b0 = *(const bf16x8*)(KcT2[cur] + swz128(tn * 16 + li, g * 16));
                    bf16x8 b1 = *(const bf16x8*)(KcT2[cur] + swz128(tn * 16 + li, 64 + g * 16));
                    f32x4 z = (f32x4)0.0f;
                    z = __builtin_amdgcn_mfma_f32_16x16x32_bf16(a0, b0, z, 0, 0, 0);
                    z = __builtin_amdgcn_mfma_f32_16x16x32_bf16(a1, b1, z, 0, 0, 0);
                    gi[tn] = z;
                }
                __builtin_amdgcn_s_setprio(0);
            }
            if (c + 1 < 64) {
                float lin = lrc[c * 4 + 0], lout = lrc[c * 4 + 1];
                float win = lrc[c * 4 + 2], wout = lrc[c * 4 + 3];
#pragma unroll
                for (int tn = 0; tn < 4; ++tn) {
                    WiR[tn] = win * WiR[tn] - lin * gi[tn];
                    WoR[tn] = wout * WoR[tn] + lout * go[tn];   // grad_out = -go
                    int d = tn * 16 + li;
                    *(uint2*)(SWoT2[nxt] + swz128(d, wk * 32 + g * 8)) =
                        make_uint2(pk2(WoR[tn][0], WoR[tn][1]), pk2(WoR[tn][2], WoR[tn][3]));
                    f32x4 ti = trans4(WiR[tn], q4);
                    *(uint2*)(SWiN + swz128(wk * 16 + g * 4 + q4, tn * 32 + b4 * 2)) =
                        make_uint2(pk2(ti[0], ti[1]), pk2(ti[2], ti[3]));
                    f32x4 to = trans4(WoR[tn], q4);
                    *(uint2*)(SWoN + swz128(wk * 16 + g * 4 + q4, tn * 32 + b4 * 2)) =
                        make_uint2(pk2(to[0], to[1]), pk2(to[2], to[3]));
                }
            }
        }
        __syncthreads();
    }
}

// ---------------------------------------------------------------------------
// Kernel D: out_proj (swizzled R10)
// ---------------------------------------------------------------------------
__global__ __launch_bounds__(256) void out_proj_kernel(
    const u16* __restrict__ ob, const u16* __restrict__ wob, float* __restrict__ out)
{
    __shared__ __align__(16) char As[128 * 128];
    __shared__ __align__(16) char Bs[128 * 128];
    const int bn = blockIdx.x;
    const int bm = blockIdx.y;
    const int cb = bn * 128;
    const int rb = bm * 128;
    const int tid = threadIdx.x;
    const int lane = tid & 63;
    const int wv = tid >> 6;
    const int wr = (wv >> 1) * 64, wc = (wv & 1) * 64;
    const int li = lane & 15, g = lane >> 4;
    const int lr8 = lane >> 3, lc8 = lane & 7;

    f32x4 acc[4][4];
#pragma unroll
    for (int i = 0; i < 4; ++i)
#pragma unroll
        for (int j = 0; j < 4; ++j) acc[i][j] = (f32x4)0.0f;

    for (int k0 = 0; k0 < 1024; k0 += 64) {
        __syncthreads();
#pragma unroll
        for (int ld = 0; ld < 4; ++ld) {
            int r0 = wv * 32 + ld * 8;
            int rowT = r0 + lr8;
            int csw = (lc8 * 8) ^ ((rowT & 7) << 3);
            gload_lds16(ob + (size_t)(rb + rowT) * 1024 + k0 + csw, As + r0 * 128);
            gload_lds16(wob + (size_t)(cb + rowT) * 1024 + k0 + csw, Bs + r0 * 128);
        }
        __syncthreads();
#pragma unroll
        for (int ks = 0; ks < 2; ++ks) {
            bf16x8 af[4], bfr[4];
#pragma unroll
            for (int m = 0; m < 4; ++m)
                af[m] = *(const bf16x8*)(As + swz128(wr + m * 16 + li, ks * 64 + g * 16));
#pragma unroll
            for (int n = 0; n < 4; ++n)
                bfr[n] = *(const bf16x8*)(Bs + swz128(wc + n * 16 + li, ks * 64 + g * 16));
#pragma unroll
            for (int m = 0; m < 4; ++m)
#pragma unroll
                for (int n = 0; n < 4; ++n)
                    acc[m][n] = __builtin_amdgcn_mfma_f32_16x16x32_bf16(af[m], bfr[n], acc[m][n], 0, 0, 0);
        }
    }
#pragma unroll
    for (int m = 0; m < 4; ++m) {
        int t = rb + wr + m * 16 + g * 4;
#pragma unroll
        for (int r = 0; r < 4; ++r) {
#pragma unroll
            for (int n = 0; n < 4; ++n) {
                int col = cb + wc + n * 16 + li;
                out[(size_t)(t + r) * 1024 + col] = acc[m][n][r];
            }
        }
    }
}

// ---------------------------------------------------------------------------
extern "C" void kernel_launch(void* const* d_in, const int* in_sizes, int n_in,
                              void* d_out, int out_size, void* d_ws, size_t ws_size,
                              hipStream_t stream)
{
    const float* x     = (const float*)d_in[0];
    const float* Wq    = (const float*)d_in[1];
    const float* Wk    = (const float*)d_in[2];
    const float* Wv    = (const float*)d_in[3];
    const float* Wlr   = (const float*)d_in[4];
    const float* Wbeta = (const float*)d_in[5];
    const float* Wo    = (const float*)d_in[6];
    const float* Wi0   = (const float*)d_in[7];
    const float* Wo0   = (const float*)d_in[8];
    float* out = (float*)d_out;

    char* od = (char*)d_out;
    u16* xb  = (u16*)(od);                 // dead before out_proj overwrites
    u16* wb  = (u16*)(od + 33554432u);
    u16* wlb = (u16*)(od + 39845888u);

    char* ws = (char*)d_ws;
    u16* qb        = (u16*)(ws);
    u16* kb        = (u16*)(ws + 33554432u);
    u16* vb        = (u16*)(ws + 67108864u);
    u16* obuf      = (u16*)(ws + 100663296u);
    float* lrc_all = (float*)(ws + 134217728u);
    u16* wob       = (u16*)(ws + 134283264u);
    if (ws_size < 136380416u) return;

    convert_kernel<<<2048, 256, 0, stream>>>(x, Wq, Wk, Wv, Wo, Wlr, Wbeta,
                                             xb, wb, wob, wlb);
    proj_qkv_kernel<<<dim3(24, 128), 256, 0, stream>>>(xb, wb, qb, kb, vb);
    lrwd_kernel<<<128, 256, 0, stream>>>(xb, wlb, lrc_all);
    scan_kernel<<<64, 512, 0, stream>>>(qb, kb, vb, lrc_all, Wi0, Wo0, obuf);
    out_proj_kernel<<<dim3(8, 128), 256, 0, stream>>>(obuf, wob, out);
}

// Round 12
// 503.995 us; speedup vs baseline: 1.5949x; 1.0090x over previous
//
#include <hip/hip_runtime.h>
#include <stdint.h>

typedef unsigned short u16;
typedef uint32_t u32;
typedef __attribute__((ext_vector_type(4))) float f32x4;
typedef __attribute__((ext_vector_type(8))) short bf16x8;

#define DEVINL __device__ __forceinline__

DEVINL u16 f2bf(float f) {
    union { float f; u32 u; } a; a.f = f;
    u32 u = a.u;
    return (u16)((u + 0x7fffu + ((u >> 16) & 1u)) >> 16);   // RNE
}
DEVINL u32 pk2(float a, float b) { return (u32)f2bf(a) | ((u32)f2bf(b) << 16); }

// 128B-row swizzled tile (conflict-free vector row reads) — verified R2..R11
DEVINL u32 swz128(u32 row, u32 colb) { return row * 128u + (colb ^ ((row & 7u) << 4)); }

// async global->LDS, 16B per lane
DEVINL void gload_lds16(const u16* g, char* l) {
    __builtin_amdgcn_global_load_lds(
        (const __attribute__((address_space(1))) void*)g,
        (__attribute__((address_space(3))) void*)l, 16, 0, 0);
}

// fast reciprocal (v_rcp_f32, ~1ulp) — softmax denominators are in [1,64]
DEVINL float frcp(float x) { float r; asm("v_rcp_f32 %0, %1" : "=v"(r) : "v"(x)); return r; }

// ---- DPP cross-lane (VALU pipe) — verified R11 ----
template<int C> DEVINL float fdpp(float x) {
    union { float f; int i; } a, b; a.f = x;
    b.i = __builtin_amdgcn_update_dpp(0, a.i, C, 0xf, 0xf, false);
    return b.f;
}
DEVINL float rmax16(float v) {
    v = fmaxf(v, fdpp<0x128>(v)); v = fmaxf(v, fdpp<0x124>(v));
    v = fmaxf(v, fdpp<0x122>(v)); v = fmaxf(v, fdpp<0x121>(v)); return v;
}
DEVINL float rsum16(float v) {
    v += fdpp<0x128>(v); v += fdpp<0x124>(v);
    v += fdpp<0x122>(v); v += fdpp<0x121>(v); return v;
}

// 4x4 transpose among 4 lanes via DPP quad_perm — verified R11
DEVINL f32x4 trans4(f32x4 v, int q) {
    float s0 = fdpp<0xB1>(v[0]), s1 = fdpp<0xB1>(v[1]),
          s2 = fdpp<0xB1>(v[2]), s3 = fdpp<0xB1>(v[3]);
    f32x4 t;
    bool q1 = (q & 1) != 0;
    t[0] = q1 ? s1 : v[0];
    t[1] = q1 ? v[1] : s0;
    t[2] = q1 ? s3 : v[2];
    t[3] = q1 ? v[3] : s2;
    float u0 = fdpp<0x4E>(t[0]), u1 = fdpp<0x4E>(t[1]),
          u2 = fdpp<0x4E>(t[2]), u3 = fdpp<0x4E>(t[3]);
    f32x4 r;
    bool q2 = (q & 2) != 0;
    r[0] = q2 ? u2 : t[0];
    r[1] = q2 ? u3 : t[1];
    r[2] = q2 ? t[2] : u0;
    r[3] = q2 ? t[3] : u1;
    return r;
}

// ---------------------------------------------------------------------------
// Kernel 0: fp32 -> bf16 convert pass
// ---------------------------------------------------------------------------
__global__ __launch_bounds__(256) void convert_kernel(
    const float* __restrict__ x, const float* __restrict__ Wq,
    const float* __restrict__ Wk, const float* __restrict__ Wv,
    const float* __restrict__ Wo, const float* __restrict__ Wlr,
    const float* __restrict__ Wbeta,
    u16* __restrict__ xb, u16* __restrict__ wb, u16* __restrict__ wob,
    u16* __restrict__ wlb)
{
    const int t0 = blockIdx.x * 256 + threadIdx.x;
    const int stride = gridDim.x * 256;
    auto cv = [&](const float* src, u16* dst, int n4) {
        for (int i = t0; i < n4; i += stride) {
            float4 v = ((const float4*)src)[i];
            uint2 p;
            p.x = pk2(v.x, v.y);
            p.y = pk2(v.z, v.w);
            ((uint2*)dst)[i] = p;
        }
    };
    cv(x, xb, 4194304);
    cv(Wq, wb, 262144);
    cv(Wk, wb + 1048576, 262144);
    cv(Wv, wb + 2097152, 262144);
    cv(Wo, wob, 262144);
    cv(Wlr, wlb, 8192);
    cv(Wbeta, wlb + 32768, 8192);
}

// ---------------------------------------------------------------------------
// Kernel A: q/k/v projections (swizzled LDS, R10-verified)
// ---------------------------------------------------------------------------
__global__ __launch_bounds__(256) void proj_qkv_kernel(
    const u16* __restrict__ xb, const u16* __restrict__ wb,
    u16* __restrict__ qb, u16* __restrict__ kb, u16* __restrict__ vb)
{
    __shared__ __align__(16) char As[128 * 128];
    __shared__ __align__(16) char Bs[128 * 128];
    const int bn = blockIdx.x;
    const int bm = blockIdx.y;
    const int wsel = bn >> 3;
    u16* __restrict__ dst = (wsel == 0) ? qb : ((wsel == 1) ? kb : vb);
    const int cb = (bn & 7) * 128;
    const int wrow = bn * 128;
    const int rb = bm * 128;
    const int tid = threadIdx.x;
    const int lane = tid & 63;
    const int wv = tid >> 6;
    const int wr = (wv >> 1) * 64, wc = (wv & 1) * 64;
    const int li = lane & 15, g = lane >> 4;
    const int lr8 = lane >> 3, lc8 = lane & 7;

    f32x4 acc[4][4];
#pragma unroll
    for (int i = 0; i < 4; ++i)
#pragma unroll
        for (int j = 0; j < 4; ++j) acc[i][j] = (f32x4)0.0f;

    for (int k0 = 0; k0 < 1024; k0 += 64) {
        __syncthreads();
#pragma unroll
        for (int ld = 0; ld < 4; ++ld) {
            int r0 = wv * 32 + ld * 8;
            int rowT = r0 + lr8;
            int csw = (lc8 * 8) ^ ((rowT & 7) << 3);
            gload_lds16(xb + (size_t)(rb + rowT) * 1024 + k0 + csw, As + r0 * 128);
            gload_lds16(wb + (size_t)(wrow + rowT) * 1024 + k0 + csw, Bs + r0 * 128);
        }
        __syncthreads();
#pragma unroll
        for (int ks = 0; ks < 2; ++ks) {
            bf16x8 af[4], bfr[4];
#pragma unroll
            for (int m = 0; m < 4; ++m)
                af[m] = *(const bf16x8*)(As + swz128(wr + m * 16 + li, ks * 64 + g * 16));
#pragma unroll
            for (int n = 0; n < 4; ++n)
                bfr[n] = *(const bf16x8*)(Bs + swz128(wc + n * 16 + li, ks * 64 + g * 16));
#pragma unroll
            for (int m = 0; m < 4; ++m)
#pragma unroll
                for (int n = 0; n < 4; ++n)
                    acc[m][n] = __builtin_amdgcn_mfma_f32_16x16x32_bf16(af[m], bfr[n], acc[m][n], 0, 0, 0);
        }
    }
    const bool do_silu = (wsel < 2);
#pragma unroll
    for (int m = 0; m < 4; ++m) {
        int t = rb + wr + m * 16 + g * 4;
#pragma unroll
        for (int r = 0; r < 4; ++r) {
#pragma unroll
            for (int n = 0; n < 4; ++n) {
                float v = acc[m][n][r];
                if (do_silu) v = v / (1.0f + __expf(-v));
                int col = cb + wc + n * 16 + li;
                dst[(size_t)(t + r) * 1024 + col] = f2bf(v);
            }
        }
    }
}

// ---------------------------------------------------------------------------
// Kernel B: lr/wd heads (swizzled R10)
// ---------------------------------------------------------------------------
__global__ __launch_bounds__(256) void lrwd_kernel(
    const u16* __restrict__ xb, const u16* __restrict__ wlb,
    float* __restrict__ lrc_all)
{
    __shared__ __align__(16) char As[128 * 128];
    __shared__ __align__(16) char Bs[64 * 128];
    __shared__ float red[128][65];
    const int bm = blockIdx.x;
    const int rb = bm * 128;
    const int tid = threadIdx.x;
    const int lane = tid & 63;
    const int wv = tid >> 6;
    const int li = lane & 15, g = lane >> 4;
    const int lr8 = lane >> 3, lc8 = lane & 7;

    f32x4 acc[2][4];
#pragma unroll
    for (int i = 0; i < 2; ++i)
#pragma unroll
        for (int j = 0; j < 4; ++j) acc[i][j] = (f32x4)0.0f;

    for (int k0 = 0; k0 < 1024; k0 += 64) {
        __syncthreads();
#pragma unroll
        for (int ld = 0; ld < 4; ++ld) {
            int r0 = wv * 32 + ld * 8;
            int rowT = r0 + lr8;
            int csw = (lc8 * 8) ^ ((rowT & 7) << 3);
            gload_lds16(xb + (size_t)(rb + rowT) * 1024 + k0 + csw, As + r0 * 128);
        }
#pragma unroll
        for (int ld = 0; ld < 2; ++ld) {
            int r0 = wv * 16 + ld * 8;
            int rowT = r0 + lr8;
            int csw = (lc8 * 8) ^ ((rowT & 7) << 3);
            gload_lds16(wlb + (size_t)rowT * 1024 + k0 + csw, Bs + r0 * 128);
        }
        __syncthreads();
#pragma unroll
        for (int ks = 0; ks < 2; ++ks) {
            bf16x8 af[2], bfr[4];
#pragma unroll
            for (int m = 0; m < 2; ++m)
                af[m] = *(const bf16x8*)(As + swz128(wv * 32 + m * 16 + li, ks * 64 + g * 16));
#pragma unroll
            for (int n = 0; n < 4; ++n)
                bfr[n] = *(const bf16x8*)(Bs + swz128(n * 16 + li, ks * 64 + g * 16));
#pragma unroll
            for (int m = 0; m < 2; ++m)
#pragma unroll
                for (int n = 0; n < 4; ++n)
                    acc[m][n] = __builtin_amdgcn_mfma_f32_16x16x32_bf16(af[m], bfr[n], acc[m][n], 0, 0, 0);
        }
    }
#pragma unroll
    for (int m = 0; m < 2; ++m) {
#pragma unroll
        for (int n = 0; n < 4; ++n) {
            int col = n * 16 + li;
            float scale = (col < 32) ? 1e-3f : 0.9f;
#pragma unroll
            for (int r = 0; r < 4; ++r) {
                int t = wv * 32 + m * 16 + g * 4 + r;
                float s = acc[m][n][r];
                red[t][col] = scale / (1.0f + __expf(-s));
            }
        }
    }
    __syncthreads();
    if (tid < 128) {
        int chunk = tid >> 6, col = tid & 63;
        float s = 0.f;
#pragma unroll
        for (int i = 0; i < 64; ++i) s += red[chunk * 64 + i][col];
        int b = bm >> 5;
        int cidx = (bm & 31) * 2 + chunk;
        lrc_all[((size_t)(b * 64 + cidx)) * 64 + col] = s * (1.0f / 64.0f);
    }
}

// ---------------------------------------------------------------------------
// Kernel C: chunk scan — R11 structure + spin-overlap: chunk-stable operands
// (SWoT for M3, KcT for M6) preloaded BEFORE the spins; A's commit moved
// before its spin; softmax 1/s via v_rcp_f32.
// ---------------------------------------------------------------------------
__global__ __launch_bounds__(512) void scan_kernel(
    const u16* __restrict__ qb, const u16* __restrict__ kb, const u16* __restrict__ vb,
    const float* __restrict__ lrc_all, const float* __restrict__ Wi0,
    const float* __restrict__ Wo0, u16* __restrict__ ob)
{
    const int bh = blockIdx.x;
    const int b = bh >> 4, h = bh & 15;
    const int tid = threadIdx.x;
    const int lane = tid & 63;
    const int w8 = tid >> 6;            // 0..7
    const bool isA = (w8 < 4);
    const int wq = w8;
    const int wk = w8 - 4;
    const int li = lane & 15, g = lane >> 4;
    const int q4 = li & 3, b4 = li & 12;

    __shared__ __align__(16) char SQ2[2][8192];
    __shared__ __align__(16) char Kc2[2][8192];
    __shared__ __align__(16) char Vc2[2][8192];
    __shared__ __align__(16) char KcT2[2][8192];
    __shared__ __align__(16) char VcT2[2][8192];
    __shared__ __align__(16) char SWoT2[2][8192];
    __shared__ __align__(16) char SWiN[8192];
    __shared__ __align__(16) char SWoN[8192];
    __shared__ __align__(16) char SPQ[8192];
    __shared__ __align__(16) char SPTN[8192];
    __shared__ __align__(16) char SGZN[8192];
    __shared__ float spart[256];
    __shared__ float lrc[256];
    __shared__ u32 cntA, cntB;

    if (tid == 0) { cntA = 0u; cntB = 0u; }

    f32x4 WiR[4], WoR[4];
    if (!isA) {
#pragma unroll
        for (int tn = 0; tn < 4; ++tn) {
            int d = tn * 16 + li;
#pragma unroll
            for (int r = 0; r < 4; ++r) {
                int D = wk * 16 + g * 4 + r;
                WiR[tn][r] = Wi0[((size_t)D * 16 + h) * 64 + d];
                WoR[tn][r] = Wo0[((size_t)D * 16 + h) * 64 + d];
            }
            *(uint2*)(SWoT2[0] + swz128(d, wk * 32 + g * 8)) =
                make_uint2(pk2(WoR[tn][0], WoR[tn][1]), pk2(WoR[tn][2], WoR[tn][3]));
            f32x4 ti = trans4(WiR[tn], q4);
            *(uint2*)(SWiN + swz128(wk * 16 + g * 4 + q4, tn * 32 + b4 * 2)) =
                make_uint2(pk2(ti[0], ti[1]), pk2(ti[2], ti[3]));
            f32x4 to = trans4(WoR[tn], q4);
            *(uint2*)(SWoN + swz128(wk * 16 + g * 4 + q4, tn * 32 + b4 * 2)) =
                make_uint2(pk2(to[0], to[1]), pk2(to[2], to[3]));
        }
    }
    if (tid < 256) {
        int cc = tid >> 2, j = tid & 3;
        lrc[cc * 4 + j] = lrc_all[((size_t)(b * 64 + cc)) * 64 + j * 16 + h];
    }

    const int nb4 = ((tid & 255) >> 4) * 4;
    const int db4 = (tid & 15) * 4;
    uint4 pq_[2];
    uint2 pk_[4], pv_[4];
    auto prefetch = [&](int c) {
        const size_t base = ((size_t)(b * 4096 + c * 64)) * 1024 + h * 64;
#pragma unroll
        for (int p = 0; p < 2; ++p) {
            int id = p * 256 + (tid & 255);
            int n = id >> 3;
            int d0 = (id & 7) * 8;
            pq_[p] = *(const uint4*)(qb + base + (size_t)n * 1024 + d0);
        }
#pragma unroll
        for (int j = 0; j < 4; ++j) {
            pk_[j] = *(const uint2*)(kb + base + (size_t)(nb4 + j) * 1024 + db4);
            pv_[j] = *(const uint2*)(vb + base + (size_t)(nb4 + j) * 1024 + db4);
        }
    };
    auto commit = [&](int buf) {
#pragma unroll
        for (int p = 0; p < 2; ++p) {
            int id = p * 256 + (tid & 255);
            int n = id >> 3;
            int d0 = (id & 7) * 8;
            *(uint4*)(SQ2[buf] + swz128(n, d0 * 2)) = pq_[p];
        }
#pragma unroll
        for (int j = 0; j < 4; ++j) {
            *(uint2*)(Kc2[buf] + swz128(nb4 + j, db4 * 2)) = pk_[j];
            *(uint2*)(Vc2[buf] + swz128(nb4 + j, db4 * 2)) = pv_[j];
        }
#pragma unroll
        for (int i = 0; i < 4; ++i) {
            u32 k0 = (((i & 2) ? pk_[0].y : pk_[0].x) >> ((i & 1) * 16)) & 0xffffu;
            u32 k1 = (((i & 2) ? pk_[1].y : pk_[1].x) >> ((i & 1) * 16)) & 0xffffu;
            u32 k2 = (((i & 2) ? pk_[2].y : pk_[2].x) >> ((i & 1) * 16)) & 0xffffu;
            u32 k3 = (((i & 2) ? pk_[3].y : pk_[3].x) >> ((i & 1) * 16)) & 0xffffu;
            *(uint2*)(KcT2[buf] + swz128(db4 + i, nb4 * 2)) =
                make_uint2(k0 | (k1 << 16), k2 | (k3 << 16));
            u32 v0 = (((i & 2) ? pv_[0].y : pv_[0].x) >> ((i & 1) * 16)) & 0xffffu;
            u32 v1 = (((i & 2) ? pv_[1].y : pv_[1].x) >> ((i & 1) * 16)) & 0xffffu;
            u32 v2 = (((i & 2) ? pv_[2].y : pv_[2].x) >> ((i & 1) * 16)) & 0xffffu;
            u32 v3 = (((i & 2) ? pv_[3].y : pv_[3].x) >> ((i & 1) * 16)) & 0xffffu;
            *(uint2*)(VcT2[buf] + swz128(db4 + i, nb4 * 2)) =
                make_uint2(v0 | (v1 << 16), v2 | (v3 << 16));
        }
    };

    if (isA) { prefetch(0); commit(0); }
    __syncthreads();

    for (int c = 0; c < 64; ++c) {
        const int cur = c & 1, nxt = cur ^ 1;
        f32x4 pk[4], aT[4], go[4];

        if (isA) {
            // ======== A pre-spin: M1 + softmax + SPQ + commit + SWoT preload ========
            if (c + 1 < 64) prefetch(c + 1);
            bf16x8 wiA0 = *(const bf16x8*)(SWiN + swz128(wq * 16 + li, g * 16));
            bf16x8 wiA1 = *(const bf16x8*)(SWiN + swz128(wq * 16 + li, 64 + g * 16));
            f32x4 sq[4];
            __builtin_amdgcn_s_setprio(1);
#pragma unroll
            for (int tn = 0; tn < 4; ++tn) {
                bf16x8 b0 = *(const bf16x8*)(SQ2[cur] + swz128(tn * 16 + li, g * 16));
                bf16x8 b1 = *(const bf16x8*)(SQ2[cur] + swz128(tn * 16 + li, 64 + g * 16));
                f32x4 z = (f32x4)0.0f;
                z = __builtin_amdgcn_mfma_f32_16x16x32_bf16(wiA0, b0, z, 0, 0, 0);
                z = __builtin_amdgcn_mfma_f32_16x16x32_bf16(wiA1, b1, z, 0, 0, 0);
                sq[tn] = z;
            }
            __builtin_amdgcn_s_setprio(0);
#pragma unroll
            for (int r = 0; r < 4; ++r) {
                float m = fmaxf(fmaxf(sq[0][r], sq[1][r]), fmaxf(sq[2][r], sq[3][r]));
                m = rmax16(m);
                float e0 = __expf(sq[0][r] - m), e1 = __expf(sq[1][r] - m);
                float e2 = __expf(sq[2][r] - m), e3 = __expf(sq[3][r] - m);
                float inv = frcp(rsum16(e0 + e1 + e2 + e3));
                sq[0][r] = e0 * inv; sq[1][r] = e1 * inv; sq[2][r] = e2 * inv; sq[3][r] = e3 * inv;
            }
#pragma unroll
            for (int tn = 0; tn < 4; ++tn) {
                int n = tn * 16 + li;
                *(uint2*)(SPQ + swz128(n, (wq * 16 + g * 4) * 2)) =
                    make_uint2(pk2(sq[tn][0], sq[tn][1]), pk2(sq[tn][2], sq[tn][3]));
            }
            // commit next chunk's tiles now (writes [nxt]; read after chunk barrier)
            if (c + 1 < 64) commit(nxt);
            // preload M3 B-frags (SWoT2[cur] stable all chunk)
            bf16x8 wob0[4], wob1[4];
#pragma unroll
            for (int tn = 0; tn < 4; ++tn) {
                wob0[tn] = *(const bf16x8*)(SWoT2[cur] + swz128(tn * 16 + li, g * 16));
                wob1[tn] = *(const bf16x8*)(SWoT2[cur] + swz128(tn * 16 + li, 64 + g * 16));
            }
            // ---- A-group spin (SPQ complete among waves 0-3) ----
            __threadfence_block();
            if (lane == 0) atomicAdd(&cntA, 1u);
            {
                volatile u32* vc = &cntA;
                u32 tgt = 4u * (u32)(c + 1);
                while (*vc < tgt) { __builtin_amdgcn_s_sleep(1); }
            }
            __threadfence_block();
            // ======== A post-spin: M3 + packed o store ========
            bf16x8 a0 = *(const bf16x8*)(SPQ + swz128(wq * 16 + li, g * 16));
            bf16x8 a1 = *(const bf16x8*)(SPQ + swz128(wq * 16 + li, 64 + g * 16));
            f32x4 o4[4];
            __builtin_amdgcn_s_setprio(1);
#pragma unroll
            for (int tn = 0; tn < 4; ++tn) {
                f32x4 z = (f32x4)0.0f;
                z = __builtin_amdgcn_mfma_f32_16x16x32_bf16(a0, wob0[tn], z, 0, 0, 0);
                z = __builtin_amdgcn_mfma_f32_16x16x32_bf16(a1, wob1[tn], z, 0, 0, 0);
                o4[tn] = z;
            }
            __builtin_amdgcn_s_setprio(0);
            const size_t obase = ((size_t)(b * 4096 + c * 64)) * 1024 + h * 64;
            const int n_ = wq * 16 + g * 4 + q4;
#pragma unroll
            for (int tn = 0; tn < 4; ++tn) {
                f32x4 to = trans4(o4[tn], q4);
                *(uint2*)(ob + obase + (size_t)n_ * 1024 + tn * 16 + b4) =
                    make_uint2(pk2(to[0], to[1]), pk2(to[2], to[3]));
            }
        } else {
            // ======== B pre-spin: M2 + softmax + M4' + spart + SPTN + M5 + KcT preload ========
            bf16x8 wiA0 = *(const bf16x8*)(SWiN + swz128(wk * 16 + li, g * 16));
            bf16x8 wiA1 = *(const bf16x8*)(SWiN + swz128(wk * 16 + li, 64 + g * 16));
            __builtin_amdgcn_s_setprio(1);
#pragma unroll
            for (int tn = 0; tn < 4; ++tn) {
                bf16x8 b0 = *(const bf16x8*)(Kc2[cur] + swz128(tn * 16 + li, g * 16));
                bf16x8 b1 = *(const bf16x8*)(Kc2[cur] + swz128(tn * 16 + li, 64 + g * 16));
                f32x4 z = (f32x4)0.0f;
                z = __builtin_amdgcn_mfma_f32_16x16x32_bf16(wiA0, b0, z, 0, 0, 0);
                z = __builtin_amdgcn_mfma_f32_16x16x32_bf16(wiA1, b1, z, 0, 0, 0);
                pk[tn] = z;
            }
            __builtin_amdgcn_s_setprio(0);
#pragma unroll
            for (int r = 0; r < 4; ++r) {
                float m = fmaxf(fmaxf(pk[0][r], pk[1][r]), fmaxf(pk[2][r], pk[3][r]));
                m = rmax16(m);
                float e0 = __expf(pk[0][r] - m), e1 = __expf(pk[1][r] - m);
                float e2 = __expf(pk[2][r] - m), e3 = __expf(pk[3][r] - m);
                float inv = frcp(rsum16(e0 + e1 + e2 + e3));
                pk[0][r] = e0 * inv; pk[1][r] = e1 * inv; pk[2][r] = e2 * inv; pk[3][r] = e3 * inv;
            }
            bf16x8 woA0 = *(const bf16x8*)(SWoN + swz128(wk * 16 + li, g * 16));
            bf16x8 woA1 = *(const bf16x8*)(SWoN + swz128(wk * 16 + li, 64 + g * 16));
            __builtin_amdgcn_s_setprio(1);
#pragma unroll
            for (int tn = 0; tn < 4; ++tn) {
                bf16x8 b0 = *(const bf16x8*)(Vc2[cur] + swz128(tn * 16 + li, g * 16));
                bf16x8 b1 = *(const bf16x8*)(Vc2[cur] + swz128(tn * 16 + li, 64 + g * 16));
                f32x4 z = (f32x4)0.0f;
                z = __builtin_amdgcn_mfma_f32_16x16x32_bf16(woA0, b0, z, 0, 0, 0);
                z = __builtin_amdgcn_mfma_f32_16x16x32_bf16(woA1, b1, z, 0, 0, 0);
                aT[tn] = z;
            }
            __builtin_amdgcn_s_setprio(0);
#pragma unroll
            for (int tn = 0; tn < 4; ++tn) {
                f32x4 t4 = pk[tn] * aT[tn];
                float s_ = t4[0] + t4[1] + t4[2] + t4[3];
                s_ += __shfl_xor(s_, 16);
                s_ += __shfl_xor(s_, 32);
                if (g == 0) spart[wk * 64 + tn * 16 + li] = s_;
            }
#pragma unroll
            for (int tn = 0; tn < 4; ++tn) {
                f32x4 tp = trans4(pk[tn], q4);
                *(uint2*)(SPTN + swz128(wk * 16 + g * 4 + q4, tn * 32 + b4 * 2)) =
                    make_uint2(pk2(tp[0], tp[1]), pk2(tp[2], tp[3]));
            }
            {
                bf16x8 a0 = *(const bf16x8*)(SPTN + swz128(wk * 16 + li, g * 16));
                bf16x8 a1 = *(const bf16x8*)(SPTN + swz128(wk * 16 + li, 64 + g * 16));
                __builtin_amdgcn_s_setprio(1);
#pragma unroll
                for (int tn = 0; tn < 4; ++tn) {
                    bf16x8 b0 = *(const bf16x8*)(VcT2[cur] + swz128(tn * 16 + li, g * 16));
                    bf16x8 b1 = *(const bf16x8*)(VcT2[cur] + swz128(tn * 16 + li, 64 + g * 16));
                    f32x4 z = (f32x4)0.0f;
                    z = __builtin_amdgcn_mfma_f32_16x16x32_bf16(a0, b0, z, 0, 0, 0);
                    z = __builtin_amdgcn_mfma_f32_16x16x32_bf16(a1, b1, z, 0, 0, 0);
                    go[tn] = z;
                }
                __builtin_amdgcn_s_setprio(0);
            }
            // preload M6 B-frags (KcT2[cur] stable all chunk)
            bf16x8 kb0[4], kb1[4];
#pragma unroll
            for (int tn = 0; tn < 4; ++tn) {
                kb0[tn] = *(const bf16x8*)(KcT2[cur] + swz128(tn * 16 + li, g * 16));
                kb1[tn] = *(const bf16x8*)(KcT2[cur] + swz128(tn * 16 + li, 64 + g * 16));
            }
            // ---- B-group spin (spart complete among waves 4-7) ----
            __threadfence_block();
            if (lane == 0) atomicAdd(&cntB, 1u);
            {
                volatile u32* vc = &cntB;
                u32 tgt = 4u * (u32)(c + 1);
                while (*vc < tgt) { __builtin_amdgcn_s_sleep(1); }
            }
            __threadfence_block();
            // ======== B post-spin: gz + SGZN + M6 + state update ========
            f32x4 gz[4];
#pragma unroll
            for (int tn = 0; tn < 4; ++tn) {
                int n = tn * 16 + li;
                float sn = spart[n] + spart[64 + n] + spart[128 + n] + spart[192 + n];
#pragma unroll
                for (int r = 0; r < 4; ++r) gz[tn][r] = pk[tn][r] * (sn - aT[tn][r]);
                f32x4 tg = trans4(gz[tn], q4);
                *(uint2*)(SGZN + swz128(wk * 16 + g * 4 + q4, tn * 32 + b4 * 2)) =
                    make_uint2(pk2(tg[0], tg[1]), pk2(tg[2], tg[3]));
            }
            f32x4 gi[4];
            {
                bf16x8 a0 = *(const bf16x8*)(SGZN + swz128(wk * 16 + li, g * 16));
                bf16x8 a1 = *(const bf16x8*)(SGZN + swz128(wk * 16 + li, 64 + g * 16));
                __builtin_amdgcn_s_setprio(1);
#pragma unroll
                for (int tn = 0; tn < 4; ++tn) {
                    f32x4 z = (f32x4)0.0f;
                    z = __builtin_amdgcn_mfma_f32_16x16x32_bf16(a0, kb0[tn], z, 0, 0, 0);
                    z = __builtin_amdgcn_mfma_f32_16x16x32_bf16(a1, kb1[tn], z, 0, 0, 0);
                    gi[tn] = z;
                }
                __builtin_amdgcn_s_setprio(0);
            }
            if (c + 1 < 64) {
                float lin = lrc[c * 4 + 0], lout = lrc[c * 4 + 1];
                float win = lrc[c * 4 + 2], wout = lrc[c * 4 + 3];
#pragma unroll
                for (int tn = 0; tn < 4; ++tn) {
                    WiR[tn] = win * WiR[tn] - lin * gi[tn];
                    WoR[tn] = wout * WoR[tn] + lout * go[tn];   // grad_out = -go
                    int d = tn * 16 + li;
                    *(uint2*)(SWoT2[nxt] + swz128(d, wk * 32 + g * 8)) =
                        make_uint2(pk2(WoR[tn][0], WoR[tn][1]), pk2(WoR[tn][2], WoR[tn][3]));
                    f32x4 ti = trans4(WiR[tn], q4);
                    *(uint2*)(SWiN + swz128(wk * 16 + g * 4 + q4, tn * 32 + b4 * 2)) =
                        make_uint2(pk2(ti[0], ti[1]), pk2(ti[2], ti[3]));
                    f32x4 to = trans4(WoR[tn], q4);
                    *(uint2*)(SWoN + swz128(wk * 16 + g * 4 + q4, tn * 32 + b4 * 2)) =
                        make_uint2(pk2(to[0], to[1]), pk2(to[2], to[3]));
                }
            }
        }
        __syncthreads();   // chunk end: tiles(c+1) + state(c+1) visible to all
    }
}

// ---------------------------------------------------------------------------
// Kernel D: out_proj (swizzled R10)
// ---------------------------------------------------------------------------
__global__ __launch_bounds__(256) void out_proj_kernel(
    const u16* __restrict__ ob, const u16* __restrict__ wob, float* __restrict__ out)
{
    __shared__ __align__(16) char As[128 * 128];
    __shared__ __align__(16) char Bs[128 * 128];
    const int bn = blockIdx.x;
    const int bm = blockIdx.y;
    const int cb = bn * 128;
    const int rb = bm * 128;
    const int tid = threadIdx.x;
    const int lane = tid & 63;
    const int wv = tid >> 6;
    const int wr = (wv >> 1) * 64, wc = (wv & 1) * 64;
    const int li = lane & 15, g = lane >> 4;
    const int lr8 = lane >> 3, lc8 = lane & 7;

    f32x4 acc[4][4];
#pragma unroll
    for (int i = 0; i < 4; ++i)
#pragma unroll
        for (int j = 0; j < 4; ++j) acc[i][j] = (f32x4)0.0f;

    for (int k0 = 0; k0 < 1024; k0 += 64) {
        __syncthreads();
#pragma unroll
        for (int ld = 0; ld < 4; ++ld) {
            int r0 = wv * 32 + ld * 8;
            int rowT = r0 + lr8;
            int csw = (lc8 * 8) ^ ((rowT & 7) << 3);
            gload_lds16(ob + (size_t)(rb + rowT) * 1024 + k0 + csw, As + r0 * 128);
            gload_lds16(wob + (size_t)(cb + rowT) * 1024 + k0 + csw, Bs + r0 * 128);
        }
        __syncthreads();
#pragma unroll
        for (int ks = 0; ks < 2; ++ks) {
            bf16x8 af[4], bfr[4];
#pragma unroll
            for (int m = 0; m < 4; ++m)
                af[m] = *(const bf16x8*)(As + swz128(wr + m * 16 + li, ks * 64 + g * 16));
#pragma unroll
            for (int n = 0; n < 4; ++n)
                bfr[n] = *(const bf16x8*)(Bs + swz128(wc + n * 16 + li, ks * 64 + g * 16));
#pragma unroll
            for (int m = 0; m < 4; ++m)
#pragma unroll
                for (int n = 0; n < 4; ++n)
                    acc[m][n] = __builtin_amdgcn_mfma_f32_16x16x32_bf16(af[m], bfr[n], acc[m][n], 0, 0, 0);
        }
    }
#pragma unroll
    for (int m = 0; m < 4; ++m) {
        int t = rb + wr + m * 16 + g * 4;
#pragma unroll
        for (int r = 0; r < 4; ++r) {
#pragma unroll
            for (int n = 0; n < 4; ++n) {
                int col = cb + wc + n * 16 + li;
                out[(size_t)(t + r) * 1024 + col] = acc[m][n][r];
            }
        }
    }
}

// ---------------------------------------------------------------------------
extern "C" void kernel_launch(void* const* d_in, const int* in_sizes, int n_in,
                              void* d_out, int out_size, void* d_ws, size_t ws_size,
                              hipStream_t stream)
{
    const float* x     = (const float*)d_in[0];
    const float* Wq    = (const float*)d_in[1];
    const float* Wk    = (const float*)d_in[2];
    const float* Wv    = (const float*)d_in[3];
    const float* Wlr   = (const float*)d_in[4];
    const float* Wbeta = (const float*)d_in[5];
    const float* Wo    = (const float*)d_in[6];
    const float* Wi0   = (const float*)d_in[7];
    const float* Wo0   = (const float*)d_in[8];
    float* out = (float*)d_out;

    char* od = (char*)d_out;
    u16* xb  = (u16*)(od);                 // dead before out_proj overwrites
    u16* wb  = (u16*)(od + 33554432u);
    u16* wlb = (u16*)(od + 39845888u);

    char* ws = (char*)d_ws;
    u16* qb        = (u16*)(ws);
    u16* kb        = (u16*)(ws + 33554432u);
    u16* vb        = (u16*)(ws + 67108864u);
    u16* obuf      = (u16*)(ws + 100663296u);
    float* lrc_all = (float*)(ws + 134217728u);
    u16* wob       = (u16*)(ws + 134283264u);
    if (ws_size < 136380416u) return;

    convert_kernel<<<2048, 256, 0, stream>>>(x, Wq, Wk, Wv, Wo, Wlr, Wbeta,
                                             xb, wb, wob, wlb);
    proj_qkv_kernel<<<dim3(24, 128), 256, 0, stream>>>(xb, wb, qb, kb, vb);
    lrwd_kernel<<<128, 256, 0, stream>>>(xb, wlb, lrc_all);
    scan_kernel<<<64, 512, 0, stream>>>(qb, kb, vb, lrc_all, Wi0, Wo0, obuf);
    out_proj_kernel<<<dim3(8, 128), 256, 0, stream>>>(obuf, wob, out);
}

// Round 13
// 488.461 us; speedup vs baseline: 1.6457x; 1.0318x over previous
//
#include <hip/hip_runtime.h>
#include <stdint.h>

typedef unsigned short u16;
typedef uint32_t u32;
typedef __attribute__((ext_vector_type(4))) float f32x4;
typedef __attribute__((ext_vector_type(8))) short bf16x8;

#define DEVINL __device__ __forceinline__

DEVINL u16 f2bf(float f) {
    union { float f; u32 u; } a; a.f = f;
    u32 u = a.u;
    return (u16)((u + 0x7fffu + ((u >> 16) & 1u)) >> 16);   // RNE
}
DEVINL u32 pk2(float a, float b) { return (u32)f2bf(a) | ((u32)f2bf(b) << 16); }

// 128B-row swizzled tile (conflict-free vector row reads) — verified R2..R12
DEVINL u32 swz128(u32 row, u32 colb) { return row * 128u + (colb ^ ((row & 7u) << 4)); }

// async global->LDS, 16B per lane
DEVINL void gload_lds16(const u16* g, char* l) {
    __builtin_amdgcn_global_load_lds(
        (const __attribute__((address_space(1))) void*)g,
        (__attribute__((address_space(3))) void*)l, 16, 0, 0);
}

// fast reciprocal (v_rcp_f32) — softmax denominators in [1,64]
DEVINL float frcp(float x) { float r; asm("v_rcp_f32 %0, %1" : "=v"(r) : "v"(x)); return r; }

// ---- DPP cross-lane (VALU pipe) — verified R11 ----
template<int C> DEVINL float fdpp(float x) {
    union { float f; int i; } a, b; a.f = x;
    b.i = __builtin_amdgcn_update_dpp(0, a.i, C, 0xf, 0xf, false);
    return b.f;
}
DEVINL float rmax16(float v) {
    v = fmaxf(v, fdpp<0x128>(v)); v = fmaxf(v, fdpp<0x124>(v));
    v = fmaxf(v, fdpp<0x122>(v)); v = fmaxf(v, fdpp<0x121>(v)); return v;
}
DEVINL float rsum16(float v) {
    v += fdpp<0x128>(v); v += fdpp<0x124>(v);
    v += fdpp<0x122>(v); v += fdpp<0x121>(v); return v;
}

// 4x4 transpose among 4 lanes via DPP quad_perm — verified R11
DEVINL f32x4 trans4(f32x4 v, int q) {
    float s0 = fdpp<0xB1>(v[0]), s1 = fdpp<0xB1>(v[1]),
          s2 = fdpp<0xB1>(v[2]), s3 = fdpp<0xB1>(v[3]);
    f32x4 t;
    bool q1 = (q & 1) != 0;
    t[0] = q1 ? s1 : v[0];
    t[1] = q1 ? v[1] : s0;
    t[2] = q1 ? s3 : v[2];
    t[3] = q1 ? v[3] : s2;
    float u0 = fdpp<0x4E>(t[0]), u1 = fdpp<0x4E>(t[1]),
          u2 = fdpp<0x4E>(t[2]), u3 = fdpp<0x4E>(t[3]);
    f32x4 r;
    bool q2 = (q & 2) != 0;
    r[0] = q2 ? u2 : t[0];
    r[1] = q2 ? u3 : t[1];
    r[2] = q2 ? t[2] : u0;
    r[3] = q2 ? t[3] : u1;
    return r;
}

// ---- raw-barrier pipeline primitives (T3/T4) ----
#define LGW()  do { asm volatile("s_waitcnt lgkmcnt(0)" ::: "memory"); \
                    __builtin_amdgcn_sched_barrier(0); } while (0)
#define VMW(N) do { asm volatile("s_waitcnt vmcnt(" #N ")" ::: "memory"); \
                    __builtin_amdgcn_sched_barrier(0); } while (0)
#define BARRAW() do { __builtin_amdgcn_sched_barrier(0); \
                      __builtin_amdgcn_s_barrier(); \
                      __builtin_amdgcn_sched_barrier(0); } while (0)

// ---------------------------------------------------------------------------
// Kernel 0: fp32 -> bf16 convert pass
// ---------------------------------------------------------------------------
__global__ __launch_bounds__(256) void convert_kernel(
    const float* __restrict__ x, const float* __restrict__ Wq,
    const float* __restrict__ Wk, const float* __restrict__ Wv,
    const float* __restrict__ Wo, const float* __restrict__ Wlr,
    const float* __restrict__ Wbeta,
    u16* __restrict__ xb, u16* __restrict__ wb, u16* __restrict__ wob,
    u16* __restrict__ wlb)
{
    const int t0 = blockIdx.x * 256 + threadIdx.x;
    const int stride = gridDim.x * 256;
    auto cv = [&](const float* src, u16* dst, int n4) {
        for (int i = t0; i < n4; i += stride) {
            float4 v = ((const float4*)src)[i];
            uint2 p;
            p.x = pk2(v.x, v.y);
            p.y = pk2(v.z, v.w);
            ((uint2*)dst)[i] = p;
        }
    };
    cv(x, xb, 4194304);
    cv(Wq, wb, 262144);
    cv(Wk, wb + 1048576, 262144);
    cv(Wv, wb + 2097152, 262144);
    cv(Wo, wob, 262144);
    cv(Wlr, wlb, 8192);
    cv(Wbeta, wlb + 32768, 8192);
}

// ---------------------------------------------------------------------------
// Kernel A (R13): q/k/v projections — 256x256 tile, 8 waves, BK=64,
// ring-2 LDS with counted vmcnt(8) and raw barriers (T3+T4).
//   per iteration kt (16 total):
//     pre : read 8 B-frags + A-q0; lgkm; BAR1 (B-buf free)
//     ph0 : read A-q1; stage B#0(kt+2); MFMA q0; lgkm
//     ph1 : read A-q2; stage B#1;       MFMA q1; lgkm
//     ph2 : read A-q3; stage B#2,#3;    MFMA q2; lgkm; BAR2 (A-buf free)
//     ph3 : stage A#0..3(kt+2);         MFMA q3
//     end : vmcnt(8) [14: 0] ; BAR3
// ---------------------------------------------------------------------------
#define RDA(BUF, Q, AF)                                                       \
    _Pragma("unroll")                                                         \
    for (int i_ = 0; i_ < 2; ++i_)                                            \
        _Pragma("unroll")                                                     \
        for (int kk_ = 0; kk_ < 2; ++kk_)                                     \
            AF[i_ * 2 + kk_] = *(const bf16x8*)(&A2[BUF][swz128(              \
                wm * 128 + (2 * (Q) + i_) * 16 + li, kk_ * 64 + g * 16)]);

#define PROJ_MFMA(Q, AF)                                                      \
    __builtin_amdgcn_s_setprio(1);                                            \
    _Pragma("unroll")                                                         \
    for (int i_ = 0; i_ < 2; ++i_)                                            \
        _Pragma("unroll")                                                     \
        for (int nf_ = 0; nf_ < 4; ++nf_) {                                   \
            acc[2 * (Q) + i_][nf_] = __builtin_amdgcn_mfma_f32_16x16x32_bf16( \
                AF[i_ * 2 + 0], Bfr[nf_ * 2 + 0], acc[2 * (Q) + i_][nf_], 0, 0, 0); \
            acc[2 * (Q) + i_][nf_] = __builtin_amdgcn_mfma_f32_16x16x32_bf16( \
                AF[i_ * 2 + 1], Bfr[nf_ * 2 + 1], acc[2 * (Q) + i_][nf_], 0, 0, 0); \
        }                                                                     \
    __builtin_amdgcn_s_setprio(0);

__global__ __launch_bounds__(512) void proj_qkv_kernel(
    const u16* __restrict__ xb, const u16* __restrict__ wb,
    u16* __restrict__ qb, u16* __restrict__ kb, u16* __restrict__ vb)
{
    __shared__ __align__(16) char A2[2][32768];   // [256 rows][64 bf16] swz128
    __shared__ __align__(16) char B2[2][32768];
    const int bn = blockIdx.x;            // 0..11
    const int bm = blockIdx.y;            // 0..63
    const int wsel = bn >> 2;
    u16* __restrict__ dst = (wsel == 0) ? qb : ((wsel == 1) ? kb : vb);
    const int cb = (bn & 3) * 256;        // out col base within 1024
    const int wrow = bn * 256;            // row base within 3072 concat
    const int rb = bm * 256;
    const int tid = threadIdx.x;
    const int lane = tid & 63;
    const int w8 = tid >> 6;              // 0..7
    const int wm = w8 >> 2;               // 0..1  (row half)
    const int wn = w8 & 3;                // 0..3  (col quarter)
    const int li = lane & 15, g = lane >> 4;
    const int q4 = li & 3, b4 = li & 12;

    // staging: pass p covers rows p*64 + (tid>>3), 16B per lane, swz source
    const int srow = tid >> 3;
    const int scol8 = (tid & 7) * 8;
    auto stA = [&](int kt2, int pass, int buf) {
        int rowT = pass * 64 + srow;
        int csw = scol8 ^ ((rowT & 7) << 3);
        gload_lds16(xb + (size_t)(rb + rowT) * 1024 + kt2 * 64 + csw,
                    &A2[buf][pass * 8192 + tid * 16]);
    };
    auto stB = [&](int kt2, int pass, int buf) {
        int rowT = pass * 64 + srow;
        int csw = scol8 ^ ((rowT & 7) << 3);
        gload_lds16(wb + (size_t)(wrow + rowT) * 1024 + kt2 * 64 + csw,
                    &B2[buf][pass * 8192 + tid * 16]);
    };

    f32x4 acc[8][4];
#pragma unroll
    for (int i = 0; i < 8; ++i)
#pragma unroll
        for (int j = 0; j < 4; ++j) acc[i][j] = (f32x4)0.0f;

    // prologue: stage tiles 0 (buf0) and 1 (buf1); wait tile0; barrier
#pragma unroll
    for (int p = 0; p < 4; ++p) { stA(0, p, 0); stB(0, p, 0); }
#pragma unroll
    for (int p = 0; p < 4; ++p) { stA(1, p, 1); stB(1, p, 1); }
    VMW(8);
    BARRAW();

    for (int kt = 0; kt < 16; ++kt) {
        const int buf = kt & 1;
        const bool st = (kt + 2 < 16);
        // ---- pre-phase: all B frags + A q0 ----
        bf16x8 Bfr[8];
#pragma unroll
        for (int nf = 0; nf < 4; ++nf)
#pragma unroll
            for (int kk = 0; kk < 2; ++kk)
                Bfr[nf * 2 + kk] = *(const bf16x8*)(&B2[buf][swz128(
                    wn * 64 + nf * 16 + li, kk * 64 + g * 16)]);
        bf16x8 Af0[4], Af1[4];
        RDA(buf, 0, Af0);
        LGW();
        BARRAW();                          // BAR1: B-buf free for stages
        // ---- phase 0 ----
        RDA(buf, 1, Af1);
        if (st) stB(kt + 2, 0, buf);
        PROJ_MFMA(0, Af0);
        LGW();
        // ---- phase 1 ----
        RDA(buf, 2, Af0);
        if (st) stB(kt + 2, 1, buf);
        PROJ_MFMA(1, Af1);
        LGW();
        // ---- phase 2 ----
        RDA(buf, 3, Af1);
        if (st) { stB(kt + 2, 2, buf); stB(kt + 2, 3, buf); }
        PROJ_MFMA(2, Af0);
        LGW();
        BARRAW();                          // BAR2: A-buf free for stages
        // ---- phase 3 ----
        if (st) { stA(kt + 2, 0, buf); stA(kt + 2, 1, buf);
                  stA(kt + 2, 2, buf); stA(kt + 2, 3, buf); }
        PROJ_MFMA(3, Af1);
        // ---- iteration end ----
        if (kt < 14) { VMW(8); } else if (kt == 14) { VMW(0); }
        BARRAW();                          // BAR3: tile kt+1 landed for all
    }

    // epilogue: silu (q,k) + packed b64 stores via trans4
    const bool do_silu = (wsel < 2);
#pragma unroll
    for (int mf = 0; mf < 8; ++mf) {
        const int n_ = rb + wm * 128 + mf * 16 + g * 4 + q4;
#pragma unroll
        for (int nf = 0; nf < 4; ++nf) {
            f32x4 o = acc[mf][nf];
            if (do_silu) {
#pragma unroll
                for (int r = 0; r < 4; ++r) o[r] = o[r] / (1.0f + __expf(-o[r]));
            }
            f32x4 to = trans4(o, q4);
            *(uint2*)(dst + (size_t)n_ * 1024 + cb + wn * 64 + nf * 16 + b4) =
                make_uint2(pk2(to[0], to[1]), pk2(to[2], to[3]));
        }
    }
}

// ---------------------------------------------------------------------------
// Kernel B: lr/wd heads (swizzled R10)
// ---------------------------------------------------------------------------
__global__ __launch_bounds__(256) void lrwd_kernel(
    const u16* __restrict__ xb, const u16* __restrict__ wlb,
    float* __restrict__ lrc_all)
{
    __shared__ __align__(16) char As[128 * 128];
    __shared__ __align__(16) char Bs[64 * 128];
    __shared__ float red[128][65];
    const int bm = blockIdx.x;
    const int rb = bm * 128;
    const int tid = threadIdx.x;
    const int lane = tid & 63;
    const int wv = tid >> 6;
    const int li = lane & 15, g = lane >> 4;
    const int lr8 = lane >> 3, lc8 = lane & 7;

    f32x4 acc[2][4];
#pragma unroll
    for (int i = 0; i < 2; ++i)
#pragma unroll
        for (int j = 0; j < 4; ++j) acc[i][j] = (f32x4)0.0f;

    for (int k0 = 0; k0 < 1024; k0 += 64) {
        __syncthreads();
#pragma unroll
        for (int ld = 0; ld < 4; ++ld) {
            int r0 = wv * 32 + ld * 8;
            int rowT = r0 + lr8;
            int csw = (lc8 * 8) ^ ((rowT & 7) << 3);
            gload_lds16(xb + (size_t)(rb + rowT) * 1024 + k0 + csw, As + r0 * 128);
        }
#pragma unroll
        for (int ld = 0; ld < 2; ++ld) {
            int r0 = wv * 16 + ld * 8;
            int rowT = r0 + lr8;
            int csw = (lc8 * 8) ^ ((rowT & 7) << 3);
            gload_lds16(wlb + (size_t)rowT * 1024 + k0 + csw, Bs + r0 * 128);
        }
        __syncthreads();
#pragma unroll
        for (int ks = 0; ks < 2; ++ks) {
            bf16x8 af[2], bfr[4];
#pragma unroll
            for (int m = 0; m < 2; ++m)
                af[m] = *(const bf16x8*)(As + swz128(wv * 32 + m * 16 + li, ks * 64 + g * 16));
#pragma unroll
            for (int n = 0; n < 4; ++n)
                bfr[n] = *(const bf16x8*)(Bs + swz128(n * 16 + li, ks * 64 + g * 16));
#pragma unroll
            for (int m = 0; m < 2; ++m)
#pragma unroll
                for (int n = 0; n < 4; ++n)
                    acc[m][n] = __builtin_amdgcn_mfma_f32_16x16x32_bf16(af[m], bfr[n], acc[m][n], 0, 0, 0);
        }
    }
#pragma unroll
    for (int m = 0; m < 2; ++m) {
#pragma unroll
        for (int n = 0; n < 4; ++n) {
            int col = n * 16 + li;
            float scale = (col < 32) ? 1e-3f : 0.9f;
#pragma unroll
            for (int r = 0; r < 4; ++r) {
                int t = wv * 32 + m * 16 + g * 4 + r;
                float s = acc[m][n][r];
                red[t][col] = scale / (1.0f + __expf(-s));
            }
        }
    }
    __syncthreads();
    if (tid < 128) {
        int chunk = tid >> 6, col = tid & 63;
        float s = 0.f;
#pragma unroll
        for (int i = 0; i < 64; ++i) s += red[chunk * 64 + i][col];
        int b = bm >> 5;
        int cidx = (bm & 31) * 2 + chunk;
        lrc_all[((size_t)(b * 64 + cidx)) * 64 + col] = s * (1.0f / 64.0f);
    }
}

// ---------------------------------------------------------------------------
// Kernel C: chunk scan — R12 verbatim (280 us verified best)
// ---------------------------------------------------------------------------
__global__ __launch_bounds__(512) void scan_kernel(
    const u16* __restrict__ qb, const u16* __restrict__ kb, const u16* __restrict__ vb,
    const float* __restrict__ lrc_all, const float* __restrict__ Wi0,
    const float* __restrict__ Wo0, u16* __restrict__ ob)
{
    const int bh = blockIdx.x;
    const int b = bh >> 4, h = bh & 15;
    const int tid = threadIdx.x;
    const int lane = tid & 63;
    const int w8 = tid >> 6;            // 0..7
    const bool isA = (w8 < 4);
    const int wq = w8;
    const int wk = w8 - 4;
    const int li = lane & 15, g = lane >> 4;
    const int q4 = li & 3, b4 = li & 12;

    __shared__ __align__(16) char SQ2[2][8192];
    __shared__ __align__(16) char Kc2[2][8192];
    __shared__ __align__(16) char Vc2[2][8192];
    __shared__ __align__(16) char KcT2[2][8192];
    __shared__ __align__(16) char VcT2[2][8192];
    __shared__ __align__(16) char SWoT2[2][8192];
    __shared__ __align__(16) char SWiN[8192];
    __shared__ __align__(16) char SWoN[8192];
    __shared__ __align__(16) char SPQ[8192];
    __shared__ __align__(16) char SPTN[8192];
    __shared__ __align__(16) char SGZN[8192];
    __shared__ float spart[256];
    __shared__ float lrc[256];
    __shared__ u32 cntA, cntB;

    if (tid == 0) { cntA = 0u; cntB = 0u; }

    f32x4 WiR[4], WoR[4];
    if (!isA) {
#pragma unroll
        for (int tn = 0; tn < 4; ++tn) {
            int d = tn * 16 + li;
#pragma unroll
            for (int r = 0; r < 4; ++r) {
                int D = wk * 16 + g * 4 + r;
                WiR[tn][r] = Wi0[((size_t)D * 16 + h) * 64 + d];
                WoR[tn][r] = Wo0[((size_t)D * 16 + h) * 64 + d];
            }
            *(uint2*)(SWoT2[0] + swz128(d, wk * 32 + g * 8)) =
                make_uint2(pk2(WoR[tn][0], WoR[tn][1]), pk2(WoR[tn][2], WoR[tn][3]));
            f32x4 ti = trans4(WiR[tn], q4);
            *(uint2*)(SWiN + swz128(wk * 16 + g * 4 + q4, tn * 32 + b4 * 2)) =
                make_uint2(pk2(ti[0], ti[1]), pk2(ti[2], ti[3]));
            f32x4 to = trans4(WoR[tn], q4);
            *(uint2*)(SWoN + swz128(wk * 16 + g * 4 + q4, tn * 32 + b4 * 2)) =
                make_uint2(pk2(to[0], to[1]), pk2(to[2], to[3]));
        }
    }
    if (tid < 256) {
        int cc = tid >> 2, j = tid & 3;
        lrc[cc * 4 + j] = lrc_all[((size_t)(b * 64 + cc)) * 64 + j * 16 + h];
    }

    const int nb4 = ((tid & 255) >> 4) * 4;
    const int db4 = (tid & 15) * 4;
    uint4 pq_[2];
    uint2 pk_[4], pv_[4];
    auto prefetch = [&](int c) {
        const size_t base = ((size_t)(b * 4096 + c * 64)) * 1024 + h * 64;
#pragma unroll
        for (int p = 0; p < 2; ++p) {
            int id = p * 256 + (tid & 255);
            int n = id >> 3;
            int d0 = (id & 7) * 8;
            pq_[p] = *(const uint4*)(qb + base + (size_t)n * 1024 + d0);
        }
#pragma unroll
        for (int j = 0; j < 4; ++j) {
            pk_[j] = *(const uint2*)(kb + base + (size_t)(nb4 + j) * 1024 + db4);
            pv_[j] = *(const uint2*)(vb + base + (size_t)(nb4 + j) * 1024 + db4);
        }
    };
    auto commit = [&](int buf) {
#pragma unroll
        for (int p = 0; p < 2; ++p) {
            int id = p * 256 + (tid & 255);
            int n = id >> 3;
            int d0 = (id & 7) * 8;
            *(uint4*)(SQ2[buf] + swz128(n, d0 * 2)) = pq_[p];
        }
#pragma unroll
        for (int j = 0; j < 4; ++j) {
            *(uint2*)(Kc2[buf] + swz128(nb4 + j, db4 * 2)) = pk_[j];
            *(uint2*)(Vc2[buf] + swz128(nb4 + j, db4 * 2)) = pv_[j];
        }
#pragma unroll
        for (int i = 0; i < 4; ++i) {
            u32 k0 = (((i & 2) ? pk_[0].y : pk_[0].x) >> ((i & 1) * 16)) & 0xffffu;
            u32 k1 = (((i & 2) ? pk_[1].y : pk_[1].x) >> ((i & 1) * 16)) & 0xffffu;
            u32 k2 = (((i & 2) ? pk_[2].y : pk_[2].x) >> ((i & 1) * 16)) & 0xffffu;
            u32 k3 = (((i & 2) ? pk_[3].y : pk_[3].x) >> ((i & 1) * 16)) & 0xffffu;
            *(uint2*)(KcT2[buf] + swz128(db4 + i, nb4 * 2)) =
                make_uint2(k0 | (k1 << 16), k2 | (k3 << 16));
            u32 v0 = (((i & 2) ? pv_[0].y : pv_[0].x) >> ((i & 1) * 16)) & 0xffffu;
            u32 v1 = (((i & 2) ? pv_[1].y : pv_[1].x) >> ((i & 1) * 16)) & 0xffffu;
            u32 v2 = (((i & 2) ? pv_[2].y : pv_[2].x) >> ((i & 1) * 16)) & 0xffffu;
            u32 v3 = (((i & 2) ? pv_[3].y : pv_[3].x) >> ((i & 1) * 16)) & 0xffffu;
            *(uint2*)(VcT2[buf] + swz128(db4 + i, nb4 * 2)) =
                make_uint2(v0 | (v1 << 16), v2 | (v3 << 16));
        }
    };

    if (isA) { prefetch(0); commit(0); }
    __syncthreads();

    for (int c = 0; c < 64; ++c) {
        const int cur = c & 1, nxt = cur ^ 1;
        f32x4 pk[4], aT[4], go[4];

        if (isA) {
            if (c + 1 < 64) prefetch(c + 1);
            bf16x8 wiA0 = *(const bf16x8*)(SWiN + swz128(wq * 16 + li, g * 16));
            bf16x8 wiA1 = *(const bf16x8*)(SWiN + swz128(wq * 16 + li, 64 + g * 16));
            f32x4 sq[4];
            __builtin_amdgcn_s_setprio(1);
#pragma unroll
            for (int tn = 0; tn < 4; ++tn) {
                bf16x8 b0 = *(const bf16x8*)(SQ2[cur] + swz128(tn * 16 + li, g * 16));
                bf16x8 b1 = *(const bf16x8*)(SQ2[cur] + swz128(tn * 16 + li, 64 + g * 16));
                f32x4 z = (f32x4)0.0f;
                z = __builtin_amdgcn_mfma_f32_16x16x32_bf16(wiA0, b0, z, 0, 0, 0);
                z = __builtin_amdgcn_mfma_f32_16x16x32_bf16(wiA1, b1, z, 0, 0, 0);
                sq[tn] = z;
            }
            __builtin_amdgcn_s_setprio(0);
#pragma unroll
            for (int r = 0; r < 4; ++r) {
                float m = fmaxf(fmaxf(sq[0][r], sq[1][r]), fmaxf(sq[2][r], sq[3][r]));
                m = rmax16(m);
                float e0 = __expf(sq[0][r] - m), e1 = __expf(sq[1][r] - m);
                float e2 = __expf(sq[2][r] - m), e3 = __expf(sq[3][r] - m);
                float inv = frcp(rsum16(e0 + e1 + e2 + e3));
                sq[0][r] = e0 * inv; sq[1][r] = e1 * inv; sq[2][r] = e2 * inv; sq[3][r] = e3 * inv;
            }
#pragma unroll
            for (int tn = 0; tn < 4; ++tn) {
                int n = tn * 16 + li;
                *(uint2*)(SPQ + swz128(n, (wq * 16 + g * 4) * 2)) =
                    make_uint2(pk2(sq[tn][0], sq[tn][1]), pk2(sq[tn][2], sq[tn][3]));
            }
            if (c + 1 < 64) commit(nxt);
            bf16x8 wob0[4], wob1[4];
#pragma unroll
            for (int tn = 0; tn < 4; ++tn) {
                wob0[tn] = *(const bf16x8*)(SWoT2[cur] + swz128(tn * 16 + li, g * 16));
                wob1[tn] = *(const bf16x8*)(SWoT2[cur] + swz128(tn * 16 + li, 64 + g * 16));
            }
            __threadfence_block();
            if (lane == 0) atomicAdd(&cntA, 1u);
            {
                volatile u32* vc = &cntA;
                u32 tgt = 4u * (u32)(c + 1);
                while (*vc < tgt) { __builtin_amdgcn_s_sleep(1); }
            }
            __threadfence_block();
            bf16x8 a0 = *(const bf16x8*)(SPQ + swz128(wq * 16 + li, g * 16));
            bf16x8 a1 = *(const bf16x8*)(SPQ + swz128(wq * 16 + li, 64 + g * 16));
            f32x4 o4[4];
            __builtin_amdgcn_s_setprio(1);
#pragma unroll
            for (int tn = 0; tn < 4; ++tn) {
                f32x4 z = (f32x4)0.0f;
                z = __builtin_amdgcn_mfma_f32_16x16x32_bf16(a0, wob0[tn], z, 0, 0, 0);
                z = __builtin_amdgcn_mfma_f32_16x16x32_bf16(a1, wob1[tn], z, 0, 0, 0);
                o4[tn] = z;
            }
            __builtin_amdgcn_s_setprio(0);
            const size_t obase = ((size_t)(b * 4096 + c * 64)) * 1024 + h * 64;
            const int n_ = wq * 16 + g * 4 + q4;
#pragma unroll
            for (int tn = 0; tn < 4; ++tn) {
                f32x4 to = trans4(o4[tn], q4);
                *(uint2*)(ob + obase + (size_t)n_ * 1024 + tn * 16 + b4) =
                    make_uint2(pk2(to[0], to[1]), pk2(to[2], to[3]));
            }
        } else {
            bf16x8 wiA0 = *(const bf16x8*)(SWiN + swz128(wk * 16 + li, g * 16));
            bf16x8 wiA1 = *(const bf16x8*)(SWiN + swz128(wk * 16 + li, 64 + g * 16));
            __builtin_amdgcn_s_setprio(1);
#pragma unroll
            for (int tn = 0; tn < 4; ++tn) {
                bf16x8 b0 = *(const bf16x8*)(Kc2[cur] + swz128(tn * 16 + li, g * 16));
                bf16x8 b1 = *(const bf16x8*)(Kc2[cur] + swz128(tn * 16 + li, 64 + g * 16));
                f32x4 z = (f32x4)0.0f;
                z = __builtin_amdgcn_mfma_f32_16x16x32_bf16(wiA0, b0, z, 0, 0, 0);
                z = __builtin_amdgcn_mfma_f32_16x16x32_bf16(wiA1, b1, z, 0, 0, 0);
                pk[tn] = z;
            }
            __builtin_amdgcn_s_setprio(0);
#pragma unroll
            for (int r = 0; r < 4; ++r) {
                float m = fmaxf(fmaxf(pk[0][r], pk[1][r]), fmaxf(pk[2][r], pk[3][r]));
                m = rmax16(m);
                float e0 = __expf(pk[0][r] - m), e1 = __expf(pk[1][r] - m);
                float e2 = __expf(pk[2][r] - m), e3 = __expf(pk[3][r] - m);
                float inv = frcp(rsum16(e0 + e1 + e2 + e3));
                pk[0][r] = e0 * inv; pk[1][r] = e1 * inv; pk[2][r] = e2 * inv; pk[3][r] = e3 * inv;
            }
            bf16x8 woA0 = *(const bf16x8*)(SWoN + swz128(wk * 16 + li, g * 16));
            bf16x8 woA1 = *(const bf16x8*)(SWoN + swz128(wk * 16 + li, 64 + g * 16));
            __builtin_amdgcn_s_setprio(1);
#pragma unroll
            for (int tn = 0; tn < 4; ++tn) {
                bf16x8 b0 = *(const bf16x8*)(Vc2[cur] + swz128(tn * 16 + li, g * 16));
                bf16x8 b1 = *(const bf16x8*)(Vc2[cur] + swz128(tn * 16 + li, 64 + g * 16));
                f32x4 z = (f32x4)0.0f;
                z = __builtin_amdgcn_mfma_f32_16x16x32_bf16(woA0, b0, z, 0, 0, 0);
                z = __builtin_amdgcn_mfma_f32_16x16x32_bf16(woA1, b1, z, 0, 0, 0);
                aT[tn] = z;
            }
            __builtin_amdgcn_s_setprio(0);
#pragma unroll
            for (int tn = 0; tn < 4; ++tn) {
                f32x4 t4 = pk[tn] * aT[tn];
                float s_ = t4[0] + t4[1] + t4[2] + t4[3];
                s_ += __shfl_xor(s_, 16);
                s_ += __shfl_xor(s_, 32);
                if (g == 0) spart[wk * 64 + tn * 16 + li] = s_;
            }
#pragma unroll
            for (int tn = 0; tn < 4; ++tn) {
                f32x4 tp = trans4(pk[tn], q4);
                *(uint2*)(SPTN + swz128(wk * 16 + g * 4 + q4, tn * 32 + b4 * 2)) =
                    make_uint2(pk2(tp[0], tp[1]), pk2(tp[2], tp[3]));
            }
            {
                bf16x8 a0 = *(const bf16x8*)(SPTN + swz128(wk * 16 + li, g * 16));
                bf16x8 a1 = *(const bf16x8*)(SPTN + swz128(wk * 16 + li, 64 + g * 16));
                __builtin_amdgcn_s_setprio(1);
#pragma unroll
                for (int tn = 0; tn < 4; ++tn) {
                    bf16x8 b0 = *(const bf16x8*)(VcT2[cur] + swz128(tn * 16 + li, g * 16));
                    bf16x8 b1 = *(const bf16x8*)(VcT2[cur] + swz128(tn * 16 + li, 64 + g * 16));
                    f32x4 z = (f32x4)0.0f;
                    z = __builtin_amdgcn_mfma_f32_16x16x32_bf16(a0, b0, z, 0, 0, 0);
                    z = __builtin_amdgcn_mfma_f32_16x16x32_bf16(a1, b1, z, 0, 0, 0);
                    go[tn] = z;
                }
                __builtin_amdgcn_s_setprio(0);
            }
            bf16x8 kb0[4], kb1[4];
#pragma unroll
            for (int tn = 0; tn < 4; ++tn) {
                kb0[tn] = *(const bf16x8*)(KcT2[cur] + swz128(tn * 16 + li, g * 16));
                kb1[tn] = *(const bf16x8*)(KcT2[cur] + swz128(tn * 16 + li, 64 + g * 16));
            }
            __threadfence_block();
            if (lane == 0) atomicAdd(&cntB, 1u);
            {
                volatile u32* vc = &cntB;
                u32 tgt = 4u * (u32)(c + 1);
                while (*vc < tgt) { __builtin_amdgcn_s_sleep(1); }
            }
            __threadfence_block();
            f32x4 gz[4];
#pragma unroll
            for (int tn = 0; tn < 4; ++tn) {
                int n = tn * 16 + li;
                float sn = spart[n] + spart[64 + n] + spart[128 + n] + spart[192 + n];
#pragma unroll
                for (int r = 0; r < 4; ++r) gz[tn][r] = pk[tn][r] * (sn - aT[tn][r]);
                f32x4 tg = trans4(gz[tn], q4);
                *(uint2*)(SGZN + swz128(wk * 16 + g * 4 + q4, tn * 32 + b4 * 2)) =
                    make_uint2(pk2(tg[0], tg[1]), pk2(tg[2], tg[3]));
            }
            f32x4 gi[4];
            {
                bf16x8 a0 = *(const bf16x8*)(SGZN + swz128(wk * 16 + li, g * 16));
                bf16x8 a1 = *(const bf16x8*)(SGZN + swz128(wk * 16 + li, 64 + g * 16));
                __builtin_amdgcn_s_setprio(1);
#pragma unroll
                for (int tn = 0; tn < 4; ++tn) {
                    f32x4 z = (f32x4)0.0f;
                    z = __builtin_amdgcn_mfma_f32_16x16x32_bf16(a0, kb0[tn], z, 0, 0, 0);
                    z = __builtin_amdgcn_mfma_f32_16x16x32_bf16(a1, kb1[tn], z, 0, 0, 0);
                    gi[tn] = z;
                }
                __builtin_amdgcn_s_setprio(0);
            }
            if (c + 1 < 64) {
                float lin = lrc[c * 4 + 0], lout = lrc[c * 4 + 1];
                float win = lrc[c * 4 + 2], wout = lrc[c * 4 + 3];
#pragma unroll
                for (int tn = 0; tn < 4; ++tn) {
                    WiR[tn] = win * WiR[tn] - lin * gi[tn];
                    WoR[tn] = wout * WoR[tn] + lout * go[tn];   // grad_out = -go
                    int d = tn * 16 + li;
                    *(uint2*)(SWoT2[nxt] + swz128(d, wk * 32 + g * 8)) =
                        make_uint2(pk2(WoR[tn][0], WoR[tn][1]), pk2(WoR[tn][2], WoR[tn][3]));
                    f32x4 ti = trans4(WiR[tn], q4);
                    *(uint2*)(SWiN + swz128(wk * 16 + g * 4 + q4, tn * 32 + b4 * 2)) =
                        make_uint2(pk2(ti[0], ti[1]), pk2(ti[2], ti[3]));
                    f32x4 to = trans4(WoR[tn], q4);
                    *(uint2*)(SWoN + swz128(wk * 16 + g * 4 + q4, tn * 32 + b4 * 2)) =
                        make_uint2(pk2(to[0], to[1]), pk2(to[2], to[3]));
                }
            }
        }
        __syncthreads();
    }
}

// ---------------------------------------------------------------------------
// Kernel D: out_proj (swizzled R10)
// ---------------------------------------------------------------------------
__global__ __launch_bounds__(256) void out_proj_kernel(
    const u16* __restrict__ ob, const u16* __restrict__ wob, float* __restrict__ out)
{
    __shared__ __align__(16) char As[128 * 128];
    __shared__ __align__(16) char Bs[128 * 128];
    const int bn = blockIdx.x;
    const int bm = blockIdx.y;
    const int cb = bn * 128;
    const int rb = bm * 128;
    const int tid = threadIdx.x;
    const int lane = tid & 63;
    const int wv = tid >> 6;
    const int wr = (wv >> 1) * 64, wc = (wv & 1) * 64;
    const int li = lane & 15, g = lane >> 4;
    const int lr8 = lane >> 3, lc8 = lane & 7;

    f32x4 acc[4][4];
#pragma unroll
    for (int i = 0; i < 4; ++i)
#pragma unroll
        for (int j = 0; j < 4; ++j) acc[i][j] = (f32x4)0.0f;

    for (int k0 = 0; k0 < 1024; k0 += 64) {
        __syncthreads();
#pragma unroll
        for (int ld = 0; ld < 4; ++ld) {
            int r0 = wv * 32 + ld * 8;
            int rowT = r0 + lr8;
            int csw = (lc8 * 8) ^ ((rowT & 7) << 3);
            gload_lds16(ob + (size_t)(rb + rowT) * 1024 + k0 + csw, As + r0 * 128);
            gload_lds16(wob + (size_t)(cb + rowT) * 1024 + k0 + csw, Bs + r0 * 128);
        }
        __syncthreads();
#pragma unroll
        for (int ks = 0; ks < 2; ++ks) {
            bf16x8 af[4], bfr[4];
#pragma unroll
            for (int m = 0; m < 4; ++m)
                af[m] = *(const bf16x8*)(As + swz128(wr + m * 16 + li, ks * 64 + g * 16));
#pragma unroll
            for (int n = 0; n < 4; ++n)
                bfr[n] = *(const bf16x8*)(Bs + swz128(wc + n * 16 + li, ks * 64 + g * 16));
#pragma unroll
            for (int m = 0; m < 4; ++m)
#pragma unroll
                for (int n = 0; n < 4; ++n)
                    acc[m][n] = __builtin_amdgcn_mfma_f32_16x16x32_bf16(af[m], bfr[n], acc[m][n], 0, 0, 0);
        }
    }
#pragma unroll
    for (int m = 0; m < 4; ++m) {
        int t = rb + wr + m * 16 + g * 4;
#pragma unroll
        for (int r = 0; r < 4; ++r) {
#pragma unroll
            for (int n = 0; n < 4; ++n) {
                int col = cb + wc + n * 16 + li;
                out[(size_t)(t + r) * 1024 + col] = acc[m][n][r];
            }
        }
    }
}

// ---------------------------------------------------------------------------
extern "C" void kernel_launch(void* const* d_in, const int* in_sizes, int n_in,
                              void* d_out, int out_size, void* d_ws, size_t ws_size,
                              hipStream_t stream)
{
    const float* x     = (const float*)d_in[0];
    const float* Wq    = (const float*)d_in[1];
    const float* Wk    = (const float*)d_in[2];
    const float* Wv    = (const float*)d_in[3];
    const float* Wlr   = (const float*)d_in[4];
    const float* Wbeta = (const float*)d_in[5];
    const float* Wo    = (const float*)d_in[6];
    const float* Wi0   = (const float*)d_in[7];
    const float* Wo0   = (const float*)d_in[8];
    float* out = (float*)d_out;

    char* od = (char*)d_out;
    u16* xb  = (u16*)(od);                 // dead before out_proj overwrites
    u16* wb  = (u16*)(od + 33554432u);
    u16* wlb = (u16*)(od + 39845888u);

    char* ws = (char*)d_ws;
    u16* qb        = (u16*)(ws);
    u16* kb        = (u16*)(ws + 33554432u);
    u16* vb        = (u16*)(ws + 67108864u);
    u16* obuf      = (u16*)(ws + 100663296u);
    float* lrc_all = (float*)(ws + 134217728u);
    u16* wob       = (u16*)(ws + 134283264u);
    if (ws_size < 136380416u) return;

    convert_kernel<<<2048, 256, 0, stream>>>(x, Wq, Wk, Wv, Wo, Wlr, Wbeta,
                                             xb, wb, wob, wlb);
    proj_qkv_kernel<<<dim3(12, 64), 512, 0, stream>>>(xb, wb, qb, kb, vb);
    lrwd_kernel<<<128, 256, 0, stream>>>(xb, wlb, lrc_all);
    scan_kernel<<<64, 512, 0, stream>>>(qb, kb, vb, lrc_all, Wi0, Wo0, obuf);
    out_proj_kernel<<<dim3(8, 128), 256, 0, stream>>>(obuf, wob, out);
}

// Round 14
// 470.436 us; speedup vs baseline: 1.7087x; 1.0383x over previous
//
#include <hip/hip_runtime.h>
#include <stdint.h>

typedef unsigned short u16;
typedef uint32_t u32;
typedef __attribute__((ext_vector_type(4))) float f32x4;
typedef __attribute__((ext_vector_type(8))) short bf16x8;

#define DEVINL __device__ __forceinline__

DEVINL u16 f2bf(float f) {
    union { float f; u32 u; } a; a.f = f;
    u32 u = a.u;
    return (u16)((u + 0x7fffu + ((u >> 16) & 1u)) >> 16);   // RNE
}
DEVINL u32 pk2(float a, float b) { return (u32)f2bf(a) | ((u32)f2bf(b) << 16); }

// 128B-row swizzled tile (conflict-free vector row reads) — verified R2..R13
DEVINL u32 swz128(u32 row, u32 colb) { return row * 128u + (colb ^ ((row & 7u) << 4)); }

// async global->LDS, 16B per lane
DEVINL void gload_lds16(const u16* g, char* l) {
    __builtin_amdgcn_global_load_lds(
        (const __attribute__((address_space(1))) void*)g,
        (__attribute__((address_space(3))) void*)l, 16, 0, 0);
}

// fast reciprocal (v_rcp_f32) — softmax denominators in [1,64]
DEVINL float frcp(float x) { float r; asm("v_rcp_f32 %0, %1" : "=v"(r) : "v"(x)); return r; }

// ---- DPP cross-lane (VALU pipe) — verified R11 ----
template<int C> DEVINL float fdpp(float x) {
    union { float f; int i; } a, b; a.f = x;
    b.i = __builtin_amdgcn_update_dpp(0, a.i, C, 0xf, 0xf, false);
    return b.f;
}
DEVINL float rmax16(float v) {
    v = fmaxf(v, fdpp<0x128>(v)); v = fmaxf(v, fdpp<0x124>(v));
    v = fmaxf(v, fdpp<0x122>(v)); v = fmaxf(v, fdpp<0x121>(v)); return v;
}
DEVINL float rsum16(float v) {
    v += fdpp<0x128>(v); v += fdpp<0x124>(v);
    v += fdpp<0x122>(v); v += fdpp<0x121>(v); return v;
}

// 4x4 transpose among 4 lanes via DPP quad_perm — verified R11
DEVINL f32x4 trans4(f32x4 v, int q) {
    float s0 = fdpp<0xB1>(v[0]), s1 = fdpp<0xB1>(v[1]),
          s2 = fdpp<0xB1>(v[2]), s3 = fdpp<0xB1>(v[3]);
    f32x4 t;
    bool q1 = (q & 1) != 0;
    t[0] = q1 ? s1 : v[0];
    t[1] = q1 ? v[1] : s0;
    t[2] = q1 ? s3 : v[2];
    t[3] = q1 ? v[3] : s2;
    float u0 = fdpp<0x4E>(t[0]), u1 = fdpp<0x4E>(t[1]),
          u2 = fdpp<0x4E>(t[2]), u3 = fdpp<0x4E>(t[3]);
    f32x4 r;
    bool q2 = (q & 2) != 0;
    r[0] = q2 ? u2 : t[0];
    r[1] = q2 ? u3 : t[1];
    r[2] = q2 ? t[2] : u0;
    r[3] = q2 ? t[3] : u1;
    return r;
}

// ---- raw-barrier pipeline primitives (T3/T4) — verified R13 ----
#define LGW()  do { asm volatile("s_waitcnt lgkmcnt(0)" ::: "memory"); \
                    __builtin_amdgcn_sched_barrier(0); } while (0)
#define VMW(N) do { asm volatile("s_waitcnt vmcnt(" #N ")" ::: "memory"); \
                    __builtin_amdgcn_sched_barrier(0); } while (0)
#define BARRAW() do { __builtin_amdgcn_sched_barrier(0); \
                      __builtin_amdgcn_s_barrier(); \
                      __builtin_amdgcn_sched_barrier(0); } while (0)

#define RDA(BUF, Q, AF)                                                       \
    _Pragma("unroll")                                                         \
    for (int i_ = 0; i_ < 2; ++i_)                                            \
        _Pragma("unroll")                                                     \
        for (int kk_ = 0; kk_ < 2; ++kk_)                                     \
            AF[i_ * 2 + kk_] = *(const bf16x8*)(&A2[BUF][swz128(              \
                wm * 128 + (2 * (Q) + i_) * 16 + li, kk_ * 64 + g * 16)]);

#define PROJ_MFMA(Q, AF)                                                      \
    __builtin_amdgcn_s_setprio(1);                                            \
    _Pragma("unroll")                                                         \
    for (int i_ = 0; i_ < 2; ++i_)                                            \
        _Pragma("unroll")                                                     \
        for (int nf_ = 0; nf_ < 4; ++nf_) {                                   \
            acc[2 * (Q) + i_][nf_] = __builtin_amdgcn_mfma_f32_16x16x32_bf16( \
                AF[i_ * 2 + 0], Bfr[nf_ * 2 + 0], acc[2 * (Q) + i_][nf_], 0, 0, 0); \
            acc[2 * (Q) + i_][nf_] = __builtin_amdgcn_mfma_f32_16x16x32_bf16( \
                AF[i_ * 2 + 1], Bfr[nf_ * 2 + 1], acc[2 * (Q) + i_][nf_], 0, 0, 0); \
        }                                                                     \
    __builtin_amdgcn_s_setprio(0);

// shared ring-2 K-loop body (16 K-tiles) — verified R13
#define RING2_KLOOP(STA, STB)                                                 \
    _Pragma("unroll")                                                         \
    for (int p = 0; p < 4; ++p) { STA(0, p, 0); STB(0, p, 0); }               \
    _Pragma("unroll")                                                         \
    for (int p = 0; p < 4; ++p) { STA(1, p, 1); STB(1, p, 1); }               \
    VMW(8);                                                                   \
    BARRAW();                                                                 \
    for (int kt = 0; kt < 16; ++kt) {                                         \
        const int buf = kt & 1;                                               \
        const bool st = (kt + 2 < 16);                                        \
        bf16x8 Bfr[8];                                                        \
        _Pragma("unroll")                                                     \
        for (int nf = 0; nf < 4; ++nf)                                        \
            _Pragma("unroll")                                                 \
            for (int kk = 0; kk < 2; ++kk)                                    \
                Bfr[nf * 2 + kk] = *(const bf16x8*)(&B2[buf][swz128(          \
                    wn * 64 + nf * 16 + li, kk * 64 + g * 16)]);              \
        bf16x8 Af0[4], Af1[4];                                                \
        RDA(buf, 0, Af0);                                                     \
        LGW();                                                                \
        BARRAW();                                                             \
        RDA(buf, 1, Af1);                                                     \
        if (st) STB(kt + 2, 0, buf);                                          \
        PROJ_MFMA(0, Af0);                                                    \
        LGW();                                                                \
        RDA(buf, 2, Af0);                                                     \
        if (st) STB(kt + 2, 1, buf);                                          \
        PROJ_MFMA(1, Af1);                                                    \
        LGW();                                                                \
        RDA(buf, 3, Af1);                                                     \
        if (st) { STB(kt + 2, 2, buf); STB(kt + 2, 3, buf); }                 \
        PROJ_MFMA(2, Af0);                                                    \
        LGW();                                                                \
        BARRAW();                                                             \
        if (st) { STA(kt + 2, 0, buf); STA(kt + 2, 1, buf);                   \
                  STA(kt + 2, 2, buf); STA(kt + 2, 3, buf); }                 \
        PROJ_MFMA(3, Af1);                                                    \
        if (kt < 14) { VMW(8); } else if (kt == 14) { VMW(0); }               \
        BARRAW();                                                             \
    }

// ---------------------------------------------------------------------------
// Kernel 0: fp32 -> bf16 convert pass
// ---------------------------------------------------------------------------
__global__ __launch_bounds__(256) void convert_kernel(
    const float* __restrict__ x, const float* __restrict__ Wq,
    const float* __restrict__ Wk, const float* __restrict__ Wv,
    const float* __restrict__ Wo, const float* __restrict__ Wlr,
    const float* __restrict__ Wbeta,
    u16* __restrict__ xb, u16* __restrict__ wb, u16* __restrict__ wob,
    u16* __restrict__ wlb)
{
    const int t0 = blockIdx.x * 256 + threadIdx.x;
    const int stride = gridDim.x * 256;
    auto cv = [&](const float* src, u16* dst, int n4) {
        for (int i = t0; i < n4; i += stride) {
            float4 v = ((const float4*)src)[i];
            uint2 p;
            p.x = pk2(v.x, v.y);
            p.y = pk2(v.z, v.w);
            ((uint2*)dst)[i] = p;
        }
    };
    cv(x, xb, 4194304);
    cv(Wq, wb, 262144);
    cv(Wk, wb + 1048576, 262144);
    cv(Wv, wb + 2097152, 262144);
    cv(Wo, wob, 262144);
    cv(Wlr, wlb, 8192);
    cv(Wbeta, wlb + 32768, 8192);
}

// ---------------------------------------------------------------------------
// Kernel A: q/k/v projections — ring-2 256x256, verified R13
// ---------------------------------------------------------------------------
__global__ __launch_bounds__(512) void proj_qkv_kernel(
    const u16* __restrict__ xb, const u16* __restrict__ wb,
    u16* __restrict__ qb, u16* __restrict__ kb, u16* __restrict__ vb)
{
    __shared__ __align__(16) char A2[2][32768];
    __shared__ __align__(16) char B2[2][32768];
    const int bn = blockIdx.x;            // 0..11
    const int bm = blockIdx.y;            // 0..63
    const int wsel = bn >> 2;
    u16* __restrict__ dst = (wsel == 0) ? qb : ((wsel == 1) ? kb : vb);
    const int cb = (bn & 3) * 256;
    const int wrow = bn * 256;
    const int rb = bm * 256;
    const int tid = threadIdx.x;
    const int lane = tid & 63;
    const int w8 = tid >> 6;
    const int wm = w8 >> 2;
    const int wn = w8 & 3;
    const int li = lane & 15, g = lane >> 4;
    const int q4 = li & 3, b4 = li & 12;

    const int srow = tid >> 3;
    const int scol8 = (tid & 7) * 8;
    auto stA = [&](int kt2, int pass, int buf) {
        int rowT = pass * 64 + srow;
        int csw = scol8 ^ ((rowT & 7) << 3);
        gload_lds16(xb + (size_t)(rb + rowT) * 1024 + kt2 * 64 + csw,
                    &A2[buf][pass * 8192 + tid * 16]);
    };
    auto stB = [&](int kt2, int pass, int buf) {
        int rowT = pass * 64 + srow;
        int csw = scol8 ^ ((rowT & 7) << 3);
        gload_lds16(wb + (size_t)(wrow + rowT) * 1024 + kt2 * 64 + csw,
                    &B2[buf][pass * 8192 + tid * 16]);
    };

    f32x4 acc[8][4];
#pragma unroll
    for (int i = 0; i < 8; ++i)
#pragma unroll
        for (int j = 0; j < 4; ++j) acc[i][j] = (f32x4)0.0f;

    RING2_KLOOP(stA, stB);

    const bool do_silu = (wsel < 2);
#pragma unroll
    for (int mf = 0; mf < 8; ++mf) {
        const int n_ = rb + wm * 128 + mf * 16 + g * 4 + q4;
#pragma unroll
        for (int nf = 0; nf < 4; ++nf) {
            f32x4 o = acc[mf][nf];
            if (do_silu) {
#pragma unroll
                for (int r = 0; r < 4; ++r) o[r] = o[r] / (1.0f + __expf(-o[r]));
            }
            f32x4 to = trans4(o, q4);
            *(uint2*)(dst + (size_t)n_ * 1024 + cb + wn * 64 + nf * 16 + b4) =
                make_uint2(pk2(to[0], to[1]), pk2(to[2], to[3]));
        }
    }
}

// ---------------------------------------------------------------------------
// Kernel D (R14): out_proj — same ring-2 256x256 template, fp32 out.
// out[t][m] = sum_j o[t][j] * Wo[m][j]
// ---------------------------------------------------------------------------
__global__ __launch_bounds__(512) void out_proj_kernel(
    const u16* __restrict__ ob, const u16* __restrict__ wob, float* __restrict__ out)
{
    __shared__ __align__(16) char A2[2][32768];
    __shared__ __align__(16) char B2[2][32768];
    const int bn = blockIdx.x;            // 0..3
    const int bm = blockIdx.y;            // 0..63
    const int cb = bn * 256;
    const int rb = bm * 256;
    const int tid = threadIdx.x;
    const int lane = tid & 63;
    const int w8 = tid >> 6;
    const int wm = w8 >> 2;
    const int wn = w8 & 3;
    const int li = lane & 15, g = lane >> 4;
    const int q4 = li & 3, b4 = li & 12;

    const int srow = tid >> 3;
    const int scol8 = (tid & 7) * 8;
    auto stA = [&](int kt2, int pass, int buf) {
        int rowT = pass * 64 + srow;
        int csw = scol8 ^ ((rowT & 7) << 3);
        gload_lds16(ob + (size_t)(rb + rowT) * 1024 + kt2 * 64 + csw,
                    &A2[buf][pass * 8192 + tid * 16]);
    };
    auto stB = [&](int kt2, int pass, int buf) {
        int rowT = pass * 64 + srow;
        int csw = scol8 ^ ((rowT & 7) << 3);
        gload_lds16(wob + (size_t)(cb + rowT) * 1024 + kt2 * 64 + csw,
                    &B2[buf][pass * 8192 + tid * 16]);
    };

    f32x4 acc[8][4];
#pragma unroll
    for (int i = 0; i < 8; ++i)
#pragma unroll
        for (int j = 0; j < 4; ++j) acc[i][j] = (f32x4)0.0f;

    RING2_KLOOP(stA, stB);

    // epilogue: fp32, float4 per (mf,nf) via trans4 (16B aligned: b4*4)
#pragma unroll
    for (int mf = 0; mf < 8; ++mf) {
        const int n_ = rb + wm * 128 + mf * 16 + g * 4 + q4;
#pragma unroll
        for (int nf = 0; nf < 4; ++nf) {
            f32x4 to = trans4(acc[mf][nf], q4);
            *(float4*)(out + (size_t)n_ * 1024 + cb + wn * 64 + nf * 16 + b4) =
                make_float4(to[0], to[1], to[2], to[3]);
        }
    }
}

// ---------------------------------------------------------------------------
// Kernel B: lr/wd heads (swizzled R10)
// ---------------------------------------------------------------------------
__global__ __launch_bounds__(256) void lrwd_kernel(
    const u16* __restrict__ xb, const u16* __restrict__ wlb,
    float* __restrict__ lrc_all)
{
    __shared__ __align__(16) char As[128 * 128];
    __shared__ __align__(16) char Bs[64 * 128];
    __shared__ float red[128][65];
    const int bm = blockIdx.x;
    const int rb = bm * 128;
    const int tid = threadIdx.x;
    const int lane = tid & 63;
    const int wv = tid >> 6;
    const int li = lane & 15, g = lane >> 4;
    const int lr8 = lane >> 3, lc8 = lane & 7;

    f32x4 acc[2][4];
#pragma unroll
    for (int i = 0; i < 2; ++i)
#pragma unroll
        for (int j = 0; j < 4; ++j) acc[i][j] = (f32x4)0.0f;

    for (int k0 = 0; k0 < 1024; k0 += 64) {
        __syncthreads();
#pragma unroll
        for (int ld = 0; ld < 4; ++ld) {
            int r0 = wv * 32 + ld * 8;
            int rowT = r0 + lr8;
            int csw = (lc8 * 8) ^ ((rowT & 7) << 3);
            gload_lds16(xb + (size_t)(rb + rowT) * 1024 + k0 + csw, As + r0 * 128);
        }
#pragma unroll
        for (int ld = 0; ld < 2; ++ld) {
            int r0 = wv * 16 + ld * 8;
            int rowT = r0 + lr8;
            int csw = (lc8 * 8) ^ ((rowT & 7) << 3);
            gload_lds16(wlb + (size_t)rowT * 1024 + k0 + csw, Bs + r0 * 128);
        }
        __syncthreads();
#pragma unroll
        for (int ks = 0; ks < 2; ++ks) {
            bf16x8 af[2], bfr[4];
#pragma unroll
            for (int m = 0; m < 2; ++m)
                af[m] = *(const bf16x8*)(As + swz128(wv * 32 + m * 16 + li, ks * 64 + g * 16));
#pragma unroll
            for (int n = 0; n < 4; ++n)
                bfr[n] = *(const bf16x8*)(Bs + swz128(n * 16 + li, ks * 64 + g * 16));
#pragma unroll
            for (int m = 0; m < 2; ++m)
#pragma unroll
                for (int n = 0; n < 4; ++n)
                    acc[m][n] = __builtin_amdgcn_mfma_f32_16x16x32_bf16(af[m], bfr[n], acc[m][n], 0, 0, 0);
        }
    }
#pragma unroll
    for (int m = 0; m < 2; ++m) {
#pragma unroll
        for (int n = 0; n < 4; ++n) {
            int col = n * 16 + li;
            float scale = (col < 32) ? 1e-3f : 0.9f;
#pragma unroll
            for (int r = 0; r < 4; ++r) {
                int t = wv * 32 + m * 16 + g * 4 + r;
                float s = acc[m][n][r];
                red[t][col] = scale / (1.0f + __expf(-s));
            }
        }
    }
    __syncthreads();
    if (tid < 128) {
        int chunk = tid >> 6, col = tid & 63;
        float s = 0.f;
#pragma unroll
        for (int i = 0; i < 64; ++i) s += red[chunk * 64 + i][col];
        int b = bm >> 5;
        int cidx = (bm & 31) * 2 + chunk;
        lrc_all[((size_t)(b * 64 + cidx)) * 64 + col] = s * (1.0f / 64.0f);
    }
}

// ---------------------------------------------------------------------------
// Kernel C: chunk scan — R12 verbatim (280 us verified best)
// ---------------------------------------------------------------------------
__global__ __launch_bounds__(512) void scan_kernel(
    const u16* __restrict__ qb, const u16* __restrict__ kb, const u16* __restrict__ vb,
    const float* __restrict__ lrc_all, const float* __restrict__ Wi0,
    const float* __restrict__ Wo0, u16* __restrict__ ob)
{
    const int bh = blockIdx.x;
    const int b = bh >> 4, h = bh & 15;
    const int tid = threadIdx.x;
    const int lane = tid & 63;
    const int w8 = tid >> 6;            // 0..7
    const bool isA = (w8 < 4);
    const int wq = w8;
    const int wk = w8 - 4;
    const int li = lane & 15, g = lane >> 4;
    const int q4 = li & 3, b4 = li & 12;

    __shared__ __align__(16) char SQ2[2][8192];
    __shared__ __align__(16) char Kc2[2][8192];
    __shared__ __align__(16) char Vc2[2][8192];
    __shared__ __align__(16) char KcT2[2][8192];
    __shared__ __align__(16) char VcT2[2][8192];
    __shared__ __align__(16) char SWoT2[2][8192];
    __shared__ __align__(16) char SWiN[8192];
    __shared__ __align__(16) char SWoN[8192];
    __shared__ __align__(16) char SPQ[8192];
    __shared__ __align__(16) char SPTN[8192];
    __shared__ __align__(16) char SGZN[8192];
    __shared__ float spart[256];
    __shared__ float lrc[256];
    __shared__ u32 cntA, cntB;

    if (tid == 0) { cntA = 0u; cntB = 0u; }

    f32x4 WiR[4], WoR[4];
    if (!isA) {
#pragma unroll
        for (int tn = 0; tn < 4; ++tn) {
            int d = tn * 16 + li;
#pragma unroll
            for (int r = 0; r < 4; ++r) {
                int D = wk * 16 + g * 4 + r;
                WiR[tn][r] = Wi0[((size_t)D * 16 + h) * 64 + d];
                WoR[tn][r] = Wo0[((size_t)D * 16 + h) * 64 + d];
            }
            *(uint2*)(SWoT2[0] + swz128(d, wk * 32 + g * 8)) =
                make_uint2(pk2(WoR[tn][0], WoR[tn][1]), pk2(WoR[tn][2], WoR[tn][3]));
            f32x4 ti = trans4(WiR[tn], q4);
            *(uint2*)(SWiN + swz128(wk * 16 + g * 4 + q4, tn * 32 + b4 * 2)) =
                make_uint2(pk2(ti[0], ti[1]), pk2(ti[2], ti[3]));
            f32x4 to = trans4(WoR[tn], q4);
            *(uint2*)(SWoN + swz128(wk * 16 + g * 4 + q4, tn * 32 + b4 * 2)) =
                make_uint2(pk2(to[0], to[1]), pk2(to[2], to[3]));
        }
    }
    if (tid < 256) {
        int cc = tid >> 2, j = tid & 3;
        lrc[cc * 4 + j] = lrc_all[((size_t)(b * 64 + cc)) * 64 + j * 16 + h];
    }

    const int nb4 = ((tid & 255) >> 4) * 4;
    const int db4 = (tid & 15) * 4;
    uint4 pq_[2];
    uint2 pk_[4], pv_[4];
    auto prefetch = [&](int c) {
        const size_t base = ((size_t)(b * 4096 + c * 64)) * 1024 + h * 64;
#pragma unroll
        for (int p = 0; p < 2; ++p) {
            int id = p * 256 + (tid & 255);
            int n = id >> 3;
            int d0 = (id & 7) * 8;
            pq_[p] = *(const uint4*)(qb + base + (size_t)n * 1024 + d0);
        }
#pragma unroll
        for (int j = 0; j < 4; ++j) {
            pk_[j] = *(const uint2*)(kb + base + (size_t)(nb4 + j) * 1024 + db4);
            pv_[j] = *(const uint2*)(vb + base + (size_t)(nb4 + j) * 1024 + db4);
        }
    };
    auto commit = [&](int buf) {
#pragma unroll
        for (int p = 0; p < 2; ++p) {
            int id = p * 256 + (tid & 255);
            int n = id >> 3;
            int d0 = (id & 7) * 8;
            *(uint4*)(SQ2[buf] + swz128(n, d0 * 2)) = pq_[p];
        }
#pragma unroll
        for (int j = 0; j < 4; ++j) {
            *(uint2*)(Kc2[buf] + swz128(nb4 + j, db4 * 2)) = pk_[j];
            *(uint2*)(Vc2[buf] + swz128(nb4 + j, db4 * 2)) = pv_[j];
        }
#pragma unroll
        for (int i = 0; i < 4; ++i) {
            u32 k0 = (((i & 2) ? pk_[0].y : pk_[0].x) >> ((i & 1) * 16)) & 0xffffu;
            u32 k1 = (((i & 2) ? pk_[1].y : pk_[1].x) >> ((i & 1) * 16)) & 0xffffu;
            u32 k2 = (((i & 2) ? pk_[2].y : pk_[2].x) >> ((i & 1) * 16)) & 0xffffu;
            u32 k3 = (((i & 2) ? pk_[3].y : pk_[3].x) >> ((i & 1) * 16)) & 0xffffu;
            *(uint2*)(KcT2[buf] + swz128(db4 + i, nb4 * 2)) =
                make_uint2(k0 | (k1 << 16), k2 | (k3 << 16));
            u32 v0 = (((i & 2) ? pv_[0].y : pv_[0].x) >> ((i & 1) * 16)) & 0xffffu;
            u32 v1 = (((i & 2) ? pv_[1].y : pv_[1].x) >> ((i & 1) * 16)) & 0xffffu;
            u32 v2 = (((i & 2) ? pv_[2].y : pv_[2].x) >> ((i & 1) * 16)) & 0xffffu;
            u32 v3 = (((i & 2) ? pv_[3].y : pv_[3].x) >> ((i & 1) * 16)) & 0xffffu;
            *(uint2*)(VcT2[buf] + swz128(db4 + i, nb4 * 2)) =
                make_uint2(v0 | (v1 << 16), v2 | (v3 << 16));
        }
    };

    if (isA) { prefetch(0); commit(0); }
    __syncthreads();

    for (int c = 0; c < 64; ++c) {
        const int cur = c & 1, nxt = cur ^ 1;
        f32x4 pk[4], aT[4], go[4];

        if (isA) {
            if (c + 1 < 64) prefetch(c + 1);
            bf16x8 wiA0 = *(const bf16x8*)(SWiN + swz128(wq * 16 + li, g * 16));
            bf16x8 wiA1 = *(const bf16x8*)(SWiN + swz128(wq * 16 + li, 64 + g * 16));
            f32x4 sq[4];
            __builtin_amdgcn_s_setprio(1);
#pragma unroll
            for (int tn = 0; tn < 4; ++tn) {
                bf16x8 b0 = *(const bf16x8*)(SQ2[cur] + swz128(tn * 16 + li, g * 16));
                bf16x8 b1 = *(const bf16x8*)(SQ2[cur] + swz128(tn * 16 + li, 64 + g * 16));
                f32x4 z = (f32x4)0.0f;
                z = __builtin_amdgcn_mfma_f32_16x16x32_bf16(wiA0, b0, z, 0, 0, 0);
                z = __builtin_amdgcn_mfma_f32_16x16x32_bf16(wiA1, b1, z, 0, 0, 0);
                sq[tn] = z;
            }
            __builtin_amdgcn_s_setprio(0);
#pragma unroll
            for (int r = 0; r < 4; ++r) {
                float m = fmaxf(fmaxf(sq[0][r], sq[1][r]), fmaxf(sq[2][r], sq[3][r]));
                m = rmax16(m);
                float e0 = __expf(sq[0][r] - m), e1 = __expf(sq[1][r] - m);
                float e2 = __expf(sq[2][r] - m), e3 = __expf(sq[3][r] - m);
                float inv = frcp(rsum16(e0 + e1 + e2 + e3));
                sq[0][r] = e0 * inv; sq[1][r] = e1 * inv; sq[2][r] = e2 * inv; sq[3][r] = e3 * inv;
            }
#pragma unroll
            for (int tn = 0; tn < 4; ++tn) {
                int n = tn * 16 + li;
                *(uint2*)(SPQ + swz128(n, (wq * 16 + g * 4) * 2)) =
                    make_uint2(pk2(sq[tn][0], sq[tn][1]), pk2(sq[tn][2], sq[tn][3]));
            }
            if (c + 1 < 64) commit(nxt);
            bf16x8 wob0[4], wob1[4];
#pragma unroll
            for (int tn = 0; tn < 4; ++tn) {
                wob0[tn] = *(const bf16x8*)(SWoT2[cur] + swz128(tn * 16 + li, g * 16));
                wob1[tn] = *(const bf16x8*)(SWoT2[cur] + swz128(tn * 16 + li, 64 + g * 16));
            }
            __threadfence_block();
            if (lane == 0) atomicAdd(&cntA, 1u);
            {
                volatile u32* vc = &cntA;
                u32 tgt = 4u * (u32)(c + 1);
                while (*vc < tgt) { __builtin_amdgcn_s_sleep(1); }
            }
            __threadfence_block();
            bf16x8 a0 = *(const bf16x8*)(SPQ + swz128(wq * 16 + li, g * 16));
            bf16x8 a1 = *(const bf16x8*)(SPQ + swz128(wq * 16 + li, 64 + g * 16));
            f32x4 o4[4];
            __builtin_amdgcn_s_setprio(1);
#pragma unroll
            for (int tn = 0; tn < 4; ++tn) {
                f32x4 z = (f32x4)0.0f;
                z = __builtin_amdgcn_mfma_f32_16x16x32_bf16(a0, wob0[tn], z, 0, 0, 0);
                z = __builtin_amdgcn_mfma_f32_16x16x32_bf16(a1, wob1[tn], z, 0, 0, 0);
                o4[tn] = z;
            }
            __builtin_amdgcn_s_setprio(0);
            const size_t obase = ((size_t)(b * 4096 + c * 64)) * 1024 + h * 64;
            const int n_ = wq * 16 + g * 4 + q4;
#pragma unroll
            for (int tn = 0; tn < 4; ++tn) {
                f32x4 to = trans4(o4[tn], q4);
                *(uint2*)(ob + obase + (size_t)n_ * 1024 + tn * 16 + b4) =
                    make_uint2(pk2(to[0], to[1]), pk2(to[2], to[3]));
            }
        } else {
            bf16x8 wiA0 = *(const bf16x8*)(SWiN + swz128(wk * 16 + li, g * 16));
            bf16x8 wiA1 = *(const bf16x8*)(SWiN + swz128(wk * 16 + li, 64 + g * 16));
            __builtin_amdgcn_s_setprio(1);
#pragma unroll
            for (int tn = 0; tn < 4; ++tn) {
                bf16x8 b0 = *(const bf16x8*)(Kc2[cur] + swz128(tn * 16 + li, g * 16));
                bf16x8 b1 = *(const bf16x8*)(Kc2[cur] + swz128(tn * 16 + li, 64 + g * 16));
                f32x4 z = (f32x4)0.0f;
                z = __builtin_amdgcn_mfma_f32_16x16x32_bf16(wiA0, b0, z, 0, 0, 0);
                z = __builtin_amdgcn_mfma_f32_16x16x32_bf16(wiA1, b1, z, 0, 0, 0);
                pk[tn] = z;
            }
            __builtin_amdgcn_s_setprio(0);
#pragma unroll
            for (int r = 0; r < 4; ++r) {
                float m = fmaxf(fmaxf(pk[0][r], pk[1][r]), fmaxf(pk[2][r], pk[3][r]));
                m = rmax16(m);
                float e0 = __expf(pk[0][r] - m), e1 = __expf(pk[1][r] - m);
                float e2 = __expf(pk[2][r] - m), e3 = __expf(pk[3][r] - m);
                float inv = frcp(rsum16(e0 + e1 + e2 + e3));
                pk[0][r] = e0 * inv; pk[1][r] = e1 * inv; pk[2][r] = e2 * inv; pk[3][r] = e3 * inv;
            }
            bf16x8 woA0 = *(const bf16x8*)(SWoN + swz128(wk * 16 + li, g * 16));
            bf16x8 woA1 = *(const bf16x8*)(SWoN + swz128(wk * 16 + li, 64 + g * 16));
            __builtin_amdgcn_s_setprio(1);
#pragma unroll
            for (int tn = 0; tn < 4; ++tn) {
                bf16x8 b0 = *(const bf16x8*)(Vc2[cur] + swz128(tn * 16 + li, g * 16));
                bf16x8 b1 = *(const bf16x8*)(Vc2[cur] + swz128(tn * 16 + li, 64 + g * 16));
                f32x4 z = (f32x4)0.0f;
                z = __builtin_amdgcn_mfma_f32_16x16x32_bf16(woA0, b0, z, 0, 0, 0);
                z = __builtin_amdgcn_mfma_f32_16x16x32_bf16(woA1, b1, z, 0, 0, 0);
                aT[tn] = z;
            }
            __builtin_amdgcn_s_setprio(0);
#pragma unroll
            for (int tn = 0; tn < 4; ++tn) {
                f32x4 t4 = pk[tn] * aT[tn];
                float s_ = t4[0] + t4[1] + t4[2] + t4[3];
                s_ += __shfl_xor(s_, 16);
                s_ += __shfl_xor(s_, 32);
                if (g == 0) spart[wk * 64 + tn * 16 + li] = s_;
            }
#pragma unroll
            for (int tn = 0; tn < 4; ++tn) {
                f32x4 tp = trans4(pk[tn], q4);
                *(uint2*)(SPTN + swz128(wk * 16 + g * 4 + q4, tn * 32 + b4 * 2)) =
                    make_uint2(pk2(tp[0], tp[1]), pk2(tp[2], tp[3]));
            }
            {
                bf16x8 a0 = *(const bf16x8*)(SPTN + swz128(wk * 16 + li, g * 16));
                bf16x8 a1 = *(const bf16x8*)(SPTN + swz128(wk * 16 + li, 64 + g * 16));
                __builtin_amdgcn_s_setprio(1);
#pragma unroll
                for (int tn = 0; tn < 4; ++tn) {
                    bf16x8 b0 = *(const bf16x8*)(VcT2[cur] + swz128(tn * 16 + li, g * 16));
                    bf16x8 b1 = *(const bf16x8*)(VcT2[cur] + swz128(tn * 16 + li, 64 + g * 16));
                    f32x4 z = (f32x4)0.0f;
                    z = __builtin_amdgcn_mfma_f32_16x16x32_bf16(a0, b0, z, 0, 0, 0);
                    z = __builtin_amdgcn_mfma_f32_16x16x32_bf16(a1, b1, z, 0, 0, 0);
                    go[tn] = z;
                }
                __builtin_amdgcn_s_setprio(0);
            }
            bf16x8 kb0[4], kb1[4];
#pragma unroll
            for (int tn = 0; tn < 4; ++tn) {
                kb0[tn] = *(const bf16x8*)(KcT2[cur] + swz128(tn * 16 + li, g * 16));
                kb1[tn] = *(const bf16x8*)(KcT2[cur] + swz128(tn * 16 + li, 64 + g * 16));
            }
            __threadfence_block();
            if (lane == 0) atomicAdd(&cntB, 1u);
            {
                volatile u32* vc = &cntB;
                u32 tgt = 4u * (u32)(c + 1);
                while (*vc < tgt) { __builtin_amdgcn_s_sleep(1); }
            }
            __threadfence_block();
            f32x4 gz[4];
#pragma unroll
            for (int tn = 0; tn < 4; ++tn) {
                int n = tn * 16 + li;
                float sn = spart[n] + spart[64 + n] + spart[128 + n] + spart[192 + n];
#pragma unroll
                for (int r = 0; r < 4; ++r) gz[tn][r] = pk[tn][r] * (sn - aT[tn][r]);
                f32x4 tg = trans4(gz[tn], q4);
                *(uint2*)(SGZN + swz128(wk * 16 + g * 4 + q4, tn * 32 + b4 * 2)) =
                    make_uint2(pk2(tg[0], tg[1]), pk2(tg[2], tg[3]));
            }
            f32x4 gi[4];
            {
                bf16x8 a0 = *(const bf16x8*)(SGZN + swz128(wk * 16 + li, g * 16));
                bf16x8 a1 = *(const bf16x8*)(SGZN + swz128(wk * 16 + li, 64 + g * 16));
                __builtin_amdgcn_s_setprio(1);
#pragma unroll
                for (int tn = 0; tn < 4; ++tn) {
                    f32x4 z = (f32x4)0.0f;
                    z = __builtin_amdgcn_mfma_f32_16x16x32_bf16(a0, kb0[tn], z, 0, 0, 0);
                    z = __builtin_amdgcn_mfma_f32_16x16x32_bf16(a1, kb1[tn], z, 0, 0, 0);
                    gi[tn] = z;
                }
                __builtin_amdgcn_s_setprio(0);
            }
            if (c + 1 < 64) {
                float lin = lrc[c * 4 + 0], lout = lrc[c * 4 + 1];
                float win = lrc[c * 4 + 2], wout = lrc[c * 4 + 3];
#pragma unroll
                for (int tn = 0; tn < 4; ++tn) {
                    WiR[tn] = win * WiR[tn] - lin * gi[tn];
                    WoR[tn] = wout * WoR[tn] + lout * go[tn];   // grad_out = -go
                    int d = tn * 16 + li;
                    *(uint2*)(SWoT2[nxt] + swz128(d, wk * 32 + g * 8)) =
                        make_uint2(pk2(WoR[tn][0], WoR[tn][1]), pk2(WoR[tn][2], WoR[tn][3]));
                    f32x4 ti = trans4(WiR[tn], q4);
                    *(uint2*)(SWiN + swz128(wk * 16 + g * 4 + q4, tn * 32 + b4 * 2)) =
                        make_uint2(pk2(ti[0], ti[1]), pk2(ti[2], ti[3]));
                    f32x4 to = trans4(WoR[tn], q4);
                    *(uint2*)(SWoN + swz128(wk * 16 + g * 4 + q4, tn * 32 + b4 * 2)) =
                        make_uint2(pk2(to[0], to[1]), pk2(to[2], to[3]));
                }
            }
        }
        __syncthreads();
    }
}

// ---------------------------------------------------------------------------
extern "C" void kernel_launch(void* const* d_in, const int* in_sizes, int n_in,
                              void* d_out, int out_size, void* d_ws, size_t ws_size,
                              hipStream_t stream)
{
    const float* x     = (const float*)d_in[0];
    const float* Wq    = (const float*)d_in[1];
    const float* Wk    = (const float*)d_in[2];
    const float* Wv    = (const float*)d_in[3];
    const float* Wlr   = (const float*)d_in[4];
    const float* Wbeta = (const float*)d_in[5];
    const float* Wo    = (const float*)d_in[6];
    const float* Wi0   = (const float*)d_in[7];
    const float* Wo0   = (const float*)d_in[8];
    float* out = (float*)d_out;

    char* od = (char*)d_out;
    u16* xb  = (u16*)(od);                 // dead before out_proj overwrites
    u16* wb  = (u16*)(od + 33554432u);
    u16* wlb = (u16*)(od + 39845888u);

    char* ws = (char*)d_ws;
    u16* qb        = (u16*)(ws);
    u16* kb        = (u16*)(ws + 33554432u);
    u16* vb        = (u16*)(ws + 67108864u);
    u16* obuf      = (u16*)(ws + 100663296u);
    float* lrc_all = (float*)(ws + 134217728u);
    u16* wob       = (u16*)(ws + 134283264u);
    if (ws_size < 136380416u) return;

    convert_kernel<<<2048, 256, 0, stream>>>(x, Wq, Wk, Wv, Wo, Wlr, Wbeta,
                                             xb, wb, wob, wlb);
    proj_qkv_kernel<<<dim3(12, 64), 512, 0, stream>>>(xb, wb, qb, kb, vb);
    lrwd_kernel<<<128, 256, 0, stream>>>(xb, wlb, lrc_all);
    scan_kernel<<<64, 512, 0, stream>>>(qb, kb, vb, lrc_all, Wi0, Wo0, obuf);
    out_proj_kernel<<<dim3(4, 64), 512, 0, stream>>>(obuf, wob, out);
}